// Round 1
// baseline (1858.497 us; speedup 1.0000x reference)
//
#include <hip/hip_runtime.h>
#include <hip/hip_bf16.h>
#include <math.h>

#define DEVFN __device__ __forceinline__

typedef __attribute__((ext_vector_type(8))) short bf16x8;
typedef __attribute__((ext_vector_type(4))) float f32x4;

static constexpr int Bn = 4, Sn = 256, En = 1024, Hn = 16;
static constexpr int Mn = 65536, Kt = 32, FFn = 4096;
static constexpr int NT = Bn * Sn;           // 1024 tokens

DEVFN unsigned short f2b(float f) {          // f32 -> bf16 RNE
  unsigned int u = __float_as_uint(f);
  unsigned int r = (u + 0x7FFFu + ((u >> 16) & 1u)) >> 16;
  return (unsigned short)r;
}

DEVFN void cvt8(const float4& a, const float4& b, unsigned short* o) {
  o[0]=f2b(a.x); o[1]=f2b(a.y); o[2]=f2b(a.z); o[3]=f2b(a.w);
  o[4]=f2b(b.x); o[5]=f2b(b.y); o[6]=f2b(b.z); o[7]=f2b(b.w);
}

// ---------------- transpose W[R][C] f32 -> out[C][R] bf16 ----------------
__global__ __launch_bounds__(256) void k_transpose_bf16(
    const float* __restrict__ in, unsigned short* __restrict__ out, int R, int C) {
  __shared__ float tile[64][65];
  int tx = threadIdx.x & 63, ty = threadIdx.x >> 6;
  int c0 = blockIdx.x * 64, r0 = blockIdx.y * 64;
  #pragma unroll
  for (int i = 0; i < 16; i++) {
    int r = ty + i * 4;
    tile[tx][r] = in[(size_t)(r0 + r) * C + (c0 + tx)];
  }
  __syncthreads();
  #pragma unroll
  for (int i = 0; i < 16; i++) {
    int c = ty + i * 4;
    out[(size_t)(c0 + c) * R + (r0 + tx)] = f2b(tile[c][tx]);
  }
}

// ---------------- f32 -> bf16 elementwise (x4) ----------------
__global__ __launch_bounds__(256) void k_cvt_bf16(
    const float* __restrict__ in, unsigned short* __restrict__ out, int n4) {
  int i = blockIdx.x * 256 + threadIdx.x;
  if (i >= n4) return;
  float4 v = ((const float4*)in)[i];
  uint2 o;
  o.x = (unsigned int)f2b(v.x) | ((unsigned int)f2b(v.y) << 16);
  o.y = (unsigned int)f2b(v.z) | ((unsigned int)f2b(v.w) << 16);
  ((uint2*)out)[i] = o;
}

// ---------------- row rnorm of mem_keys: 1/max(||row||, 1e-12) ----------------
__global__ __launch_bounds__(256) void k_row_rnorm(
    const float* __restrict__ mk, float* __restrict__ rn) {
  int m = blockIdx.x;
  float4 v = ((const float4*)(mk + (size_t)m * En))[threadIdx.x];
  float ss = v.x*v.x + v.y*v.y + v.z*v.z + v.w*v.w;
  #pragma unroll
  for (int d = 32; d; d >>= 1) ss += __shfl_down(ss, d);
  __shared__ float red[4];
  int lane = threadIdx.x & 63, w = threadIdx.x >> 6;
  if (lane == 0) red[w] = ss;
  __syncthreads();
  if (threadIdx.x == 0)
    rn[m] = 1.0f / fmaxf(sqrtf(red[0] + red[1] + red[2] + red[3]), 1e-12f);
}

// ---------------- LayerNorm over rows of [NT][En] ----------------
__global__ __launch_bounds__(256) void k_layernorm(
    const float* __restrict__ in, const float* __restrict__ g, const float* __restrict__ bb,
    float* __restrict__ outf, unsigned short* __restrict__ outb) {
  int n = blockIdx.x, t = threadIdx.x;
  float4 v = ((const float4*)(in + (size_t)n * En))[t];
  float s  = v.x + v.y + v.z + v.w;
  float s2 = v.x*v.x + v.y*v.y + v.z*v.z + v.w*v.w;
  #pragma unroll
  for (int d = 32; d; d >>= 1) { s += __shfl_down(s, d); s2 += __shfl_down(s2, d); }
  __shared__ float rs[4], rq[4];
  int lane = t & 63, w = t >> 6;
  if (lane == 0) { rs[w] = s; rq[w] = s2; }
  __syncthreads();
  float mean = (rs[0]+rs[1]+rs[2]+rs[3]) * (1.0f/En);
  float var  = (rq[0]+rq[1]+rq[2]+rq[3]) * (1.0f/En) - mean*mean;
  float rstd = rsqrtf(var + 1e-5f);
  float4 gg = ((const float4*)g)[t];
  float4 bv = ((const float4*)bb)[t];
  float o0 = (v.x-mean)*rstd*gg.x + bv.x;
  float o1 = (v.y-mean)*rstd*gg.y + bv.y;
  float o2 = (v.z-mean)*rstd*gg.z + bv.z;
  float o3 = (v.w-mean)*rstd*gg.w + bv.w;
  if (outf) { float4 ov = {o0,o1,o2,o3}; ((float4*)(outf + (size_t)n*En))[t] = ov; }
  if (outb) {
    uint2 o;
    o.x = (unsigned int)f2b(o0) | ((unsigned int)f2b(o1) << 16);
    o.y = (unsigned int)f2b(o2) | ((unsigned int)f2b(o3) << 16);
    ((uint2*)(outb + (size_t)n*En))[t] = o;
  }
}

// ---------------- GEMM: C[M][N] = A[M][K] @ Bt[N][K]^T (+epilogue) ----------------
// EPI 0: bf16 out (+bias) | 1: f32 out (+bias+resid) | 2: GELU->bf16 (+bias) | 3: f32 out * colscale
template<int EPI, bool AGATHER, bool BF32>
__global__ __launch_bounds__(256) void k_gemm(
    const unsigned short* __restrict__ Ab, const float* __restrict__ Af,
    const unsigned short* __restrict__ Bb, const float* __restrict__ Bf,
    const int* __restrict__ gidx,
    const float* __restrict__ bias, const float* __restrict__ resid,
    const float* __restrict__ colscale,
    float* __restrict__ Cf, unsigned short* __restrict__ Cb,
    int Mdim, int Ndim, int Kdim) {
  __shared__ unsigned short As[128][48];   // stride 48 shorts = 96B (16B-aligned rows)
  __shared__ unsigned short Bs[128][48];
  const int t = threadIdx.x, lane = t & 63, w = t >> 6;
  const int wr = w >> 1, wc = w & 1, l15 = lane & 15, l4 = lane >> 4;
  const int row0 = blockIdx.y * 128, col0 = blockIdx.x * 128;
  const int lr = t >> 2;              // staging row 0..63 (and +64)
  const int k8 = (t & 3) * 8;         // staging k offset

  int ga0 = 0, ga1 = 0;
  if constexpr (AGATHER) { ga0 = gidx[row0 + lr]; ga1 = gidx[row0 + lr + 64]; }

  f32x4 acc[4][4];
  #pragma unroll
  for (int i = 0; i < 4; i++)
    #pragma unroll
    for (int j = 0; j < 4; j++) acc[i][j] = (f32x4){0.f,0.f,0.f,0.f};

  for (int kt0 = 0; kt0 < Kdim; kt0 += 32) {
    uint4 a0, a1, b0, b1;
    float4 fa00, fa01, fa10, fa11, fb00, fb01, fb10, fb11;
    if constexpr (!AGATHER) {
      const unsigned short* p = Ab + (size_t)(row0 + lr) * Kdim + kt0 + k8;
      a0 = *(const uint4*)p;
      a1 = *(const uint4*)(p + (size_t)64 * Kdim);
    } else {
      const float* p0 = Af + (size_t)ga0 * Kdim + kt0 + k8;
      fa00 = *(const float4*)p0; fa01 = *(const float4*)(p0 + 4);
      const float* p1 = Af + (size_t)ga1 * Kdim + kt0 + k8;
      fa10 = *(const float4*)p1; fa11 = *(const float4*)(p1 + 4);
    }
    if constexpr (!BF32) {
      const unsigned short* p = Bb + (size_t)(col0 + lr) * Kdim + kt0 + k8;
      b0 = *(const uint4*)p;
      b1 = *(const uint4*)(p + (size_t)64 * Kdim);
    } else {
      const float* p0 = Bf + (size_t)(col0 + lr) * Kdim + kt0 + k8;
      fb00 = *(const float4*)p0; fb01 = *(const float4*)(p0 + 4);
      const float* p1 = p0 + (size_t)64 * Kdim;
      fb10 = *(const float4*)p1; fb11 = *(const float4*)(p1 + 4);
    }
    __syncthreads();
    if constexpr (!AGATHER) {
      *(uint4*)&As[lr][k8] = a0;
      *(uint4*)&As[lr + 64][k8] = a1;
    } else {
      cvt8(fa00, fa01, &As[lr][k8]);
      cvt8(fa10, fa11, &As[lr + 64][k8]);
    }
    if constexpr (!BF32) {
      *(uint4*)&Bs[lr][k8] = b0;
      *(uint4*)&Bs[lr + 64][k8] = b1;
    } else {
      cvt8(fb00, fb01, &Bs[lr][k8]);
      cvt8(fb10, fb11, &Bs[lr + 64][k8]);
    }
    __syncthreads();
    bf16x8 af[4], bfr[4];
    #pragma unroll
    for (int mi = 0; mi < 4; mi++) af[mi]  = *(const bf16x8*)&As[wr*64 + mi*16 + l15][l4*8];
    #pragma unroll
    for (int ni = 0; ni < 4; ni++) bfr[ni] = *(const bf16x8*)&Bs[wc*64 + ni*16 + l15][l4*8];
    #pragma unroll
    for (int mi = 0; mi < 4; mi++)
      #pragma unroll
      for (int ni = 0; ni < 4; ni++)
        acc[mi][ni] = __builtin_amdgcn_mfma_f32_16x16x32_bf16(af[mi], bfr[ni], acc[mi][ni], 0, 0, 0);
  }

  #pragma unroll
  for (int mi = 0; mi < 4; mi++) {
    #pragma unroll
    for (int ni = 0; ni < 4; ni++) {
      int col  = col0 + wc*64 + ni*16 + l15;
      int rowb = row0 + wr*64 + mi*16 + l4*4;
      #pragma unroll
      for (int r = 0; r < 4; r++) {
        float v = acc[mi][ni][r];
        size_t off = (size_t)(rowb + r) * Ndim + col;
        if constexpr (EPI == 0) {
          Cb[off] = f2b(v + bias[col]);
        } else if constexpr (EPI == 1) {
          Cf[off] = v + bias[col] + resid[off];
        } else if constexpr (EPI == 2) {
          float u = v + bias[col];
          u = 0.5f * u * (1.0f + erff(u * 0.70710678118654752f));
          Cb[off] = f2b(u);
        } else {
          Cf[off] = v * colscale[col];
        }
      }
    }
  }
}

// ---------------- fused attention (flash-style), Lk in {256, 8192} ----------------
// Q: [B*Sn][En] bf16 ; K,V: [B*Lk][En] bf16 ; Out: [B*Sn][En] bf16. scale = 1/8.
__global__ __launch_bounds__(256) void k_attn(
    const unsigned short* __restrict__ Qp, const unsigned short* __restrict__ Kp,
    const unsigned short* __restrict__ Vp, unsigned short* __restrict__ Op, int Lk) {
  __shared__ unsigned short Ks[64][72];
  __shared__ unsigned short Vt[64][72];   // V transposed: Vt[d][k]
  __shared__ float Ps[4][16][68];         // per-wave P transpose buffer
  const int b = blockIdx.z, h = blockIdx.y, q0 = blockIdx.x * 64;
  const int t = threadIdx.x, lane = t & 63, w = t >> 6;
  const int l15 = lane & 15, l4 = lane >> 4;

  const int qrow = q0 + w * 16 + l15;
  const unsigned short* qptr = Qp + (size_t)(b * Sn + qrow) * En + h * 64 + l4 * 8;
  bf16x8 qf0 = *(const bf16x8*)qptr;
  bf16x8 qf1 = *(const bf16x8*)(qptr + 32);

  f32x4 oacc[4];
  #pragma unroll
  for (int i = 0; i < 4; i++) oacc[i] = (f32x4){0.f,0.f,0.f,0.f};
  float m_[4] = {-INFINITY, -INFINITY, -INFINITY, -INFINITY};
  float l_[4] = {0.f, 0.f, 0.f, 0.f};

  const int nkt = Lk / 64;
  for (int kt = 0; kt < nkt; ++kt) {
    __syncthreads();                       // protect LDS from previous iter readers
    #pragma unroll
    for (int i = 0; i < 2; i++) {
      int ld = t + i * 256;                // 0..511
      int kr = ld >> 3, d8 = (ld & 7) * 8;
      size_t base = (size_t)(b * Lk + kt * 64 + kr) * En + h * 64 + d8;
      *(uint4*)&Ks[kr][d8] = *(const uint4*)(Kp + base);
      bf16x8 vv = *(const bf16x8*)(Vp + base);
      #pragma unroll
      for (int j = 0; j < 8; j++) Vt[d8 + j][kr] = ((unsigned short*)&vv)[j];
    }
    __syncthreads();

    // S = Q @ K^T  (per wave: 16 q-rows x 64 k-cols)
    f32x4 s[4];
    #pragma unroll
    for (int ni = 0; ni < 4; ni++) {
      s[ni] = (f32x4){0.f,0.f,0.f,0.f};
      bf16x8 kb0 = *(const bf16x8*)&Ks[ni*16 + l15][l4*8];
      bf16x8 kb1 = *(const bf16x8*)&Ks[ni*16 + l15][l4*8 + 32];
      s[ni] = __builtin_amdgcn_mfma_f32_16x16x32_bf16(qf0, kb0, s[ni], 0, 0, 0);
      s[ni] = __builtin_amdgcn_mfma_f32_16x16x32_bf16(qf1, kb1, s[ni], 0, 0, 0);
    }

    // online softmax per q-row (row = l4*4 + r, cols across l15 groups)
    #pragma unroll
    for (int r = 0; r < 4; r++) {
      #pragma unroll
      for (int ni = 0; ni < 4; ni++) s[ni][r] *= 0.125f;
      float mx = fmaxf(fmaxf(s[0][r], s[1][r]), fmaxf(s[2][r], s[3][r]));
      #pragma unroll
      for (int d2 = 1; d2 < 16; d2 <<= 1) mx = fmaxf(mx, __shfl_xor(mx, d2));
      float mn = fmaxf(m_[r], mx);
      float alpha = expf(m_[r] - mn);
      float rsum = 0.f;
      #pragma unroll
      for (int ni = 0; ni < 4; ni++) { float p = expf(s[ni][r] - mn); s[ni][r] = p; rsum += p; }
      #pragma unroll
      for (int d2 = 1; d2 < 16; d2 <<= 1) rsum += __shfl_xor(rsum, d2);
      l_[r] = l_[r] * alpha + rsum;
      m_[r] = mn;
      #pragma unroll
      for (int nd = 0; nd < 4; nd++) oacc[nd][r] *= alpha;
    }

    // transpose P through per-wave LDS into A-frag layout
    #pragma unroll
    for (int ni = 0; ni < 4; ni++)
      #pragma unroll
      for (int r = 0; r < 4; r++)
        Ps[w][l4*4 + r][ni*16 + l15] = s[ni][r];
    asm volatile("s_waitcnt lgkmcnt(0)" ::: "memory");

    #pragma unroll
    for (int half = 0; half < 2; half++) {
      float4 pv0 = *(const float4*)&Ps[w][l15][half*32 + l4*8];
      float4 pv1 = *(const float4*)&Ps[w][l15][half*32 + l4*8 + 4];
      bf16x8 pa;
      pa[0]=(short)f2b(pv0.x); pa[1]=(short)f2b(pv0.y); pa[2]=(short)f2b(pv0.z); pa[3]=(short)f2b(pv0.w);
      pa[4]=(short)f2b(pv1.x); pa[5]=(short)f2b(pv1.y); pa[6]=(short)f2b(pv1.z); pa[7]=(short)f2b(pv1.w);
      #pragma unroll
      for (int nd = 0; nd < 4; nd++) {
        bf16x8 vb = *(const bf16x8*)&Vt[nd*16 + l15][half*32 + l4*8];
        oacc[nd] = __builtin_amdgcn_mfma_f32_16x16x32_bf16(pa, vb, oacc[nd], 0, 0, 0);
      }
    }
  }

  #pragma unroll
  for (int nd = 0; nd < 4; nd++) {
    #pragma unroll
    for (int r = 0; r < 4; r++) {
      int q = q0 + w*16 + l4*4 + r;
      float v = oacc[nd][r] / l_[r];
      Op[(size_t)(b * Sn + q) * En + h * 64 + nd*16 + l15] = f2b(v);
    }
  }
}

// ---------------- exact top-32 per row by iterative max extraction ----------------
__global__ __launch_bounds__(1024) void k_topk(
    float* __restrict__ sims, int* __restrict__ oidx) {
  const int n = blockIdx.x, t = threadIdx.x;
  float* row = sims + (size_t)n * Mn;
  __shared__ float sv[1024];
  __shared__ int   si[1024];
  __shared__ int   bwi;
  const int base = t * 64;
  float lmax = -INFINITY; int lidx = 0;
  for (int j = 0; j < 64; j++) { float v = row[base + j]; if (v > lmax) { lmax = v; lidx = base + j; } }
  for (int it = 0; it < Kt; ++it) {
    sv[t] = lmax; si[t] = lidx;
    __syncthreads();
    if (t < 64) {
      float mv = sv[t]; int mi2 = si[t];
      #pragma unroll 4
      for (int j = 1; j < 16; j++) {
        float v2 = sv[t + 64*j]; int i2 = si[t + 64*j];
        if (v2 > mv || (v2 == mv && i2 < mi2)) { mv = v2; mi2 = i2; }
      }
      #pragma unroll
      for (int d2 = 1; d2 < 64; d2 <<= 1) {
        float ov = __shfl_xor(mv, d2); int oi = __shfl_xor(mi2, d2);
        if (ov > mv || (ov == mv && oi < mi2)) { mv = ov; mi2 = oi; }
      }
      if (t == 0) { bwi = mi2; oidx[n * Kt + it] = mi2; }
    }
    __syncthreads();
    int winner = bwi;
    if ((winner >> 6) == t) {      // I own the winning segment: remove & rescan
      row[winner] = -INFINITY;
      lmax = -INFINITY; lidx = 0;
      for (int j = 0; j < 64; j++) { float v = row[base + j]; if (v > lmax) { lmax = v; lidx = base + j; } }
    }
  }
}

// =============================== host ===============================
extern "C" void kernel_launch(void* const* d_in, const int* in_sizes, int n_in,
                              void* d_out, int out_size, void* d_ws, size_t ws_size,
                              hipStream_t stream) {
  (void)in_sizes; (void)n_in; (void)out_size;
  const float* x      = (const float*)d_in[0];
  const float* mem_k  = (const float*)d_in[1];
  const float* mem_v  = (const float*)d_in[2];
  const float* sa_w[4] = {(const float*)d_in[3], (const float*)d_in[4], (const float*)d_in[5], (const float*)d_in[6]};
  const float* sa_b[4] = {(const float*)d_in[7], (const float*)d_in[8], (const float*)d_in[9], (const float*)d_in[10]};
  const float* ma_w[4] = {(const float*)d_in[11], (const float*)d_in[12], (const float*)d_in[13], (const float*)d_in[14]};
  const float* ma_b[4] = {(const float*)d_in[15], (const float*)d_in[16], (const float*)d_in[17], (const float*)d_in[18]};
  const float* ln_g[3] = {(const float*)d_in[19], (const float*)d_in[21], (const float*)d_in[23]};
  const float* ln_b[3] = {(const float*)d_in[20], (const float*)d_in[22], (const float*)d_in[24]};
  const float* fc1_w = (const float*)d_in[25];
  const float* fc1_b = (const float*)d_in[26];
  const float* fc2_w = (const float*)d_in[27];
  const float* fc2_b = (const float*)d_in[28];
  float* out = (float*)d_out;

  char* ws = (char*)d_ws;
  size_t off = 0;
  auto alloc = [&](size_t bytes) -> char* {
    char* p = ws + off;
    off = (off + bytes + 255) & ~(size_t)255;
    return p;
  };

  unsigned short* wt[8];
  for (int i = 0; i < 8; i++) wt[i] = (unsigned short*)alloc((size_t)En * En * 2);
  unsigned short* fc1t  = (unsigned short*)alloc((size_t)FFn * En * 2);
  unsigned short* fc2t  = (unsigned short*)alloc((size_t)En * FFn * 2);
  unsigned short* xb    = (unsigned short*)alloc((size_t)NT * En * 2);
  unsigned short* Qb    = (unsigned short*)alloc((size_t)NT * En * 2);
  unsigned short* Kb    = (unsigned short*)alloc((size_t)NT * En * 2);
  unsigned short* Vb    = (unsigned short*)alloc((size_t)NT * En * 2);
  unsigned short* at1b  = (unsigned short*)alloc((size_t)NT * En * 2);
  float*          t1    = (float*)alloc((size_t)NT * En * 4);
  float*          x1f   = (float*)alloc((size_t)NT * En * 4);
  unsigned short* x1b   = (unsigned short*)alloc((size_t)NT * En * 2);
  float*          rn    = (float*)alloc((size_t)Mn * 4);
  float*          sims  = (float*)alloc((size_t)NT * Mn * 4);
  int*            idx   = (int*)alloc((size_t)NT * Kt * 4);
  unsigned short* K2b   = (unsigned short*)alloc((size_t)NT * Kt * En * 2);
  unsigned short* V2b   = (unsigned short*)alloc((size_t)NT * Kt * En * 2);
  unsigned short* Q2b   = (unsigned short*)alloc((size_t)NT * En * 2);
  unsigned short* at2b  = (unsigned short*)alloc((size_t)NT * En * 2);
  float*          t2    = (float*)alloc((size_t)NT * En * 4);
  float*          x2f   = (float*)alloc((size_t)NT * En * 4);
  unsigned short* x2b   = (unsigned short*)alloc((size_t)NT * En * 2);
  unsigned short* hb    = (unsigned short*)alloc((size_t)NT * FFn * 2);
  float*          t3    = (float*)alloc((size_t)NT * En * 4);

  if (off > ws_size) return;   // insufficient workspace: leave output poisoned (fail loudly)

  // ---- prep: weight transposes to bf16 [N][K] ----
  for (int i = 0; i < 4; i++)
    k_transpose_bf16<<<dim3(16, 16), 256, 0, stream>>>(sa_w[i], wt[i], En, En);
  for (int i = 0; i < 4; i++)
    k_transpose_bf16<<<dim3(16, 16), 256, 0, stream>>>(ma_w[i], wt[4 + i], En, En);
  k_transpose_bf16<<<dim3(64, 16), 256, 0, stream>>>(fc1_w, fc1t, En, FFn);
  k_transpose_bf16<<<dim3(16, 64), 256, 0, stream>>>(fc2_w, fc2t, FFn, En);

  k_cvt_bf16<<<dim3(NT * En / 4 / 256), 256, 0, stream>>>(x, xb, NT * En / 4);

  const dim3 g1(En / 128, NT / 128);   // (8,8)

  // ---- self-attention ----
  k_gemm<0,false,false><<<g1, 256, 0, stream>>>(xb, nullptr, wt[0], nullptr, nullptr, sa_b[0], nullptr, nullptr, nullptr, Qb, NT, En, En);
  k_gemm<0,false,false><<<g1, 256, 0, stream>>>(xb, nullptr, wt[1], nullptr, nullptr, sa_b[1], nullptr, nullptr, nullptr, Kb, NT, En, En);
  k_gemm<0,false,false><<<g1, 256, 0, stream>>>(xb, nullptr, wt[2], nullptr, nullptr, sa_b[2], nullptr, nullptr, nullptr, Vb, NT, En, En);
  k_attn<<<dim3(Sn / 64, Hn, Bn), 256, 0, stream>>>(Qb, Kb, Vb, at1b, Sn);
  k_gemm<1,false,false><<<g1, 256, 0, stream>>>(at1b, nullptr, wt[3], nullptr, nullptr, sa_b[3], x, nullptr, t1, nullptr, NT, En, En);
  k_layernorm<<<NT, 256, 0, stream>>>(t1, ln_g[0], ln_b[0], x1f, x1b);

  // ---- retrieval: sims + top-k ----
  k_row_rnorm<<<Mn, 256, 0, stream>>>(mem_k, rn);
  k_gemm<3,false,true><<<dim3(Mn / 128, NT / 128), 256, 0, stream>>>(x1b, nullptr, nullptr, mem_k, nullptr, nullptr, nullptr, rn, sims, nullptr, NT, Mn, En);
  k_topk<<<NT, 1024, 0, stream>>>(sims, idx);

  // ---- memory cross-attention ----
  const dim3 g4(En / 128, NT * Kt / 128);  // (8,256)
  k_gemm<0,true,false><<<g4, 256, 0, stream>>>(nullptr, mem_v, wt[5], nullptr, idx, ma_b[1], nullptr, nullptr, nullptr, K2b, NT * Kt, En, En);
  k_gemm<0,true,false><<<g4, 256, 0, stream>>>(nullptr, mem_v, wt[6], nullptr, idx, ma_b[2], nullptr, nullptr, nullptr, V2b, NT * Kt, En, En);
  k_gemm<0,false,false><<<g1, 256, 0, stream>>>(x1b, nullptr, wt[4], nullptr, nullptr, ma_b[0], nullptr, nullptr, nullptr, Q2b, NT, En, En);
  k_attn<<<dim3(Sn / 64, Hn, Bn), 256, 0, stream>>>(Q2b, K2b, V2b, at2b, Sn * Kt);
  k_gemm<1,false,false><<<g1, 256, 0, stream>>>(at2b, nullptr, wt[7], nullptr, nullptr, ma_b[3], x1f, nullptr, t2, nullptr, NT, En, En);
  k_layernorm<<<NT, 256, 0, stream>>>(t2, ln_g[1], ln_b[1], x2f, x2b);

  // ---- FFN ----
  k_gemm<2,false,false><<<dim3(FFn / 128, NT / 128), 256, 0, stream>>>(x2b, nullptr, fc1t, nullptr, nullptr, fc1_b, nullptr, nullptr, nullptr, hb, NT, FFn, En);
  k_gemm<1,false,false><<<g1, 256, 0, stream>>>(hb, nullptr, fc2t, nullptr, nullptr, fc2_b, x2f, nullptr, t3, nullptr, NT, En, FFn);
  k_layernorm<<<NT, 256, 0, stream>>>(t3, ln_g[2], ln_b[2], out, nullptr);
}

// Round 2
// 1398.221 us; speedup vs baseline: 1.3292x; 1.3292x over previous
//
#include <hip/hip_runtime.h>
#include <hip/hip_bf16.h>
#include <math.h>

#define DEVFN __device__ __forceinline__

typedef __attribute__((ext_vector_type(8))) short bf16x8;
typedef __attribute__((ext_vector_type(4))) float f32x4;

static constexpr int Bn = 4, Sn = 256, En = 1024, Hn = 16;
static constexpr int Mn = 65536, Kt = 32, FFn = 4096;
static constexpr int NT = Bn * Sn;           // 1024 tokens

DEVFN unsigned short f2b(float f) {          // f32 -> bf16 RNE
  unsigned int u = __float_as_uint(f);
  unsigned int r = (u + 0x7FFFu + ((u >> 16) & 1u)) >> 16;
  return (unsigned short)r;
}

// ---------------- transpose W[R][C] f32 -> out[C][R] bf16 ----------------
__global__ __launch_bounds__(256) void k_transpose_bf16(
    const float* __restrict__ in, unsigned short* __restrict__ out, int R, int C) {
  __shared__ float tile[64][65];
  int tx = threadIdx.x & 63, ty = threadIdx.x >> 6;
  int c0 = blockIdx.x * 64, r0 = blockIdx.y * 64;
  #pragma unroll
  for (int i = 0; i < 16; i++) {
    int r = ty + i * 4;
    tile[tx][r] = in[(size_t)(r0 + r) * C + (c0 + tx)];
  }
  __syncthreads();
  #pragma unroll
  for (int i = 0; i < 16; i++) {
    int c = ty + i * 4;
    out[(size_t)(c0 + c) * R + (r0 + tx)] = f2b(tile[c][tx]);
  }
}

// ---------------- f32 -> bf16 elementwise (x4) ----------------
__global__ __launch_bounds__(256) void k_cvt_bf16(
    const float* __restrict__ in, unsigned short* __restrict__ out, int n4) {
  int i = blockIdx.x * 256 + threadIdx.x;
  if (i >= n4) return;
  float4 v = ((const float4*)in)[i];
  uint2 o;
  o.x = (unsigned int)f2b(v.x) | ((unsigned int)f2b(v.y) << 16);
  o.y = (unsigned int)f2b(v.z) | ((unsigned int)f2b(v.w) << 16);
  ((uint2*)out)[i] = o;
}

// ---- mem_keys row-normalize + cvt to bf16 (folds cosine norm into B) ----
__global__ __launch_bounds__(256) void k_normcvt(
    const float* __restrict__ mk, unsigned short* __restrict__ out) {
  int m = blockIdx.x, t = threadIdx.x;
  float4 v = ((const float4*)(mk + (size_t)m * En))[t];
  float ss = v.x*v.x + v.y*v.y + v.z*v.z + v.w*v.w;
  #pragma unroll
  for (int d = 32; d; d >>= 1) ss += __shfl_down(ss, d);
  __shared__ float red[4];
  int lane = t & 63, w = t >> 6;
  if (lane == 0) red[w] = ss;
  __syncthreads();
  float rs = 1.0f / fmaxf(sqrtf(red[0] + red[1] + red[2] + red[3]), 1e-12f);
  uint2 o;
  o.x = (unsigned int)f2b(v.x * rs) | ((unsigned int)f2b(v.y * rs) << 16);
  o.y = (unsigned int)f2b(v.z * rs) | ((unsigned int)f2b(v.w * rs) << 16);
  ((uint2*)(out + (size_t)m * En))[t] = o;
}

// ---------------- LayerNorm over rows of [NT][En] ----------------
__global__ __launch_bounds__(256) void k_layernorm(
    const float* __restrict__ in, const float* __restrict__ g, const float* __restrict__ bb,
    float* __restrict__ outf, unsigned short* __restrict__ outb) {
  int n = blockIdx.x, t = threadIdx.x;
  float4 v = ((const float4*)(in + (size_t)n * En))[t];
  float s  = v.x + v.y + v.z + v.w;
  float s2 = v.x*v.x + v.y*v.y + v.z*v.z + v.w*v.w;
  #pragma unroll
  for (int d = 32; d; d >>= 1) { s += __shfl_down(s, d); s2 += __shfl_down(s2, d); }
  __shared__ float rs[4], rq[4];
  int lane = t & 63, w = t >> 6;
  if (lane == 0) { rs[w] = s; rq[w] = s2; }
  __syncthreads();
  float mean = (rs[0]+rs[1]+rs[2]+rs[3]) * (1.0f/En);
  float var  = (rq[0]+rq[1]+rq[2]+rq[3]) * (1.0f/En) - mean*mean;
  float rstd = rsqrtf(var + 1e-5f);
  float4 gg = ((const float4*)g)[t];
  float4 bv = ((const float4*)bb)[t];
  float o0 = (v.x-mean)*rstd*gg.x + bv.x;
  float o1 = (v.y-mean)*rstd*gg.y + bv.y;
  float o2 = (v.z-mean)*rstd*gg.z + bv.z;
  float o3 = (v.w-mean)*rstd*gg.w + bv.w;
  if (outf) { float4 ov = {o0,o1,o2,o3}; ((float4*)(outf + (size_t)n*En))[t] = ov; }
  if (outb) {
    uint2 o;
    o.x = (unsigned int)f2b(o0) | ((unsigned int)f2b(o1) << 16);
    o.y = (unsigned int)f2b(o2) | ((unsigned int)f2b(o3) << 16);
    ((uint2*)(outb + (size_t)n*En))[t] = o;
  }
}

// ---------------- GEMM: C[M][N] = A[M][K] @ Bt[N][K]^T (+epilogue) ----------------
// EPI 0: bf16 out (+bias) | 1: f32 out (+bias+resid) | 2: GELU->bf16 (+bias) | 4: f32 out
// SWAPG: blockIdx.x indexes row-tiles (B-tile L2 reuse across adjacent blocks)
template<int EPI, bool AGATHER, bool SWAPG>
__global__ __launch_bounds__(256) void k_gemm(
    const unsigned short* __restrict__ Ab, const unsigned short* __restrict__ Bb,
    const int* __restrict__ gidx,
    const float* __restrict__ bias, const float* __restrict__ resid,
    float* __restrict__ Cf, unsigned short* __restrict__ Cb,
    int Ndim, int Kdim) {
  __shared__ unsigned short As[128][48];   // stride 48 shorts = 96B (16B-aligned rows)
  __shared__ unsigned short Bs[128][48];
  const int t = threadIdx.x, lane = t & 63, w = t >> 6;
  const int wr = w >> 1, wc = w & 1, l15 = lane & 15, l4 = lane >> 4;
  const int row0 = (SWAPG ? blockIdx.x : blockIdx.y) * 128;
  const int col0 = (SWAPG ? blockIdx.y : blockIdx.x) * 128;
  const int lr = t >> 2;              // staging row 0..63 (and +64)
  const int k8 = (t & 3) * 8;         // staging k offset

  size_t ra0, ra1;
  if constexpr (AGATHER) {
    ra0 = (size_t)gidx[row0 + lr] * Kdim;
    ra1 = (size_t)gidx[row0 + lr + 64] * Kdim;
  } else {
    ra0 = (size_t)(row0 + lr) * Kdim;
    ra1 = ra0 + (size_t)64 * Kdim;
  }

  f32x4 acc[4][4];
  #pragma unroll
  for (int i = 0; i < 4; i++)
    #pragma unroll
    for (int j = 0; j < 4; j++) acc[i][j] = (f32x4){0.f,0.f,0.f,0.f};

  for (int kt0 = 0; kt0 < Kdim; kt0 += 32) {
    uint4 a0 = *(const uint4*)(Ab + ra0 + kt0 + k8);
    uint4 a1 = *(const uint4*)(Ab + ra1 + kt0 + k8);
    const unsigned short* p = Bb + (size_t)(col0 + lr) * Kdim + kt0 + k8;
    uint4 b0 = *(const uint4*)p;
    uint4 b1 = *(const uint4*)(p + (size_t)64 * Kdim);
    __syncthreads();
    *(uint4*)&As[lr][k8] = a0;
    *(uint4*)&As[lr + 64][k8] = a1;
    *(uint4*)&Bs[lr][k8] = b0;
    *(uint4*)&Bs[lr + 64][k8] = b1;
    __syncthreads();
    bf16x8 af[4], bfr[4];
    #pragma unroll
    for (int mi = 0; mi < 4; mi++) af[mi]  = *(const bf16x8*)&As[wr*64 + mi*16 + l15][l4*8];
    #pragma unroll
    for (int ni = 0; ni < 4; ni++) bfr[ni] = *(const bf16x8*)&Bs[wc*64 + ni*16 + l15][l4*8];
    #pragma unroll
    for (int mi = 0; mi < 4; mi++)
      #pragma unroll
      for (int ni = 0; ni < 4; ni++)
        acc[mi][ni] = __builtin_amdgcn_mfma_f32_16x16x32_bf16(af[mi], bfr[ni], acc[mi][ni], 0, 0, 0);
  }

  #pragma unroll
  for (int mi = 0; mi < 4; mi++) {
    #pragma unroll
    for (int ni = 0; ni < 4; ni++) {
      int col  = col0 + wc*64 + ni*16 + l15;
      int rowb = row0 + wr*64 + mi*16 + l4*4;
      #pragma unroll
      for (int r = 0; r < 4; r++) {
        float v = acc[mi][ni][r];
        size_t off = (size_t)(rowb + r) * Ndim + col;
        if constexpr (EPI == 0) {
          Cb[off] = f2b(v + bias[col]);
        } else if constexpr (EPI == 1) {
          Cf[off] = v + bias[col] + resid[off];
        } else if constexpr (EPI == 2) {
          float u = v + bias[col];
          u = 0.5f * u * (1.0f + erff(u * 0.70710678118654752f));
          Cb[off] = f2b(u);
        } else {
          Cf[off] = v;
        }
      }
    }
  }
}

// ---------------- fused attention (flash-style) with optional KV-split ----------------
// SPLIT==1: direct bf16 out. SPLIT>1: unnormalized partials (PO, PM, PL).
template<int SPLIT>
__global__ __launch_bounds__(256) void k_attn(
    const unsigned short* __restrict__ Qp, const unsigned short* __restrict__ Kp,
    const unsigned short* __restrict__ Vp, unsigned short* __restrict__ Op,
    float* __restrict__ PO, float* __restrict__ PM, float* __restrict__ PL, int Lk) {
  __shared__ unsigned short Ks[64][72];
  __shared__ unsigned short Vt[64][72];   // V transposed (k-chunk XOR-swizzled by d>>3)
  __shared__ float Ps[4][16][68];         // per-wave P transpose buffer
  const int b = blockIdx.z / SPLIT, sp = blockIdx.z % SPLIT;
  const int h = blockIdx.y, q0 = blockIdx.x * 64;
  const int t = threadIdx.x, lane = t & 63, w = t >> 6;
  const int l15 = lane & 15, l4 = lane >> 4;

  const int qrow = q0 + w * 16 + l15;
  const unsigned short* qptr = Qp + (size_t)(b * Sn + qrow) * En + h * 64 + l4 * 8;
  bf16x8 qf0 = *(const bf16x8*)qptr;
  bf16x8 qf1 = *(const bf16x8*)(qptr + 32);

  f32x4 oacc[4];
  #pragma unroll
  for (int i = 0; i < 4; i++) oacc[i] = (f32x4){0.f,0.f,0.f,0.f};
  float m_[4] = {-INFINITY, -INFINITY, -INFINITY, -INFINITY};
  float l_[4] = {0.f, 0.f, 0.f, 0.f};

  const int nkt = Lk / (64 * SPLIT);
  for (int kt = sp * nkt; kt < (sp + 1) * nkt; ++kt) {
    __syncthreads();                       // protect LDS from previous iter readers
    #pragma unroll
    for (int i = 0; i < 2; i++) {
      int ld = t + i * 256;                // 0..511
      int kr = ld >> 3, d8 = (ld & 7) * 8;
      size_t base = (size_t)(b * Lk + kt * 64 + kr) * En + h * 64 + d8;
      *(uint4*)&Ks[kr][d8] = *(const uint4*)(Kp + base);
      bf16x8 vv = *(const bf16x8*)(Vp + base);
      int colswz = kr ^ ((t & 7) << 3);    // XOR-swizzle: spreads d8-groups across banks
      #pragma unroll
      for (int j = 0; j < 8; j++) Vt[d8 + j][colswz] = ((unsigned short*)&vv)[j];
    }
    __syncthreads();

    // S = Q @ K^T  (per wave: 16 q-rows x 64 k-cols)
    f32x4 s[4];
    #pragma unroll
    for (int ni = 0; ni < 4; ni++) {
      s[ni] = (f32x4){0.f,0.f,0.f,0.f};
      bf16x8 kb0 = *(const bf16x8*)&Ks[ni*16 + l15][l4*8];
      bf16x8 kb1 = *(const bf16x8*)&Ks[ni*16 + l15][l4*8 + 32];
      s[ni] = __builtin_amdgcn_mfma_f32_16x16x32_bf16(qf0, kb0, s[ni], 0, 0, 0);
      s[ni] = __builtin_amdgcn_mfma_f32_16x16x32_bf16(qf1, kb1, s[ni], 0, 0, 0);
    }

    // online softmax per q-row (row = l4*4 + r, cols across l15 groups)
    #pragma unroll
    for (int r = 0; r < 4; r++) {
      #pragma unroll
      for (int ni = 0; ni < 4; ni++) s[ni][r] *= 0.125f;
      float mx = fmaxf(fmaxf(s[0][r], s[1][r]), fmaxf(s[2][r], s[3][r]));
      #pragma unroll
      for (int d2 = 1; d2 < 16; d2 <<= 1) mx = fmaxf(mx, __shfl_xor(mx, d2));
      float mn = fmaxf(m_[r], mx);
      float alpha = expf(m_[r] - mn);
      float rsum = 0.f;
      #pragma unroll
      for (int ni = 0; ni < 4; ni++) { float p = expf(s[ni][r] - mn); s[ni][r] = p; rsum += p; }
      #pragma unroll
      for (int d2 = 1; d2 < 16; d2 <<= 1) rsum += __shfl_xor(rsum, d2);
      l_[r] = l_[r] * alpha + rsum;
      m_[r] = mn;
      #pragma unroll
      for (int nd = 0; nd < 4; nd++) oacc[nd][r] *= alpha;
    }

    // transpose P through per-wave LDS into A-frag layout
    #pragma unroll
    for (int ni = 0; ni < 4; ni++)
      #pragma unroll
      for (int r = 0; r < 4; r++)
        Ps[w][l4*4 + r][ni*16 + l15] = s[ni][r];
    asm volatile("s_waitcnt lgkmcnt(0)" ::: "memory");

    #pragma unroll
    for (int half = 0; half < 2; half++) {
      float4 pv0 = *(const float4*)&Ps[w][l15][half*32 + l4*8];
      float4 pv1 = *(const float4*)&Ps[w][l15][half*32 + l4*8 + 4];
      bf16x8 pa;
      pa[0]=(short)f2b(pv0.x); pa[1]=(short)f2b(pv0.y); pa[2]=(short)f2b(pv0.z); pa[3]=(short)f2b(pv0.w);
      pa[4]=(short)f2b(pv1.x); pa[5]=(short)f2b(pv1.y); pa[6]=(short)f2b(pv1.z); pa[7]=(short)f2b(pv1.w);
      #pragma unroll
      for (int nd = 0; nd < 4; nd++) {
        int dd = nd*16 + l15;
        bf16x8 vb = *(const bf16x8*)&Vt[dd][(half*32 + l4*8) ^ (((dd >> 3) & 7) << 3)];
        oacc[nd] = __builtin_amdgcn_mfma_f32_16x16x32_bf16(pa, vb, oacc[nd], 0, 0, 0);
      }
    }
  }

  if constexpr (SPLIT == 1) {
    #pragma unroll
    for (int nd = 0; nd < 4; nd++)
      #pragma unroll
      for (int r = 0; r < 4; r++) {
        int q = q0 + w*16 + l4*4 + r;
        Op[(size_t)(b * Sn + q) * En + h * 64 + nd*16 + l15] = f2b(oacc[nd][r] / l_[r]);
      }
  } else {
    const int slot = ((b * Hn + h) * 4 + blockIdx.x) * SPLIT + sp;
    #pragma unroll
    for (int nd = 0; nd < 4; nd++)
      #pragma unroll
      for (int r = 0; r < 4; r++)
        PO[slot * 4096 + (w*16 + l4*4 + r) * 64 + nd*16 + l15] = oacc[nd][r];
    if (l15 == 0) {
      #pragma unroll
      for (int r = 0; r < 4; r++) {
        PM[slot * 64 + w*16 + l4*4 + r] = m_[r];
        PL[slot * 64 + w*16 + l4*4 + r] = l_[r];
      }
    }
  }
}

// ---------------- combine split-K attention partials (SPLIT=4) ----------------
__global__ __launch_bounds__(256) void k_attn_comb(
    const float* __restrict__ PO, const float* __restrict__ PM,
    const float* __restrict__ PL, unsigned short* __restrict__ Op) {
  const int W = blockIdx.x * 4 + (threadIdx.x >> 6);  // global wave = (bh, q) row
  const int lane = threadIdx.x & 63;
  const int bh = W >> 8, q = W & 255;
  const int qb = q >> 6, qq = q & 63;
  const int slotBase = (bh * 4 + qb) * 4;
  float ms[4];
  float M = -INFINITY;
  #pragma unroll
  for (int s = 0; s < 4; s++) { ms[s] = PM[(slotBase + s) * 64 + qq]; M = fmaxf(M, ms[s]); }
  float L = 0.f, acc = 0.f;
  #pragma unroll
  for (int s = 0; s < 4; s++) {
    float wgt = expf(ms[s] - M);
    L += PL[(slotBase + s) * 64 + qq] * wgt;
    acc += wgt * PO[(size_t)(slotBase + s) * 4096 + qq * 64 + lane];
  }
  const int b = bh >> 4, h = bh & 15;
  Op[(size_t)(b * Sn + q) * En + h * 64 + lane] = f2b(acc / L);
}

// ---------------- exact top-32 per row by iterative max extraction ----------------
__global__ __launch_bounds__(1024) void k_topk(
    float* __restrict__ sims, int* __restrict__ oidx) {
  const int n = blockIdx.x, t = threadIdx.x;
  float* row = sims + (size_t)n * Mn;
  __shared__ float sv[1024];
  __shared__ int   si[1024];
  __shared__ int   bwi;
  const int base = t * 64;
  const float4* row4 = (const float4*)(row + base);
  float lmax = -INFINITY; int lidx = 0;
  #pragma unroll 4
  for (int jj = 0; jj < 16; jj++) {
    float4 v = row4[jj];
    if (v.x > lmax) { lmax = v.x; lidx = base + jj*4; }
    if (v.y > lmax) { lmax = v.y; lidx = base + jj*4 + 1; }
    if (v.z > lmax) { lmax = v.z; lidx = base + jj*4 + 2; }
    if (v.w > lmax) { lmax = v.w; lidx = base + jj*4 + 3; }
  }
  for (int it = 0; it < Kt; ++it) {
    sv[t] = lmax; si[t] = lidx;
    __syncthreads();
    if (t < 64) {
      float mv = sv[t]; int mi2 = si[t];
      #pragma unroll 4
      for (int j = 1; j < 16; j++) {
        float v2 = sv[t + 64*j]; int i2 = si[t + 64*j];
        if (v2 > mv || (v2 == mv && i2 < mi2)) { mv = v2; mi2 = i2; }
      }
      #pragma unroll
      for (int d2 = 1; d2 < 64; d2 <<= 1) {
        float ov = __shfl_xor(mv, d2); int oi = __shfl_xor(mi2, d2);
        if (ov > mv || (ov == mv && oi < mi2)) { mv = ov; mi2 = oi; }
      }
      if (t == 0) { bwi = mi2; oidx[n * Kt + it] = mi2; }
    }
    __syncthreads();
    int winner = bwi;
    if ((winner >> 6) == t) {      // I own the winning segment: remove & rescan
      row[winner] = -INFINITY;
      lmax = -INFINITY; lidx = 0;
      #pragma unroll 4
      for (int jj = 0; jj < 16; jj++) {
        float4 v = row4[jj];
        if (v.x > lmax) { lmax = v.x; lidx = base + jj*4; }
        if (v.y > lmax) { lmax = v.y; lidx = base + jj*4 + 1; }
        if (v.z > lmax) { lmax = v.z; lidx = base + jj*4 + 2; }
        if (v.w > lmax) { lmax = v.w; lidx = base + jj*4 + 3; }
      }
    }
  }
}

// =============================== host ===============================
extern "C" void kernel_launch(void* const* d_in, const int* in_sizes, int n_in,
                              void* d_out, int out_size, void* d_ws, size_t ws_size,
                              hipStream_t stream) {
  (void)in_sizes; (void)n_in; (void)out_size;
  const float* x      = (const float*)d_in[0];
  const float* mem_k  = (const float*)d_in[1];
  const float* mem_v  = (const float*)d_in[2];
  const float* sa_w[4] = {(const float*)d_in[3], (const float*)d_in[4], (const float*)d_in[5], (const float*)d_in[6]};
  const float* sa_b[4] = {(const float*)d_in[7], (const float*)d_in[8], (const float*)d_in[9], (const float*)d_in[10]};
  const float* ma_w[4] = {(const float*)d_in[11], (const float*)d_in[12], (const float*)d_in[13], (const float*)d_in[14]};
  const float* ma_b[4] = {(const float*)d_in[15], (const float*)d_in[16], (const float*)d_in[17], (const float*)d_in[18]};
  const float* ln_g[3] = {(const float*)d_in[19], (const float*)d_in[21], (const float*)d_in[23]};
  const float* ln_b[3] = {(const float*)d_in[20], (const float*)d_in[22], (const float*)d_in[24]};
  const float* fc1_w = (const float*)d_in[25];
  const float* fc1_b = (const float*)d_in[26];
  const float* fc2_w = (const float*)d_in[27];
  const float* fc2_b = (const float*)d_in[28];
  float* out = (float*)d_out;

  char* ws = (char*)d_ws;
  size_t off = 0;
  auto alloc = [&](size_t bytes) -> char* {
    char* p = ws + off;
    off = (off + bytes + 255) & ~(size_t)255;
    return p;
  };

  unsigned short* wt[8];
  for (int i = 0; i < 8; i++) wt[i] = (unsigned short*)alloc((size_t)En * En * 2);
  unsigned short* fc1t  = (unsigned short*)alloc((size_t)FFn * En * 2);
  unsigned short* fc2t  = (unsigned short*)alloc((size_t)En * FFn * 2);
  unsigned short* xb    = (unsigned short*)alloc((size_t)NT * En * 2);
  unsigned short* Qb    = (unsigned short*)alloc((size_t)NT * En * 2);
  unsigned short* Kb    = (unsigned short*)alloc((size_t)NT * En * 2);
  unsigned short* Vb    = (unsigned short*)alloc((size_t)NT * En * 2);
  unsigned short* at1b  = (unsigned short*)alloc((size_t)NT * En * 2);
  float*          t1    = (float*)alloc((size_t)NT * En * 4);
  float*          x1f   = (float*)alloc((size_t)NT * En * 4);
  unsigned short* x1b   = (unsigned short*)alloc((size_t)NT * En * 2);
  float*          sims  = (float*)alloc((size_t)NT * Mn * 4);          // 256 MiB
  int*            idx   = (int*)alloc((size_t)NT * Kt * 4);
  unsigned short* K2b   = (unsigned short*)alloc((size_t)NT * Kt * En * 2);  // 64 MiB
  unsigned short* V2b   = (unsigned short*)alloc((size_t)NT * Kt * En * 2);  // contiguous after K2b
  unsigned short* Q2b   = (unsigned short*)alloc((size_t)NT * En * 2);
  unsigned short* at2b  = (unsigned short*)alloc((size_t)NT * En * 2);
  float*          t2    = (float*)alloc((size_t)NT * En * 4);
  float*          x2f   = (float*)alloc((size_t)NT * En * 4);
  unsigned short* x2b   = (unsigned short*)alloc((size_t)NT * En * 2);
  unsigned short* hb    = (unsigned short*)alloc((size_t)NT * FFn * 2);
  float*          t3    = (float*)alloc((size_t)NT * En * 4);

  if (off > ws_size) return;   // insufficient workspace: leave output poisoned (fail loudly)

  // Overlays (dead-region reuse, keeps ws footprint at round-1 level):
  //  mkb (normalized bf16 mem_keys, 128 MiB) lives in K2b+V2b until the sims GEMM is done.
  //  mvb (bf16 mem_vals, 128 MiB) + attn partials (~65 MiB) live in sims after topk.
  unsigned short* mkb = (unsigned short*)K2b;
  unsigned short* mvb = (unsigned short*)sims;
  float* PO = (float*)((char*)sims + (size_t)128 * 1024 * 1024);
  float* PM = PO + (size_t)1024 * 4096;
  float* PL = PM + (size_t)1024 * 64;

  // ---- prep: weight transposes to bf16 [N][K] ----
  for (int i = 0; i < 4; i++)
    k_transpose_bf16<<<dim3(16, 16), 256, 0, stream>>>(sa_w[i], wt[i], En, En);
  for (int i = 0; i < 4; i++)
    k_transpose_bf16<<<dim3(16, 16), 256, 0, stream>>>(ma_w[i], wt[4 + i], En, En);
  k_transpose_bf16<<<dim3(64, 16), 256, 0, stream>>>(fc1_w, fc1t, En, FFn);
  k_transpose_bf16<<<dim3(16, 64), 256, 0, stream>>>(fc2_w, fc2t, FFn, En);

  k_cvt_bf16<<<dim3(NT * En / 4 / 256), 256, 0, stream>>>(x, xb, NT * En / 4);
  k_normcvt<<<dim3(Mn), 256, 0, stream>>>(mem_k, mkb);

  const dim3 g1(En / 128, NT / 128);   // (8,8)

  // ---- self-attention ----
  k_gemm<0,false,false><<<g1, 256, 0, stream>>>(xb, wt[0], nullptr, sa_b[0], nullptr, nullptr, Qb, En, En);
  k_gemm<0,false,false><<<g1, 256, 0, stream>>>(xb, wt[1], nullptr, sa_b[1], nullptr, nullptr, Kb, En, En);
  k_gemm<0,false,false><<<g1, 256, 0, stream>>>(xb, wt[2], nullptr, sa_b[2], nullptr, nullptr, Vb, En, En);
  k_attn<1><<<dim3(Sn / 64, Hn, Bn), 256, 0, stream>>>(Qb, Kb, Vb, at1b, nullptr, nullptr, nullptr, Sn);
  k_gemm<1,false,false><<<g1, 256, 0, stream>>>(at1b, wt[3], nullptr, sa_b[3], x, t1, nullptr, En, En);
  k_layernorm<<<NT, 256, 0, stream>>>(t1, ln_g[0], ln_b[0], x1f, x1b);

  // ---- retrieval: sims + top-k (SWAPG: 8 row-tiles adjacent -> B read once) ----
  k_gemm<4,false,true><<<dim3(NT / 128, Mn / 128), 256, 0, stream>>>(x1b, mkb, nullptr, nullptr, nullptr, sims, nullptr, Mn, En);
  k_topk<<<NT, 1024, 0, stream>>>(sims, idx);

  // ---- memory cross-attention ----
  k_cvt_bf16<<<dim3(Mn * En / 4 / 256), 256, 0, stream>>>(mem_v, mvb, Mn * En / 4);
  const dim3 g4(En / 128, NT * Kt / 128);  // (8,256): 8 col-tiles adjacent share gathered rows
  k_gemm<0,true,false><<<g4, 256, 0, stream>>>(mvb, wt[5], idx, ma_b[1], nullptr, nullptr, K2b, En, En);
  k_gemm<0,true,false><<<g4, 256, 0, stream>>>(mvb, wt[6], idx, ma_b[2], nullptr, nullptr, V2b, En, En);
  k_gemm<0,false,false><<<g1, 256, 0, stream>>>(x1b, wt[4], nullptr, ma_b[0], nullptr, nullptr, Q2b, En, En);
  k_attn<4><<<dim3(Sn / 64, Hn, Bn * 4), 256, 0, stream>>>(Q2b, K2b, V2b, nullptr, PO, PM, PL, Sn * Kt);
  k_attn_comb<<<dim3(Bn * Hn * Sn / 4), 256, 0, stream>>>(PO, PM, PL, at2b);
  k_gemm<1,false,false><<<g1, 256, 0, stream>>>(at2b, wt[7], nullptr, ma_b[3], x1f, t2, nullptr, En, En);
  k_layernorm<<<NT, 256, 0, stream>>>(t2, ln_g[1], ln_b[1], x2f, x2b);

  // ---- FFN ----
  k_gemm<2,false,false><<<dim3(FFn / 128, NT / 128), 256, 0, stream>>>(x2b, fc1t, nullptr, fc1_b, nullptr, nullptr, hb, FFn, En);
  k_gemm<1,false,false><<<g1, 256, 0, stream>>>(hb, fc2t, nullptr, fc2_b, x2f, t3, nullptr, En, FFn);
  k_layernorm<<<NT, 256, 0, stream>>>(t3, ln_g[2], ln_b[2], out, nullptr);
}

// Round 3
// 1239.115 us; speedup vs baseline: 1.4999x; 1.1284x over previous
//
#include <hip/hip_runtime.h>
#include <hip/hip_bf16.h>
#include <math.h>

#define DEVFN __device__ __forceinline__

typedef __attribute__((ext_vector_type(8))) short bf16x8;
typedef __attribute__((ext_vector_type(4))) float f32x4;

static constexpr int Bn = 4, Sn = 256, En = 1024, Hn = 16;
static constexpr int Mn = 65536, Kt = 32, FFn = 4096;
static constexpr int NT = Bn * Sn;           // 1024 tokens

DEVFN unsigned short f2b(float f) {          // f32 -> bf16 RNE
  unsigned int u = __float_as_uint(f);
  unsigned int r = (u + 0x7FFFu + ((u >> 16) & 1u)) >> 16;
  return (unsigned short)r;
}

DEVFN unsigned okey(float f) {               // order-preserving f32 -> u32
  unsigned u = __float_as_uint(f);
  return u ^ ((u >> 31) ? 0xFFFFFFFFu : 0x80000000u);
}

// ---------------- transpose W[R][C] f32 -> out[C][R] bf16 ----------------
__global__ __launch_bounds__(256) void k_transpose_bf16(
    const float* __restrict__ in, unsigned short* __restrict__ out, int R, int C) {
  __shared__ float tile[64][65];
  int tx = threadIdx.x & 63, ty = threadIdx.x >> 6;
  int c0 = blockIdx.x * 64, r0 = blockIdx.y * 64;
  #pragma unroll
  for (int i = 0; i < 16; i++) {
    int r = ty + i * 4;
    tile[tx][r] = in[(size_t)(r0 + r) * C + (c0 + tx)];
  }
  __syncthreads();
  #pragma unroll
  for (int i = 0; i < 16; i++) {
    int c = ty + i * 4;
    out[(size_t)(c0 + c) * R + (r0 + tx)] = f2b(tile[c][tx]);
  }
}

// ---------------- f32 -> bf16 elementwise (x4) ----------------
__global__ __launch_bounds__(256) void k_cvt_bf16(
    const float* __restrict__ in, unsigned short* __restrict__ out, int n4) {
  int i = blockIdx.x * 256 + threadIdx.x;
  if (i >= n4) return;
  float4 v = ((const float4*)in)[i];
  uint2 o;
  o.x = (unsigned int)f2b(v.x) | ((unsigned int)f2b(v.y) << 16);
  o.y = (unsigned int)f2b(v.z) | ((unsigned int)f2b(v.w) << 16);
  ((uint2*)out)[i] = o;
}

// ---------------- concat up to 3 x 1024-f32 vectors ----------------
__global__ __launch_bounds__(256) void k_concat3(
    const float* __restrict__ a, const float* __restrict__ b,
    const float* __restrict__ c, float* __restrict__ o) {
  int i = blockIdx.x * 256 + threadIdx.x;
  float v = (i < 1024) ? a[i] : (i < 2048) ? b[i - 1024] : c[i - 2048];
  o[i] = v;
}

// ---- mem_keys row-normalize + cvt to bf16 (folds cosine norm into B) ----
__global__ __launch_bounds__(256) void k_normcvt(
    const float* __restrict__ mk, unsigned short* __restrict__ out) {
  int m = blockIdx.x, t = threadIdx.x;
  float4 v = ((const float4*)(mk + (size_t)m * En))[t];
  float ss = v.x*v.x + v.y*v.y + v.z*v.z + v.w*v.w;
  #pragma unroll
  for (int d = 32; d; d >>= 1) ss += __shfl_down(ss, d);
  __shared__ float red[4];
  int lane = t & 63, w = t >> 6;
  if (lane == 0) red[w] = ss;
  __syncthreads();
  float rs = 1.0f / fmaxf(sqrtf(red[0] + red[1] + red[2] + red[3]), 1e-12f);
  uint2 o;
  o.x = (unsigned int)f2b(v.x * rs) | ((unsigned int)f2b(v.y * rs) << 16);
  o.y = (unsigned int)f2b(v.z * rs) | ((unsigned int)f2b(v.w * rs) << 16);
  ((uint2*)(out + (size_t)m * En))[t] = o;
}

// ---------------- LayerNorm over rows of [NT][En] ----------------
__global__ __launch_bounds__(256) void k_layernorm(
    const float* __restrict__ in, const float* __restrict__ g, const float* __restrict__ bb,
    float* __restrict__ outf, unsigned short* __restrict__ outb) {
  int n = blockIdx.x, t = threadIdx.x;
  float4 v = ((const float4*)(in + (size_t)n * En))[t];
  float s  = v.x + v.y + v.z + v.w;
  float s2 = v.x*v.x + v.y*v.y + v.z*v.z + v.w*v.w;
  #pragma unroll
  for (int d = 32; d; d >>= 1) { s += __shfl_down(s, d); s2 += __shfl_down(s2, d); }
  __shared__ float rs[4], rq[4];
  int lane = t & 63, w = t >> 6;
  if (lane == 0) { rs[w] = s; rq[w] = s2; }
  __syncthreads();
  float mean = (rs[0]+rs[1]+rs[2]+rs[3]) * (1.0f/En);
  float var  = (rq[0]+rq[1]+rq[2]+rq[3]) * (1.0f/En) - mean*mean;
  float rstd = rsqrtf(var + 1e-5f);
  float4 gg = ((const float4*)g)[t];
  float4 bv = ((const float4*)bb)[t];
  float o0 = (v.x-mean)*rstd*gg.x + bv.x;
  float o1 = (v.y-mean)*rstd*gg.y + bv.y;
  float o2 = (v.z-mean)*rstd*gg.z + bv.z;
  float o3 = (v.w-mean)*rstd*gg.w + bv.w;
  if (outf) { float4 ov = {o0,o1,o2,o3}; ((float4*)(outf + (size_t)n*En))[t] = ov; }
  if (outb) {
    uint2 o;
    o.x = (unsigned int)f2b(o0) | ((unsigned int)f2b(o1) << 16);
    o.y = (unsigned int)f2b(o2) | ((unsigned int)f2b(o3) << 16);
    ((uint2*)(outb + (size_t)n*En))[t] = o;
  }
}

// ---------------- GEMM: C[M][N] = A[M][K] @ Bt[N][K]^T (+epilogue) ----------------
// EPI 0: bf16 out (+bias) | 1: f32 out (+bias+resid) | 2: GELU->bf16 (+bias) | 4: f32 out
// SWAPG: blockIdx.x indexes row-tiles. NOUT>1: split N into 1024-wide outputs cb0/cb1/cb2.
template<int EPI, bool AGATHER, bool SWAPG, int NOUT>
__global__ __launch_bounds__(256) void k_gemm(
    const unsigned short* __restrict__ Ab, const unsigned short* __restrict__ Bb,
    const int* __restrict__ gidx,
    const float* __restrict__ bias, const float* __restrict__ resid,
    float* __restrict__ Cf, unsigned short* __restrict__ cb0,
    unsigned short* __restrict__ cb1, unsigned short* __restrict__ cb2,
    int Ndim, int Kdim) {
  __shared__ unsigned short As[128][48];   // stride 48 shorts = 96B (16B-aligned rows)
  __shared__ unsigned short Bs[128][48];
  const int t = threadIdx.x, lane = t & 63, w = t >> 6;
  const int wr = w >> 1, wc = w & 1, l15 = lane & 15, l4 = lane >> 4;
  const int row0 = (SWAPG ? blockIdx.x : blockIdx.y) * 128;
  const int col0 = (SWAPG ? blockIdx.y : blockIdx.x) * 128;
  const int lr = t >> 2;              // staging row 0..63 (and +64)
  const int k8 = (t & 3) * 8;         // staging k offset

  size_t ra0, ra1;
  if constexpr (AGATHER) {
    ra0 = (size_t)gidx[row0 + lr] * Kdim;
    ra1 = (size_t)gidx[row0 + lr + 64] * Kdim;
  } else {
    ra0 = (size_t)(row0 + lr) * Kdim;
    ra1 = ra0 + (size_t)64 * Kdim;
  }

  f32x4 acc[4][4];
  #pragma unroll
  for (int i = 0; i < 4; i++)
    #pragma unroll
    for (int j = 0; j < 4; j++) acc[i][j] = (f32x4){0.f,0.f,0.f,0.f};

  for (int kt0 = 0; kt0 < Kdim; kt0 += 32) {
    uint4 a0 = *(const uint4*)(Ab + ra0 + kt0 + k8);
    uint4 a1 = *(const uint4*)(Ab + ra1 + kt0 + k8);
    const unsigned short* p = Bb + (size_t)(col0 + lr) * Kdim + kt0 + k8;
    uint4 b0 = *(const uint4*)p;
    uint4 b1 = *(const uint4*)(p + (size_t)64 * Kdim);
    __syncthreads();
    *(uint4*)&As[lr][k8] = a0;
    *(uint4*)&As[lr + 64][k8] = a1;
    *(uint4*)&Bs[lr][k8] = b0;
    *(uint4*)&Bs[lr + 64][k8] = b1;
    __syncthreads();
    bf16x8 af[4], bfr[4];
    #pragma unroll
    for (int mi = 0; mi < 4; mi++) af[mi]  = *(const bf16x8*)&As[wr*64 + mi*16 + l15][l4*8];
    #pragma unroll
    for (int ni = 0; ni < 4; ni++) bfr[ni] = *(const bf16x8*)&Bs[wc*64 + ni*16 + l15][l4*8];
    #pragma unroll
    for (int mi = 0; mi < 4; mi++)
      #pragma unroll
      for (int ni = 0; ni < 4; ni++)
        acc[mi][ni] = __builtin_amdgcn_mfma_f32_16x16x32_bf16(af[mi], bfr[ni], acc[mi][ni], 0, 0, 0);
  }

  unsigned short* cbase = cb0;
  int colsub = 0;
  if constexpr (NOUT > 1) {
    int which = col0 >> 10;                       // block-uniform output select
    cbase = (which == 0) ? cb0 : (which == 1) ? cb1 : cb2;
    colsub = col0 & 1023;
  }

  #pragma unroll
  for (int mi = 0; mi < 4; mi++) {
    #pragma unroll
    for (int ni = 0; ni < 4; ni++) {
      int col  = col0 + wc*64 + ni*16 + l15;
      int rowb = row0 + wr*64 + mi*16 + l4*4;
      #pragma unroll
      for (int r = 0; r < 4; r++) {
        float v = acc[mi][ni][r];
        size_t off = (size_t)(rowb + r) * Ndim + col;
        if constexpr (EPI == 0) {
          if constexpr (NOUT > 1) {
            int c2 = colsub + wc*64 + ni*16 + l15;
            cbase[(size_t)(rowb + r) * 1024 + c2] = f2b(v + bias[col]);
          } else {
            cb0[off] = f2b(v + bias[col]);
          }
        } else if constexpr (EPI == 1) {
          Cf[off] = v + bias[col] + resid[off];
        } else if constexpr (EPI == 2) {
          float u = v + bias[col];
          u = 0.5f * u * (1.0f + erff(u * 0.70710678118654752f));
          cb0[off] = f2b(u);
        } else {
          Cf[off] = v;
        }
      }
    }
  }
}

// ---------------- fused attention (flash-style) with optional KV-split ----------------
template<int SPLIT>
__global__ __launch_bounds__(256) void k_attn(
    const unsigned short* __restrict__ Qp, const unsigned short* __restrict__ Kp,
    const unsigned short* __restrict__ Vp, unsigned short* __restrict__ Op,
    float* __restrict__ PO, float* __restrict__ PM, float* __restrict__ PL, int Lk) {
  __shared__ unsigned short Ks[64][72];
  __shared__ unsigned short Vt[64][72];   // V transposed (k-chunk XOR-swizzled by d>>3)
  __shared__ float Ps[4][16][68];         // per-wave P transpose buffer
  const int b = blockIdx.z / SPLIT, sp = blockIdx.z % SPLIT;
  const int h = blockIdx.y, q0 = blockIdx.x * 64;
  const int t = threadIdx.x, lane = t & 63, w = t >> 6;
  const int l15 = lane & 15, l4 = lane >> 4;

  const int qrow = q0 + w * 16 + l15;
  const unsigned short* qptr = Qp + (size_t)(b * Sn + qrow) * En + h * 64 + l4 * 8;
  bf16x8 qf0 = *(const bf16x8*)qptr;
  bf16x8 qf1 = *(const bf16x8*)(qptr + 32);

  f32x4 oacc[4];
  #pragma unroll
  for (int i = 0; i < 4; i++) oacc[i] = (f32x4){0.f,0.f,0.f,0.f};
  float m_[4] = {-INFINITY, -INFINITY, -INFINITY, -INFINITY};
  float l_[4] = {0.f, 0.f, 0.f, 0.f};

  const int nkt = Lk / (64 * SPLIT);
  for (int kt = sp * nkt; kt < (sp + 1) * nkt; ++kt) {
    __syncthreads();                       // protect LDS from previous iter readers
    #pragma unroll
    for (int i = 0; i < 2; i++) {
      int ld = t + i * 256;                // 0..511
      int kr = ld >> 3, d8 = (ld & 7) * 8;
      size_t base = (size_t)(b * Lk + kt * 64 + kr) * En + h * 64 + d8;
      *(uint4*)&Ks[kr][d8] = *(const uint4*)(Kp + base);
      bf16x8 vv = *(const bf16x8*)(Vp + base);
      int colswz = kr ^ ((t & 7) << 3);    // XOR-swizzle: spreads d8-groups across banks
      #pragma unroll
      for (int j = 0; j < 8; j++) Vt[d8 + j][colswz] = ((unsigned short*)&vv)[j];
    }
    __syncthreads();

    // S = Q @ K^T  (per wave: 16 q-rows x 64 k-cols)
    f32x4 s[4];
    #pragma unroll
    for (int ni = 0; ni < 4; ni++) {
      s[ni] = (f32x4){0.f,0.f,0.f,0.f};
      bf16x8 kb0 = *(const bf16x8*)&Ks[ni*16 + l15][l4*8];
      bf16x8 kb1 = *(const bf16x8*)&Ks[ni*16 + l15][l4*8 + 32];
      s[ni] = __builtin_amdgcn_mfma_f32_16x16x32_bf16(qf0, kb0, s[ni], 0, 0, 0);
      s[ni] = __builtin_amdgcn_mfma_f32_16x16x32_bf16(qf1, kb1, s[ni], 0, 0, 0);
    }

    // online softmax per q-row
    #pragma unroll
    for (int r = 0; r < 4; r++) {
      #pragma unroll
      for (int ni = 0; ni < 4; ni++) s[ni][r] *= 0.125f;
      float mx = fmaxf(fmaxf(s[0][r], s[1][r]), fmaxf(s[2][r], s[3][r]));
      #pragma unroll
      for (int d2 = 1; d2 < 16; d2 <<= 1) mx = fmaxf(mx, __shfl_xor(mx, d2));
      float mn = fmaxf(m_[r], mx);
      float alpha = expf(m_[r] - mn);
      float rsum = 0.f;
      #pragma unroll
      for (int ni = 0; ni < 4; ni++) { float p = expf(s[ni][r] - mn); s[ni][r] = p; rsum += p; }
      #pragma unroll
      for (int d2 = 1; d2 < 16; d2 <<= 1) rsum += __shfl_xor(rsum, d2);
      l_[r] = l_[r] * alpha + rsum;
      m_[r] = mn;
      #pragma unroll
      for (int nd = 0; nd < 4; nd++) oacc[nd][r] *= alpha;
    }

    // transpose P through per-wave LDS into A-frag layout
    #pragma unroll
    for (int ni = 0; ni < 4; ni++)
      #pragma unroll
      for (int r = 0; r < 4; r++)
        Ps[w][l4*4 + r][ni*16 + l15] = s[ni][r];
    asm volatile("s_waitcnt lgkmcnt(0)" ::: "memory");

    #pragma unroll
    for (int half = 0; half < 2; half++) {
      float4 pv0 = *(const float4*)&Ps[w][l15][half*32 + l4*8];
      float4 pv1 = *(const float4*)&Ps[w][l15][half*32 + l4*8 + 4];
      bf16x8 pa;
      pa[0]=(short)f2b(pv0.x); pa[1]=(short)f2b(pv0.y); pa[2]=(short)f2b(pv0.z); pa[3]=(short)f2b(pv0.w);
      pa[4]=(short)f2b(pv1.x); pa[5]=(short)f2b(pv1.y); pa[6]=(short)f2b(pv1.z); pa[7]=(short)f2b(pv1.w);
      #pragma unroll
      for (int nd = 0; nd < 4; nd++) {
        int dd = nd*16 + l15;
        bf16x8 vb = *(const bf16x8*)&Vt[dd][(half*32 + l4*8) ^ (((dd >> 3) & 7) << 3)];
        oacc[nd] = __builtin_amdgcn_mfma_f32_16x16x32_bf16(pa, vb, oacc[nd], 0, 0, 0);
      }
    }
  }

  if constexpr (SPLIT == 1) {
    #pragma unroll
    for (int nd = 0; nd < 4; nd++)
      #pragma unroll
      for (int r = 0; r < 4; r++) {
        int q = q0 + w*16 + l4*4 + r;
        Op[(size_t)(b * Sn + q) * En + h * 64 + nd*16 + l15] = f2b(oacc[nd][r] / l_[r]);
      }
  } else {
    const int slot = ((b * Hn + h) * 4 + blockIdx.x) * SPLIT + sp;
    #pragma unroll
    for (int nd = 0; nd < 4; nd++)
      #pragma unroll
      for (int r = 0; r < 4; r++)
        PO[slot * 4096 + (w*16 + l4*4 + r) * 64 + nd*16 + l15] = oacc[nd][r];
    if (l15 == 0) {
      #pragma unroll
      for (int r = 0; r < 4; r++) {
        PM[slot * 64 + w*16 + l4*4 + r] = m_[r];
        PL[slot * 64 + w*16 + l4*4 + r] = l_[r];
      }
    }
  }
}

// ---------------- combine split-K attention partials (SPLIT=4) ----------------
__global__ __launch_bounds__(256) void k_attn_comb(
    const float* __restrict__ PO, const float* __restrict__ PM,
    const float* __restrict__ PL, unsigned short* __restrict__ Op) {
  const int W = blockIdx.x * 4 + (threadIdx.x >> 6);
  const int lane = threadIdx.x & 63;
  const int bh = W >> 8, q = W & 255;
  const int qb = q >> 6, qq = q & 63;
  const int slotBase = (bh * 4 + qb) * 4;
  float ms[4];
  float M = -INFINITY;
  #pragma unroll
  for (int s = 0; s < 4; s++) { ms[s] = PM[(slotBase + s) * 64 + qq]; M = fmaxf(M, ms[s]); }
  float L = 0.f, acc = 0.f;
  #pragma unroll
  for (int s = 0; s < 4; s++) {
    float wgt = expf(ms[s] - M);
    L += PL[(slotBase + s) * 64 + qq] * wgt;
    acc += wgt * PO[(size_t)(slotBase + s) * 4096 + qq * 64 + lane];
  }
  const int b = bh >> 4, h = bh & 15;
  Op[(size_t)(b * Sn + q) * En + h * 64 + lane] = f2b(acc / L);
}

// ------------- helpers for radix top-k -------------
DEVFN unsigned blk_exscan(unsigned part, volatile unsigned* wsum, int lane, int wid) {
  unsigned v = part;
  #pragma unroll
  for (int d = 1; d < 64; d <<= 1) { unsigned o = __shfl_up(v, d); if (lane >= d) v += o; }
  if (lane == 63) wsum[wid] = v;
  __syncthreads();
  unsigned woff = 0;
  for (int i = 0; i < wid; i++) woff += wsum[i];
  unsigned r = woff + v - part;
  __syncthreads();
  return r;
}

DEVFN void find_thr(const unsigned* hist, int NB, unsigned need,
                    int t, int lane, int wid, volatile unsigned* wsum,
                    volatile int* s_thr, volatile unsigned* s_above) {
  int per = NB >> 9;                         // bins per thread (NB/512)
  int lo = NB - per * (t + 1);               // my bins, descending coverage with t
  unsigned part = 0;
  for (int j = 0; j < per; j++) part += hist[lo + j];
  unsigned ex = blk_exscan(part, wsum, lane, wid);   // keys in bins above my range
  if (ex < need && ex + part >= need) {      // crossing is in my range (unique t)
    unsigned c = ex;
    for (int j = per - 1; j >= 0; j--) {
      unsigned h = hist[lo + j];
      if (c + h >= need) { *s_thr = lo + j; *s_above = c; break; }
      c += h;
    }
  }
  __syncthreads();
}

// ---------------- exact top-32 per row via 3-level radix select ----------------
// 512 threads/row; scans: hist(31:21) -> hist(20:10) -> hist(9:0) -> ordered emit.
__global__ __launch_bounds__(512) void k_topk(
    const float* __restrict__ sims, int* __restrict__ oidx) {
  const int n = blockIdx.x, t = threadIdx.x;
  const int lane = t & 63, wid = t >> 6;
  const float4* row4 = (const float4*)(sims + (size_t)n * Mn);
  __shared__ unsigned hist[2048];
  __shared__ unsigned wsum[8];
  __shared__ int s_thr;
  __shared__ unsigned s_above, s_imin;

  // ---- P1: bits 31:21 ----
  for (int i = t; i < 2048; i += 512) hist[i] = 0;
  __syncthreads();
  for (int p = 0; p < 32; p++) {
    float4 v = row4[p * 512 + t];
    atomicAdd(&hist[okey(v.x) >> 21], 1u);
    atomicAdd(&hist[okey(v.y) >> 21], 1u);
    atomicAdd(&hist[okey(v.z) >> 21], 1u);
    atomicAdd(&hist[okey(v.w) >> 21], 1u);
  }
  __syncthreads();
  find_thr(hist, 2048, 32, t, lane, wid, wsum, &s_thr, &s_above);
  const unsigned T1 = (unsigned)s_thr;
  const unsigned need2 = 32 - s_above;
  const unsigned cnt1 = hist[T1];

  unsigned L = 0, istar = 0xFFFFFFFFu;
  bool done = false;
  if (cnt1 == need2) { L = T1 << 21; done = true; }   // whole bin accepted

  if (!done) {
    // ---- P2: bits 20:10 within bin T1 ----
    __syncthreads();
    for (int i = t; i < 2048; i += 512) hist[i] = 0;
    __syncthreads();
    for (int p = 0; p < 32; p++) {
      float4 v = row4[p * 512 + t];
      unsigned k;
      k = okey(v.x); if ((k >> 21) == T1) atomicAdd(&hist[(k >> 10) & 2047], 1u);
      k = okey(v.y); if ((k >> 21) == T1) atomicAdd(&hist[(k >> 10) & 2047], 1u);
      k = okey(v.z); if ((k >> 21) == T1) atomicAdd(&hist[(k >> 10) & 2047], 1u);
      k = okey(v.w); if ((k >> 21) == T1) atomicAdd(&hist[(k >> 10) & 2047], 1u);
    }
    __syncthreads();
    find_thr(hist, 2048, need2, t, lane, wid, wsum, &s_thr, &s_above);
    const unsigned T2 = (unsigned)s_thr;
    const unsigned need3 = need2 - s_above;
    const unsigned cnt2 = hist[T2];
    const unsigned pfx2 = (T1 << 11) | T2;            // top-22 bits
    if (cnt2 == need3) { L = pfx2 << 10; done = true; }

    if (!done) {
      // ---- P3: bits 9:0 within prefix pfx2 ----
      __syncthreads();
      for (int i = t; i < 2048; i += 512) hist[i] = 0;
      __syncthreads();
      for (int p = 0; p < 32; p++) {
        float4 v = row4[p * 512 + t];
        unsigned k;
        k = okey(v.x); if ((k >> 10) == pfx2) atomicAdd(&hist[k & 1023], 1u);
        k = okey(v.y); if ((k >> 10) == pfx2) atomicAdd(&hist[k & 1023], 1u);
        k = okey(v.z); if ((k >> 10) == pfx2) atomicAdd(&hist[k & 1023], 1u);
        k = okey(v.w); if ((k >> 10) == pfx2) atomicAdd(&hist[k & 1023], 1u);
      }
      __syncthreads();
      find_thr(hist, 1024, need3, t, lane, wid, wsum, &s_thr, &s_above);
      const unsigned T3 = (unsigned)s_thr;
      const unsigned needEq = need3 - s_above;
      const unsigned cntEq = hist[T3];
      L = (pfx2 << 10) | T3;                          // exact 32-bit threshold key
      if (cntEq != needEq) {
        // excess exact ties: keep the needEq smallest indices (jax tie-break)
        int prev = -1;
        for (unsigned j = 0; j < needEq; j++) {
          if (t == 0) s_imin = 0xFFFFFFFFu;
          __syncthreads();
          for (int p = 0; p < 32; p++) {
            float4 v = row4[p * 512 + t];
            int i0 = (p * 512 + t) * 4;
            unsigned k;
            k = okey(v.x); if (k == L && i0     > prev) atomicMin(&s_imin, (unsigned)i0);
            k = okey(v.y); if (k == L && i0 + 1 > prev) atomicMin(&s_imin, (unsigned)(i0 + 1));
            k = okey(v.z); if (k == L && i0 + 2 > prev) atomicMin(&s_imin, (unsigned)(i0 + 2));
            k = okey(v.w); if (k == L && i0 + 3 > prev) atomicMin(&s_imin, (unsigned)(i0 + 3));
          }
          __syncthreads();
          prev = (int)s_imin;
          __syncthreads();
        }
        istar = (unsigned)prev;
      }
    }
  }
  __syncthreads();

  // ---- final: deterministic ordered compaction of accepted indices ----
  unsigned cnt = 0;
  for (int p = 0; p < 32; p++) {
    float4 v = row4[p * 512 + t];
    unsigned i0 = (unsigned)(p * 512 + t) * 4;
    unsigned k;
    k = okey(v.x); cnt += (k > L || (k == L && i0     <= istar));
    k = okey(v.y); cnt += (k > L || (k == L && i0 + 1 <= istar));
    k = okey(v.z); cnt += (k > L || (k == L && i0 + 2 <= istar));
    k = okey(v.w); cnt += (k > L || (k == L && i0 + 3 <= istar));
  }
  unsigned pos = blk_exscan(cnt, wsum, lane, wid);
  for (int p = 0; p < 32; p++) {
    float4 v = row4[p * 512 + t];
    unsigned i0 = (unsigned)(p * 512 + t) * 4;
    unsigned k;
    k = okey(v.x); if (k > L || (k == L && i0     <= istar)) oidx[n * Kt + pos++] = (int)i0;
    k = okey(v.y); if (k > L || (k == L && i0 + 1 <= istar)) oidx[n * Kt + pos++] = (int)(i0 + 1);
    k = okey(v.z); if (k > L || (k == L && i0 + 2 <= istar)) oidx[n * Kt + pos++] = (int)(i0 + 2);
    k = okey(v.w); if (k > L || (k == L && i0 + 3 <= istar)) oidx[n * Kt + pos++] = (int)(i0 + 3);
  }
}

// =============================== host ===============================
extern "C" void kernel_launch(void* const* d_in, const int* in_sizes, int n_in,
                              void* d_out, int out_size, void* d_ws, size_t ws_size,
                              hipStream_t stream) {
  (void)in_sizes; (void)n_in; (void)out_size;
  const float* x      = (const float*)d_in[0];
  const float* mem_k  = (const float*)d_in[1];
  const float* mem_v  = (const float*)d_in[2];
  const float* sa_w[4] = {(const float*)d_in[3], (const float*)d_in[4], (const float*)d_in[5], (const float*)d_in[6]};
  const float* sa_b[4] = {(const float*)d_in[7], (const float*)d_in[8], (const float*)d_in[9], (const float*)d_in[10]};
  const float* ma_w[4] = {(const float*)d_in[11], (const float*)d_in[12], (const float*)d_in[13], (const float*)d_in[14]};
  const float* ma_b[4] = {(const float*)d_in[15], (const float*)d_in[16], (const float*)d_in[17], (const float*)d_in[18]};
  const float* ln_g[3] = {(const float*)d_in[19], (const float*)d_in[21], (const float*)d_in[23]};
  const float* ln_b[3] = {(const float*)d_in[20], (const float*)d_in[22], (const float*)d_in[24]};
  const float* fc1_w = (const float*)d_in[25];
  const float* fc1_b = (const float*)d_in[26];
  const float* fc2_w = (const float*)d_in[27];
  const float* fc2_b = (const float*)d_in[28];
  float* out = (float*)d_out;

  char* ws = (char*)d_ws;
  size_t off = 0;
  auto alloc = [&](size_t bytes) -> char* {
    char* p = ws + off;
    off = (off + bytes + 255) & ~(size_t)255;
    return p;
  };

  unsigned short* wt[8];
  for (int i = 0; i < 8; i++) wt[i] = (unsigned short*)alloc((size_t)En * En * 2);  // contiguous
  unsigned short* fc1t  = (unsigned short*)alloc((size_t)FFn * En * 2);
  unsigned short* fc2t  = (unsigned short*)alloc((size_t)En * FFn * 2);
  unsigned short* xb    = (unsigned short*)alloc((size_t)NT * En * 2);
  unsigned short* Qb    = (unsigned short*)alloc((size_t)NT * En * 2);
  unsigned short* Kb    = (unsigned short*)alloc((size_t)NT * En * 2);
  unsigned short* Vb    = (unsigned short*)alloc((size_t)NT * En * 2);
  unsigned short* at1b  = (unsigned short*)alloc((size_t)NT * En * 2);
  float*          t1    = (float*)alloc((size_t)NT * En * 4);
  float*          x1f   = (float*)alloc((size_t)NT * En * 4);
  unsigned short* x1b   = (unsigned short*)alloc((size_t)NT * En * 2);
  float*          sims  = (float*)alloc((size_t)NT * Mn * 4);          // 256 MiB
  int*            idx   = (int*)alloc((size_t)NT * Kt * 4);
  unsigned short* K2b   = (unsigned short*)alloc((size_t)NT * Kt * En * 2);  // 64 MiB
  unsigned short* V2b   = (unsigned short*)alloc((size_t)NT * Kt * En * 2);  // contiguous after K2b
  unsigned short* Q2b   = (unsigned short*)alloc((size_t)NT * En * 2);
  unsigned short* at2b  = (unsigned short*)alloc((size_t)NT * En * 2);
  float*          t2    = (float*)alloc((size_t)NT * En * 4);
  float*          x2f   = (float*)alloc((size_t)NT * En * 4);
  unsigned short* x2b   = (unsigned short*)alloc((size_t)NT * En * 2);
  unsigned short* hb    = (unsigned short*)alloc((size_t)NT * FFn * 2);
  float*          t3    = (float*)alloc((size_t)NT * En * 4);
  float*          bcat_sa = (float*)alloc(3072 * 4);
  float*          bcat_ma = (float*)alloc(2048 * 4);

  if (off > ws_size) return;   // insufficient workspace: leave output poisoned (fail loudly)

  // Overlays (dead-region reuse):
  //  mkb (normalized bf16 mem_keys, 128 MiB) lives in K2b+V2b until the sims GEMM is done.
  //  mvb (bf16 mem_vals, 128 MiB) + attn partials live in sims after topk.
  unsigned short* mkb = (unsigned short*)K2b;
  unsigned short* mvb = (unsigned short*)sims;
  float* PO = (float*)((char*)sims + (size_t)128 * 1024 * 1024);
  float* PM = PO + (size_t)1024 * 4096;
  float* PL = PM + (size_t)1024 * 64;

  // ---- prep: weight transposes to bf16 [N][K], bias concats ----
  for (int i = 0; i < 4; i++)
    k_transpose_bf16<<<dim3(16, 16), 256, 0, stream>>>(sa_w[i], wt[i], En, En);
  for (int i = 0; i < 4; i++)
    k_transpose_bf16<<<dim3(16, 16), 256, 0, stream>>>(ma_w[i], wt[4 + i], En, En);
  k_transpose_bf16<<<dim3(64, 16), 256, 0, stream>>>(fc1_w, fc1t, En, FFn);
  k_transpose_bf16<<<dim3(16, 64), 256, 0, stream>>>(fc2_w, fc2t, FFn, En);
  k_concat3<<<dim3(12), 256, 0, stream>>>(sa_b[0], sa_b[1], sa_b[2], bcat_sa);
  k_concat3<<<dim3(8),  256, 0, stream>>>(ma_b[1], ma_b[2], ma_b[2], bcat_ma);

  k_cvt_bf16<<<dim3(NT * En / 4 / 256), 256, 0, stream>>>(x, xb, NT * En / 4);
  k_normcvt<<<dim3(Mn), 256, 0, stream>>>(mem_k, mkb);

  const dim3 g1(En / 128, NT / 128);   // (8,8)

  // ---- self-attention (QKV fused: N=3072 over contiguous wt[0..2]) ----
  k_gemm<0,false,false,3><<<dim3(24, 8), 256, 0, stream>>>(xb, wt[0], nullptr, bcat_sa, nullptr, nullptr, Qb, Kb, Vb, 3072, En);
  k_attn<1><<<dim3(Sn / 64, Hn, Bn), 256, 0, stream>>>(Qb, Kb, Vb, at1b, nullptr, nullptr, nullptr, Sn);
  k_gemm<1,false,false,1><<<g1, 256, 0, stream>>>(at1b, wt[3], nullptr, sa_b[3], x, t1, nullptr, nullptr, nullptr, En, En);
  k_layernorm<<<NT, 256, 0, stream>>>(t1, ln_g[0], ln_b[0], x1f, x1b);

  // ---- retrieval: sims + radix top-k ----
  // grid (512,8): blocks sharing a B col-tile are wgid===x (mod 8) -> same XCD L2
  k_gemm<4,false,false,1><<<dim3(Mn / 128, NT / 128), 256, 0, stream>>>(x1b, mkb, nullptr, nullptr, nullptr, sims, nullptr, nullptr, nullptr, Mn, En);
  k_topk<<<NT, 512, 0, stream>>>(sims, idx);

  // ---- memory cross-attention (K2/V2 fused: N=2048 over contiguous wt[5..6]) ----
  k_cvt_bf16<<<dim3(Mn * En / 4 / 256), 256, 0, stream>>>(mem_v, mvb, Mn * En / 4);
  // SWAPG grid (256,16): blocks sharing a gathered A row-tile land on the same XCD
  k_gemm<0,true,true,2><<<dim3(256, 16), 256, 0, stream>>>(mvb, wt[5], idx, bcat_ma, nullptr, nullptr, K2b, V2b, nullptr, 2048, En);
  k_gemm<0,false,false,1><<<g1, 256, 0, stream>>>(x1b, wt[4], nullptr, ma_b[0], nullptr, nullptr, Q2b, nullptr, nullptr, En, En);
  k_attn<4><<<dim3(Sn / 64, Hn, Bn * 4), 256, 0, stream>>>(Q2b, K2b, V2b, nullptr, PO, PM, PL, Sn * Kt);
  k_attn_comb<<<dim3(Bn * Hn * Sn / 4), 256, 0, stream>>>(PO, PM, PL, at2b);
  k_gemm<1,false,false,1><<<g1, 256, 0, stream>>>(at2b, wt[7], nullptr, ma_b[3], x1f, t2, nullptr, nullptr, nullptr, En, En);
  k_layernorm<<<NT, 256, 0, stream>>>(t2, ln_g[1], ln_b[1], x2f, x2b);

  // ---- FFN ----
  k_gemm<2,false,false,1><<<dim3(FFn / 128, NT / 128), 256, 0, stream>>>(x2b, fc1t, nullptr, fc1_b, nullptr, nullptr, hb, nullptr, nullptr, FFn, En);
  k_gemm<1,false,false,1><<<g1, 256, 0, stream>>>(hb, fc2t, nullptr, fc2_b, x2f, t3, nullptr, nullptr, nullptr, En, FFn);
  k_layernorm<<<NT, 256, 0, stream>>>(t3, ln_g[2], ln_b[2], out, nullptr);
}

// Round 4
// 1228.723 us; speedup vs baseline: 1.5125x; 1.0085x over previous
//
#include <hip/hip_runtime.h>
#include <hip/hip_bf16.h>
#include <math.h>

#define DEVFN __device__ __forceinline__

typedef __attribute__((ext_vector_type(8))) short bf16x8;
typedef __attribute__((ext_vector_type(4))) float f32x4;

static constexpr int Bn = 4, Sn = 256, En = 1024, Hn = 16;
static constexpr int Mn = 65536, Kt = 32, FFn = 4096;
static constexpr int NT = Bn * Sn;           // 1024 tokens

DEVFN unsigned short f2b(float f) {          // f32 -> bf16 RNE
  unsigned int u = __float_as_uint(f);
  unsigned int r = (u + 0x7FFFu + ((u >> 16) & 1u)) >> 16;
  return (unsigned short)r;
}

DEVFN unsigned okey(float f) {               // order-preserving f32 -> u32
  unsigned u = __float_as_uint(f);
  return u ^ ((u >> 31) ? 0xFFFFFFFFu : 0x80000000u);
}

typedef const __attribute__((address_space(1))) void* as1cv_t;
typedef __attribute__((address_space(3))) void* as3v_t;
DEVFN void gload16(const void* g, void* l) {   // async global->LDS, 16B/lane
  __builtin_amdgcn_global_load_lds((as1cv_t)g, (as3v_t)l, 16, 0, 0);
}

// ---------------- transpose W[R][C] f32 -> out[C][R] bf16 ----------------
__global__ __launch_bounds__(256) void k_transpose_bf16(
    const float* __restrict__ in, unsigned short* __restrict__ out, int R, int C) {
  __shared__ float tile[64][65];
  int tx = threadIdx.x & 63, ty = threadIdx.x >> 6;
  int c0 = blockIdx.x * 64, r0 = blockIdx.y * 64;
  #pragma unroll
  for (int i = 0; i < 16; i++) {
    int r = ty + i * 4;
    tile[tx][r] = in[(size_t)(r0 + r) * C + (c0 + tx)];
  }
  __syncthreads();
  #pragma unroll
  for (int i = 0; i < 16; i++) {
    int c = ty + i * 4;
    out[(size_t)(c0 + c) * R + (r0 + tx)] = f2b(tile[c][tx]);
  }
}

// ---------------- f32 -> bf16 elementwise (x4) ----------------
__global__ __launch_bounds__(256) void k_cvt_bf16(
    const float* __restrict__ in, unsigned short* __restrict__ out, int n4) {
  int i = blockIdx.x * 256 + threadIdx.x;
  if (i >= n4) return;
  float4 v = ((const float4*)in)[i];
  uint2 o;
  o.x = (unsigned int)f2b(v.x) | ((unsigned int)f2b(v.y) << 16);
  o.y = (unsigned int)f2b(v.z) | ((unsigned int)f2b(v.w) << 16);
  ((uint2*)out)[i] = o;
}

// ---------------- concat up to 3 x 1024-f32 vectors ----------------
__global__ __launch_bounds__(256) void k_concat3(
    const float* __restrict__ a, const float* __restrict__ b,
    const float* __restrict__ c, float* __restrict__ o) {
  int i = blockIdx.x * 256 + threadIdx.x;
  float v = (i < 1024) ? a[i] : (i < 2048) ? b[i - 1024] : c[i - 2048];
  o[i] = v;
}

// ---- mem_keys row-normalize + cvt to bf16 (folds cosine norm into B) ----
__global__ __launch_bounds__(256) void k_normcvt(
    const float* __restrict__ mk, unsigned short* __restrict__ out) {
  int m = blockIdx.x, t = threadIdx.x;
  float4 v = ((const float4*)(mk + (size_t)m * En))[t];
  float ss = v.x*v.x + v.y*v.y + v.z*v.z + v.w*v.w;
  #pragma unroll
  for (int d = 32; d; d >>= 1) ss += __shfl_down(ss, d);
  __shared__ float red[4];
  int lane = t & 63, w = t >> 6;
  if (lane == 0) red[w] = ss;
  __syncthreads();
  float rs = 1.0f / fmaxf(sqrtf(red[0] + red[1] + red[2] + red[3]), 1e-12f);
  uint2 o;
  o.x = (unsigned int)f2b(v.x * rs) | ((unsigned int)f2b(v.y * rs) << 16);
  o.y = (unsigned int)f2b(v.z * rs) | ((unsigned int)f2b(v.w * rs) << 16);
  ((uint2*)(out + (size_t)m * En))[t] = o;
}

// ---------------- LayerNorm over rows of [NT][En] ----------------
__global__ __launch_bounds__(256) void k_layernorm(
    const float* __restrict__ in, const float* __restrict__ g, const float* __restrict__ bb,
    float* __restrict__ outf, unsigned short* __restrict__ outb) {
  int n = blockIdx.x, t = threadIdx.x;
  float4 v = ((const float4*)(in + (size_t)n * En))[t];
  float s  = v.x + v.y + v.z + v.w;
  float s2 = v.x*v.x + v.y*v.y + v.z*v.z + v.w*v.w;
  #pragma unroll
  for (int d = 32; d; d >>= 1) { s += __shfl_down(s, d); s2 += __shfl_down(s2, d); }
  __shared__ float rs[4], rq[4];
  int lane = t & 63, w = t >> 6;
  if (lane == 0) { rs[w] = s; rq[w] = s2; }
  __syncthreads();
  float mean = (rs[0]+rs[1]+rs[2]+rs[3]) * (1.0f/En);
  float var  = (rq[0]+rq[1]+rq[2]+rq[3]) * (1.0f/En) - mean*mean;
  float rstd = rsqrtf(var + 1e-5f);
  float4 gg = ((const float4*)g)[t];
  float4 bv = ((const float4*)bb)[t];
  float o0 = (v.x-mean)*rstd*gg.x + bv.x;
  float o1 = (v.y-mean)*rstd*gg.y + bv.y;
  float o2 = (v.z-mean)*rstd*gg.z + bv.z;
  float o3 = (v.w-mean)*rstd*gg.w + bv.w;
  if (outf) { float4 ov = {o0,o1,o2,o3}; ((float4*)(outf + (size_t)n*En))[t] = ov; }
  if (outb) {
    uint2 o;
    o.x = (unsigned int)f2b(o0) | ((unsigned int)f2b(o1) << 16);
    o.y = (unsigned int)f2b(o2) | ((unsigned int)f2b(o3) << 16);
    ((uint2*)(outb + (size_t)n*En))[t] = o;
  }
}

// ---------------- GEMM: C[M][N] = A[M][K] @ Bt[N][K]^T (+epilogue) ----------------
// EPI 0: bf16 out (+bias) | 1: f32 out (+bias+resid) | 2: GELU->bf16 (+bias) | 4: f32 out
// Staging: global_load_lds width-16 into LINEAR [128][32] LDS (m97 structure).
template<int EPI, bool AGATHER, bool SWAPG, int NOUT>
__global__ __launch_bounds__(256) void k_gemm(
    const unsigned short* __restrict__ Ab, const unsigned short* __restrict__ Bb,
    const int* __restrict__ gidx,
    const float* __restrict__ bias, const float* __restrict__ resid,
    float* __restrict__ Cf, unsigned short* __restrict__ cb0,
    unsigned short* __restrict__ cb1, unsigned short* __restrict__ cb2,
    int Ndim, int Kdim) {
  __shared__ unsigned short As[128][32];   // linear: rows are 64B, lane*16 covers 16 rows/wave-op
  __shared__ unsigned short Bs[128][32];
  const int t = threadIdx.x, lane = t & 63, w = t >> 6;
  const int wr = w >> 1, wc = w & 1, l15 = lane & 15, l4 = lane >> 4;
  const int row0 = (SWAPG ? blockIdx.x : blockIdx.y) * 128;
  const int col0 = (SWAPG ? blockIdx.y : blockIdx.x) * 128;
  const int c8  = (lane & 3) * 8;      // k-offset (shorts) this lane stages
  const int r16 = lane >> 2;           // row within a 16-row group
  const int rA0 = w * 32 + r16, rA1 = rA0 + 16;   // this thread's two staging rows

  size_t raA0, raA1, raB0, raB1;
  if constexpr (AGATHER) {
    raA0 = (size_t)gidx[row0 + rA0] * Kdim;
    raA1 = (size_t)gidx[row0 + rA1] * Kdim;
  } else {
    raA0 = (size_t)(row0 + rA0) * Kdim;
    raA1 = (size_t)(row0 + rA1) * Kdim;
  }
  raB0 = (size_t)(col0 + rA0) * Kdim;
  raB1 = (size_t)(col0 + rA1) * Kdim;

  f32x4 acc[4][4];
  #pragma unroll
  for (int i = 0; i < 4; i++)
    #pragma unroll
    for (int j = 0; j < 4; j++) acc[i][j] = (f32x4){0.f,0.f,0.f,0.f};

  for (int kt0 = 0; kt0 < Kdim; kt0 += 32) {
    __syncthreads();                    // prior iteration's readers done
    gload16(Ab + raA0 + kt0 + c8, &As[w * 32][0]);
    gload16(Ab + raA1 + kt0 + c8, &As[w * 32 + 16][0]);
    gload16(Bb + raB0 + kt0 + c8, &Bs[w * 32][0]);
    gload16(Bb + raB1 + kt0 + c8, &Bs[w * 32 + 16][0]);
    __syncthreads();                    // drains vmcnt -> LDS visible
    bf16x8 af[4], bfr[4];
    #pragma unroll
    for (int mi = 0; mi < 4; mi++) af[mi]  = *(const bf16x8*)&As[wr*64 + mi*16 + l15][l4*8];
    #pragma unroll
    for (int ni = 0; ni < 4; ni++) bfr[ni] = *(const bf16x8*)&Bs[wc*64 + ni*16 + l15][l4*8];
    #pragma unroll
    for (int mi = 0; mi < 4; mi++)
      #pragma unroll
      for (int ni = 0; ni < 4; ni++)
        acc[mi][ni] = __builtin_amdgcn_mfma_f32_16x16x32_bf16(af[mi], bfr[ni], acc[mi][ni], 0, 0, 0);
  }

  unsigned short* cbase = cb0;
  int colsub = 0;
  if constexpr (NOUT > 1) {
    int which = col0 >> 10;                       // block-uniform output select
    cbase = (which == 0) ? cb0 : (which == 1) ? cb1 : cb2;
    colsub = col0 & 1023;
  }

  #pragma unroll
  for (int mi = 0; mi < 4; mi++) {
    #pragma unroll
    for (int ni = 0; ni < 4; ni++) {
      int col  = col0 + wc*64 + ni*16 + l15;
      int rowb = row0 + wr*64 + mi*16 + l4*4;
      #pragma unroll
      for (int r = 0; r < 4; r++) {
        float v = acc[mi][ni][r];
        size_t off = (size_t)(rowb + r) * Ndim + col;
        if constexpr (EPI == 0) {
          if constexpr (NOUT > 1) {
            int c2 = colsub + wc*64 + ni*16 + l15;
            cbase[(size_t)(rowb + r) * 1024 + c2] = f2b(v + bias[col]);
          } else {
            cb0[off] = f2b(v + bias[col]);
          }
        } else if constexpr (EPI == 1) {
          Cf[off] = v + bias[col] + resid[off];
        } else if constexpr (EPI == 2) {
          float u = v + bias[col];
          u = 0.5f * u * (1.0f + erff(u * 0.70710678118654752f));
          cb0[off] = f2b(u);
        } else {
          Cf[off] = v;
        }
      }
    }
  }
}

// ---------------- fused attention (flash-style) with optional KV-split ----------------
template<int SPLIT>
__global__ __launch_bounds__(256) void k_attn(
    const unsigned short* __restrict__ Qp, const unsigned short* __restrict__ Kp,
    const unsigned short* __restrict__ Vp, unsigned short* __restrict__ Op,
    float* __restrict__ PO, float* __restrict__ PM, float* __restrict__ PL, int Lk) {
  __shared__ unsigned short Ks[64][72];
  __shared__ unsigned short Vt[64][72];   // V transposed (k-chunk XOR-swizzled by d>>3)
  __shared__ float Ps[4][16][68];         // per-wave P transpose buffer
  const int b = blockIdx.z / SPLIT, sp = blockIdx.z % SPLIT;
  const int h = blockIdx.y, q0 = blockIdx.x * 64;
  const int t = threadIdx.x, lane = t & 63, w = t >> 6;
  const int l15 = lane & 15, l4 = lane >> 4;

  const int qrow = q0 + w * 16 + l15;
  const unsigned short* qptr = Qp + (size_t)(b * Sn + qrow) * En + h * 64 + l4 * 8;
  bf16x8 qf0 = *(const bf16x8*)qptr;
  bf16x8 qf1 = *(const bf16x8*)(qptr + 32);

  f32x4 oacc[4];
  #pragma unroll
  for (int i = 0; i < 4; i++) oacc[i] = (f32x4){0.f,0.f,0.f,0.f};
  float m_[4] = {-INFINITY, -INFINITY, -INFINITY, -INFINITY};
  float l_[4] = {0.f, 0.f, 0.f, 0.f};

  const int nkt = Lk / (64 * SPLIT);
  for (int kt = sp * nkt; kt < (sp + 1) * nkt; ++kt) {
    __syncthreads();                       // protect LDS from previous iter readers
    #pragma unroll
    for (int i = 0; i < 2; i++) {
      int ld = t + i * 256;                // 0..511
      int kr = ld >> 3, d8 = (ld & 7) * 8;
      size_t base = (size_t)(b * Lk + kt * 64 + kr) * En + h * 64 + d8;
      *(uint4*)&Ks[kr][d8] = *(const uint4*)(Kp + base);
      bf16x8 vv = *(const bf16x8*)(Vp + base);
      int colswz = kr ^ ((t & 7) << 3);    // XOR-swizzle: spreads d8-groups across banks
      #pragma unroll
      for (int j = 0; j < 8; j++) Vt[d8 + j][colswz] = ((unsigned short*)&vv)[j];
    }
    __syncthreads();

    // S = Q @ K^T  (per wave: 16 q-rows x 64 k-cols)
    f32x4 s[4];
    #pragma unroll
    for (int ni = 0; ni < 4; ni++) {
      s[ni] = (f32x4){0.f,0.f,0.f,0.f};
      bf16x8 kb0 = *(const bf16x8*)&Ks[ni*16 + l15][l4*8];
      bf16x8 kb1 = *(const bf16x8*)&Ks[ni*16 + l15][l4*8 + 32];
      s[ni] = __builtin_amdgcn_mfma_f32_16x16x32_bf16(qf0, kb0, s[ni], 0, 0, 0);
      s[ni] = __builtin_amdgcn_mfma_f32_16x16x32_bf16(qf1, kb1, s[ni], 0, 0, 0);
    }

    // online softmax per q-row
    #pragma unroll
    for (int r = 0; r < 4; r++) {
      #pragma unroll
      for (int ni = 0; ni < 4; ni++) s[ni][r] *= 0.125f;
      float mx = fmaxf(fmaxf(s[0][r], s[1][r]), fmaxf(s[2][r], s[3][r]));
      #pragma unroll
      for (int d2 = 1; d2 < 16; d2 <<= 1) mx = fmaxf(mx, __shfl_xor(mx, d2));
      float mn = fmaxf(m_[r], mx);
      float alpha = expf(m_[r] - mn);
      float rsum = 0.f;
      #pragma unroll
      for (int ni = 0; ni < 4; ni++) { float p = expf(s[ni][r] - mn); s[ni][r] = p; rsum += p; }
      #pragma unroll
      for (int d2 = 1; d2 < 16; d2 <<= 1) rsum += __shfl_xor(rsum, d2);
      l_[r] = l_[r] * alpha + rsum;
      m_[r] = mn;
      #pragma unroll
      for (int nd = 0; nd < 4; nd++) oacc[nd][r] *= alpha;
    }

    // transpose P through per-wave LDS into A-frag layout
    #pragma unroll
    for (int ni = 0; ni < 4; ni++)
      #pragma unroll
      for (int r = 0; r < 4; r++)
        Ps[w][l4*4 + r][ni*16 + l15] = s[ni][r];
    asm volatile("s_waitcnt lgkmcnt(0)" ::: "memory");

    #pragma unroll
    for (int half = 0; half < 2; half++) {
      float4 pv0 = *(const float4*)&Ps[w][l15][half*32 + l4*8];
      float4 pv1 = *(const float4*)&Ps[w][l15][half*32 + l4*8 + 4];
      bf16x8 pa;
      pa[0]=(short)f2b(pv0.x); pa[1]=(short)f2b(pv0.y); pa[2]=(short)f2b(pv0.z); pa[3]=(short)f2b(pv0.w);
      pa[4]=(short)f2b(pv1.x); pa[5]=(short)f2b(pv1.y); pa[6]=(short)f2b(pv1.z); pa[7]=(short)f2b(pv1.w);
      #pragma unroll
      for (int nd = 0; nd < 4; nd++) {
        int dd = nd*16 + l15;
        bf16x8 vb = *(const bf16x8*)&Vt[dd][(half*32 + l4*8) ^ (((dd >> 3) & 7) << 3)];
        oacc[nd] = __builtin_amdgcn_mfma_f32_16x16x32_bf16(pa, vb, oacc[nd], 0, 0, 0);
      }
    }
  }

  if constexpr (SPLIT == 1) {
    #pragma unroll
    for (int nd = 0; nd < 4; nd++)
      #pragma unroll
      for (int r = 0; r < 4; r++) {
        int q = q0 + w*16 + l4*4 + r;
        Op[(size_t)(b * Sn + q) * En + h * 64 + nd*16 + l15] = f2b(oacc[nd][r] / l_[r]);
      }
  } else {
    const int slot = ((b * Hn + h) * 4 + blockIdx.x) * SPLIT + sp;
    #pragma unroll
    for (int nd = 0; nd < 4; nd++)
      #pragma unroll
      for (int r = 0; r < 4; r++)
        PO[slot * 4096 + (w*16 + l4*4 + r) * 64 + nd*16 + l15] = oacc[nd][r];
    if (l15 == 0) {
      #pragma unroll
      for (int r = 0; r < 4; r++) {
        PM[slot * 64 + w*16 + l4*4 + r] = m_[r];
        PL[slot * 64 + w*16 + l4*4 + r] = l_[r];
      }
    }
  }
}

// ---------------- combine split-K attention partials (SPLIT=4) ----------------
__global__ __launch_bounds__(256) void k_attn_comb(
    const float* __restrict__ PO, const float* __restrict__ PM,
    const float* __restrict__ PL, unsigned short* __restrict__ Op) {
  const int W = blockIdx.x * 4 + (threadIdx.x >> 6);
  const int lane = threadIdx.x & 63;
  const int bh = W >> 8, q = W & 255;
  const int qb = q >> 6, qq = q & 63;
  const int slotBase = (bh * 4 + qb) * 4;
  float ms[4];
  float M = -INFINITY;
  #pragma unroll
  for (int s = 0; s < 4; s++) { ms[s] = PM[(slotBase + s) * 64 + qq]; M = fmaxf(M, ms[s]); }
  float L = 0.f, acc = 0.f;
  #pragma unroll
  for (int s = 0; s < 4; s++) {
    float wgt = expf(ms[s] - M);
    L += PL[(slotBase + s) * 64 + qq] * wgt;
    acc += wgt * PO[(size_t)(slotBase + s) * 4096 + qq * 64 + lane];
  }
  const int b = bh >> 4, h = bh & 15;
  Op[(size_t)(b * Sn + q) * En + h * 64 + lane] = f2b(acc / L);
}

// ------------- helpers for radix top-k -------------
DEVFN unsigned blk_exscan(unsigned part, volatile unsigned* wsum, int lane, int wid) {
  unsigned v = part;
  #pragma unroll
  for (int d = 1; d < 64; d <<= 1) { unsigned o = __shfl_up(v, d); if (lane >= d) v += o; }
  if (lane == 63) wsum[wid] = v;
  __syncthreads();
  unsigned woff = 0;
  for (int i = 0; i < wid; i++) woff += wsum[i];
  unsigned r = woff + v - part;
  __syncthreads();
  return r;
}

DEVFN void find_thr(const unsigned* hist, int NB, unsigned need,
                    int t, int lane, int wid, volatile unsigned* wsum,
                    volatile int* s_thr, volatile unsigned* s_above) {
  int per = NB >> 9;                         // bins per thread (NB/512)
  int lo = NB - per * (t + 1);               // my bins, descending coverage with t
  unsigned part = 0;
  for (int j = 0; j < per; j++) part += hist[lo + j];
  unsigned ex = blk_exscan(part, wsum, lane, wid);   // keys in bins above my range
  if (ex < need && ex + part >= need) {      // crossing is in my range (unique t)
    unsigned c = ex;
    for (int j = per - 1; j >= 0; j--) {
      unsigned h = hist[lo + j];
      if (c + h >= need) { *s_thr = lo + j; *s_above = c; break; }
      c += h;
    }
  }
  __syncthreads();
}

// ---------------- exact top-32 per row via 3-level radix select ----------------
__global__ __launch_bounds__(512) void k_topk(
    const float* __restrict__ sims, int* __restrict__ oidx) {
  const int n = blockIdx.x, t = threadIdx.x;
  const int lane = t & 63, wid = t >> 6;
  const float4* row4 = (const float4*)(sims + (size_t)n * Mn);
  __shared__ unsigned hist[2048];
  __shared__ unsigned wsum[8];
  __shared__ int s_thr;
  __shared__ unsigned s_above, s_imin;

  // ---- P1: bits 31:21 ----
  for (int i = t; i < 2048; i += 512) hist[i] = 0;
  __syncthreads();
  for (int p = 0; p < 32; p++) {
    float4 v = row4[p * 512 + t];
    atomicAdd(&hist[okey(v.x) >> 21], 1u);
    atomicAdd(&hist[okey(v.y) >> 21], 1u);
    atomicAdd(&hist[okey(v.z) >> 21], 1u);
    atomicAdd(&hist[okey(v.w) >> 21], 1u);
  }
  __syncthreads();
  find_thr(hist, 2048, 32, t, lane, wid, wsum, &s_thr, &s_above);
  const unsigned T1 = (unsigned)s_thr;
  const unsigned need2 = 32 - s_above;
  const unsigned cnt1 = hist[T1];

  unsigned L = 0, istar = 0xFFFFFFFFu;
  bool done = false;
  if (cnt1 == need2) { L = T1 << 21; done = true; }   // whole bin accepted

  if (!done) {
    // ---- P2: bits 20:10 within bin T1 ----
    __syncthreads();
    for (int i = t; i < 2048; i += 512) hist[i] = 0;
    __syncthreads();
    for (int p = 0; p < 32; p++) {
      float4 v = row4[p * 512 + t];
      unsigned k;
      k = okey(v.x); if ((k >> 21) == T1) atomicAdd(&hist[(k >> 10) & 2047], 1u);
      k = okey(v.y); if ((k >> 21) == T1) atomicAdd(&hist[(k >> 10) & 2047], 1u);
      k = okey(v.z); if ((k >> 21) == T1) atomicAdd(&hist[(k >> 10) & 2047], 1u);
      k = okey(v.w); if ((k >> 21) == T1) atomicAdd(&hist[(k >> 10) & 2047], 1u);
    }
    __syncthreads();
    find_thr(hist, 2048, need2, t, lane, wid, wsum, &s_thr, &s_above);
    const unsigned T2 = (unsigned)s_thr;
    const unsigned need3 = need2 - s_above;
    const unsigned cnt2 = hist[T2];
    const unsigned pfx2 = (T1 << 11) | T2;            // top-22 bits
    if (cnt2 == need3) { L = pfx2 << 10; done = true; }

    if (!done) {
      // ---- P3: bits 9:0 within prefix pfx2 ----
      __syncthreads();
      for (int i = t; i < 2048; i += 512) hist[i] = 0;
      __syncthreads();
      for (int p = 0; p < 32; p++) {
        float4 v = row4[p * 512 + t];
        unsigned k;
        k = okey(v.x); if ((k >> 10) == pfx2) atomicAdd(&hist[k & 1023], 1u);
        k = okey(v.y); if ((k >> 10) == pfx2) atomicAdd(&hist[k & 1023], 1u);
        k = okey(v.z); if ((k >> 10) == pfx2) atomicAdd(&hist[k & 1023], 1u);
        k = okey(v.w); if ((k >> 10) == pfx2) atomicAdd(&hist[k & 1023], 1u);
      }
      __syncthreads();
      find_thr(hist, 1024, need3, t, lane, wid, wsum, &s_thr, &s_above);
      const unsigned T3 = (unsigned)s_thr;
      const unsigned needEq = need3 - s_above;
      const unsigned cntEq = hist[T3];
      L = (pfx2 << 10) | T3;                          // exact 32-bit threshold key
      if (cntEq != needEq) {
        // excess exact ties: keep the needEq smallest indices (jax tie-break)
        int prev = -1;
        for (unsigned j = 0; j < needEq; j++) {
          if (t == 0) s_imin = 0xFFFFFFFFu;
          __syncthreads();
          for (int p = 0; p < 32; p++) {
            float4 v = row4[p * 512 + t];
            int i0 = (p * 512 + t) * 4;
            unsigned k;
            k = okey(v.x); if (k == L && i0     > prev) atomicMin(&s_imin, (unsigned)i0);
            k = okey(v.y); if (k == L && i0 + 1 > prev) atomicMin(&s_imin, (unsigned)(i0 + 1));
            k = okey(v.z); if (k == L && i0 + 2 > prev) atomicMin(&s_imin, (unsigned)(i0 + 2));
            k = okey(v.w); if (k == L && i0 + 3 > prev) atomicMin(&s_imin, (unsigned)(i0 + 3));
          }
          __syncthreads();
          prev = (int)s_imin;
          __syncthreads();
        }
        istar = (unsigned)prev;
      }
    }
  }
  __syncthreads();

  // ---- final: deterministic ordered compaction of accepted indices ----
  unsigned cnt = 0;
  for (int p = 0; p < 32; p++) {
    float4 v = row4[p * 512 + t];
    unsigned i0 = (unsigned)(p * 512 + t) * 4;
    unsigned k;
    k = okey(v.x); cnt += (k > L || (k == L && i0     <= istar));
    k = okey(v.y); cnt += (k > L || (k == L && i0 + 1 <= istar));
    k = okey(v.z); cnt += (k > L || (k == L && i0 + 2 <= istar));
    k = okey(v.w); cnt += (k > L || (k == L && i0 + 3 <= istar));
  }
  unsigned pos = blk_exscan(cnt, wsum, lane, wid);
  for (int p = 0; p < 32; p++) {
    float4 v = row4[p * 512 + t];
    unsigned i0 = (unsigned)(p * 512 + t) * 4;
    unsigned k;
    k = okey(v.x); if (k > L || (k == L && i0     <= istar)) oidx[n * Kt + pos++] = (int)i0;
    k = okey(v.y); if (k > L || (k == L && i0 + 1 <= istar)) oidx[n * Kt + pos++] = (int)(i0 + 1);
    k = okey(v.z); if (k > L || (k == L && i0 + 2 <= istar)) oidx[n * Kt + pos++] = (int)(i0 + 2);
    k = okey(v.w); if (k > L || (k == L && i0 + 3 <= istar)) oidx[n * Kt + pos++] = (int)(i0 + 3);
  }
}

// =============================== host ===============================
extern "C" void kernel_launch(void* const* d_in, const int* in_sizes, int n_in,
                              void* d_out, int out_size, void* d_ws, size_t ws_size,
                              hipStream_t stream) {
  (void)in_sizes; (void)n_in; (void)out_size;
  const float* x      = (const float*)d_in[0];
  const float* mem_k  = (const float*)d_in[1];
  const float* mem_v  = (const float*)d_in[2];
  const float* sa_w[4] = {(const float*)d_in[3], (const float*)d_in[4], (const float*)d_in[5], (const float*)d_in[6]};
  const float* sa_b[4] = {(const float*)d_in[7], (const float*)d_in[8], (const float*)d_in[9], (const float*)d_in[10]};
  const float* ma_w[4] = {(const float*)d_in[11], (const float*)d_in[12], (const float*)d_in[13], (const float*)d_in[14]};
  const float* ma_b[4] = {(const float*)d_in[15], (const float*)d_in[16], (const float*)d_in[17], (const float*)d_in[18]};
  const float* ln_g[3] = {(const float*)d_in[19], (const float*)d_in[21], (const float*)d_in[23]};
  const float* ln_b[3] = {(const float*)d_in[20], (const float*)d_in[22], (const float*)d_in[24]};
  const float* fc1_w = (const float*)d_in[25];
  const float* fc1_b = (const float*)d_in[26];
  const float* fc2_w = (const float*)d_in[27];
  const float* fc2_b = (const float*)d_in[28];
  float* out = (float*)d_out;

  char* ws = (char*)d_ws;
  size_t off = 0;
  auto alloc = [&](size_t bytes) -> char* {
    char* p = ws + off;
    off = (off + bytes + 255) & ~(size_t)255;
    return p;
  };

  unsigned short* wt[8];
  for (int i = 0; i < 8; i++) wt[i] = (unsigned short*)alloc((size_t)En * En * 2);  // contiguous
  unsigned short* fc1t  = (unsigned short*)alloc((size_t)FFn * En * 2);
  unsigned short* fc2t  = (unsigned short*)alloc((size_t)En * FFn * 2);
  unsigned short* xb    = (unsigned short*)alloc((size_t)NT * En * 2);
  unsigned short* Qb    = (unsigned short*)alloc((size_t)NT * En * 2);
  unsigned short* Kb    = (unsigned short*)alloc((size_t)NT * En * 2);
  unsigned short* Vb    = (unsigned short*)alloc((size_t)NT * En * 2);
  unsigned short* at1b  = (unsigned short*)alloc((size_t)NT * En * 2);
  float*          t1    = (float*)alloc((size_t)NT * En * 4);
  float*          x1f   = (float*)alloc((size_t)NT * En * 4);
  unsigned short* x1b   = (unsigned short*)alloc((size_t)NT * En * 2);
  float*          sims  = (float*)alloc((size_t)NT * Mn * 4);          // 256 MiB
  int*            idx   = (int*)alloc((size_t)NT * Kt * 4);
  unsigned short* K2b   = (unsigned short*)alloc((size_t)NT * Kt * En * 2);  // 64 MiB
  unsigned short* V2b   = (unsigned short*)alloc((size_t)NT * Kt * En * 2);  // contiguous after K2b
  unsigned short* Q2b   = (unsigned short*)alloc((size_t)NT * En * 2);
  unsigned short* at2b  = (unsigned short*)alloc((size_t)NT * En * 2);
  float*          t2    = (float*)alloc((size_t)NT * En * 4);
  float*          x2f   = (float*)alloc((size_t)NT * En * 4);
  unsigned short* x2b   = (unsigned short*)alloc((size_t)NT * En * 2);
  unsigned short* hb    = (unsigned short*)alloc((size_t)NT * FFn * 2);
  float*          t3    = (float*)alloc((size_t)NT * En * 4);
  float*          bcat_sa = (float*)alloc(3072 * 4);
  float*          bcat_ma = (float*)alloc(2048 * 4);

  if (off > ws_size) return;   // insufficient workspace: leave output poisoned (fail loudly)

  // Overlays (dead-region reuse):
  //  mkb (normalized bf16 mem_keys, 128 MiB) lives in K2b+V2b until the sims GEMM is done.
  //  mvb (bf16 mem_vals, 128 MiB) + attn partials live in sims after topk.
  unsigned short* mkb = (unsigned short*)K2b;
  unsigned short* mvb = (unsigned short*)sims;
  float* PO = (float*)((char*)sims + (size_t)128 * 1024 * 1024);
  float* PM = PO + (size_t)1024 * 4096;
  float* PL = PM + (size_t)1024 * 64;

  // ---- prep: weight transposes to bf16 [N][K], bias concats ----
  for (int i = 0; i < 4; i++)
    k_transpose_bf16<<<dim3(16, 16), 256, 0, stream>>>(sa_w[i], wt[i], En, En);
  for (int i = 0; i < 4; i++)
    k_transpose_bf16<<<dim3(16, 16), 256, 0, stream>>>(ma_w[i], wt[4 + i], En, En);
  k_transpose_bf16<<<dim3(64, 16), 256, 0, stream>>>(fc1_w, fc1t, En, FFn);
  k_transpose_bf16<<<dim3(16, 64), 256, 0, stream>>>(fc2_w, fc2t, FFn, En);
  k_concat3<<<dim3(12), 256, 0, stream>>>(sa_b[0], sa_b[1], sa_b[2], bcat_sa);
  k_concat3<<<dim3(8),  256, 0, stream>>>(ma_b[1], ma_b[2], ma_b[2], bcat_ma);

  k_cvt_bf16<<<dim3(NT * En / 4 / 256), 256, 0, stream>>>(x, xb, NT * En / 4);
  k_normcvt<<<dim3(Mn), 256, 0, stream>>>(mem_k, mkb);

  const dim3 g1(En / 128, NT / 128);   // (8,8)

  // ---- self-attention (QKV fused: N=3072 over contiguous wt[0..2]) ----
  k_gemm<0,false,false,3><<<dim3(24, 8), 256, 0, stream>>>(xb, wt[0], nullptr, bcat_sa, nullptr, nullptr, Qb, Kb, Vb, 3072, En);
  k_attn<1><<<dim3(Sn / 64, Hn, Bn), 256, 0, stream>>>(Qb, Kb, Vb, at1b, nullptr, nullptr, nullptr, Sn);
  k_gemm<1,false,false,1><<<g1, 256, 0, stream>>>(at1b, wt[3], nullptr, sa_b[3], x, t1, nullptr, nullptr, nullptr, En, En);
  k_layernorm<<<NT, 256, 0, stream>>>(t1, ln_g[0], ln_b[0], x1f, x1b);

  // ---- retrieval: sims + radix top-k ----
  // SWAPG grid (8,512): the 8 row-tile sharers of each B col-tile are dispatch-consecutive
  // -> concurrent across XCDs -> B served ~once from HBM (rest L3 hits)
  k_gemm<4,false,true,1><<<dim3(NT / 128, Mn / 128), 256, 0, stream>>>(x1b, mkb, nullptr, nullptr, nullptr, sims, nullptr, nullptr, nullptr, Mn, En);
  k_topk<<<NT, 512, 0, stream>>>(sims, idx);

  // ---- memory cross-attention (K2/V2 fused: N=2048 over contiguous wt[5..6]) ----
  k_cvt_bf16<<<dim3(Mn * En / 4 / 256), 256, 0, stream>>>(mem_v, mvb, Mn * En / 4);
  // grid (16,256): the 16 col-tile sharers of each gathered A row-tile are consecutive
  k_gemm<0,true,false,2><<<dim3(16, 256), 256, 0, stream>>>(mvb, wt[5], idx, bcat_ma, nullptr, nullptr, K2b, V2b, nullptr, 2048, En);
  k_gemm<0,false,false,1><<<g1, 256, 0, stream>>>(x1b, wt[4], nullptr, ma_b[0], nullptr, nullptr, Q2b, nullptr, nullptr, En, En);
  k_attn<4><<<dim3(Sn / 64, Hn, Bn * 4), 256, 0, stream>>>(Q2b, K2b, V2b, nullptr, PO, PM, PL, Sn * Kt);
  k_attn_comb<<<dim3(Bn * Hn * Sn / 4), 256, 0, stream>>>(PO, PM, PL, at2b);
  k_gemm<1,false,false,1><<<g1, 256, 0, stream>>>(at2b, wt[7], nullptr, ma_b[3], x1f, t2, nullptr, nullptr, nullptr, En, En);
  k_layernorm<<<NT, 256, 0, stream>>>(t2, ln_g[1], ln_b[1], x2f, x2b);

  // ---- FFN ----
  k_gemm<2,false,false,1><<<dim3(FFn / 128, NT / 128), 256, 0, stream>>>(x2b, fc1t, nullptr, fc1_b, nullptr, nullptr, hb, nullptr, nullptr, FFn, En);
  k_gemm<1,false,false,1><<<g1, 256, 0, stream>>>(hb, fc2t, nullptr, fc2_b, x2f, t3, nullptr, nullptr, nullptr, En, FFn);
  k_layernorm<<<NT, 256, 0, stream>>>(t3, ln_g[2], ln_b[2], out, nullptr);
}

// Round 5
// 1130.822 us; speedup vs baseline: 1.6435x; 1.0866x over previous
//
#include <hip/hip_runtime.h>
#include <hip/hip_bf16.h>
#include <math.h>

#define DEVFN __device__ __forceinline__

typedef __attribute__((ext_vector_type(8))) short bf16x8;
typedef __attribute__((ext_vector_type(4))) float f32x4;

static constexpr int Bn = 4, Sn = 256, En = 1024, Hn = 16;
static constexpr int Mn = 65536, Kt = 32, FFn = 4096;
static constexpr int NT = Bn * Sn;           // 1024 tokens

DEVFN unsigned short f2b(float f) {          // f32 -> bf16 RNE
  unsigned int u = __float_as_uint(f);
  unsigned int r = (u + 0x7FFFu + ((u >> 16) & 1u)) >> 16;
  return (unsigned short)r;
}

DEVFN unsigned okey(float f) {               // order-preserving f32 -> u32
  unsigned u = __float_as_uint(f);
  return u ^ ((u >> 31) ? 0xFFFFFFFFu : 0x80000000u);
}

typedef const __attribute__((address_space(1))) void* as1cv_t;
typedef __attribute__((address_space(3))) void* as3v_t;
DEVFN void gload16(const void* g, void* l) {   // async global->LDS, 16B/lane
  __builtin_amdgcn_global_load_lds((as1cv_t)g, (as3v_t)l, 16, 0, 0);
}

// ---------------- transpose W[R][C] f32 -> out[C][R] bf16 ----------------
__global__ __launch_bounds__(256) void k_transpose_bf16(
    const float* __restrict__ in, unsigned short* __restrict__ out, int R, int C) {
  __shared__ float tile[64][65];
  int tx = threadIdx.x & 63, ty = threadIdx.x >> 6;
  int c0 = blockIdx.x * 64, r0 = blockIdx.y * 64;
  #pragma unroll
  for (int i = 0; i < 16; i++) {
    int r = ty + i * 4;
    tile[tx][r] = in[(size_t)(r0 + r) * C + (c0 + tx)];
  }
  __syncthreads();
  #pragma unroll
  for (int i = 0; i < 16; i++) {
    int c = ty + i * 4;
    out[(size_t)(c0 + c) * R + (r0 + tx)] = f2b(tile[c][tx]);
  }
}

// ---------------- f32 -> bf16 elementwise (x4) ----------------
__global__ __launch_bounds__(256) void k_cvt_bf16(
    const float* __restrict__ in, unsigned short* __restrict__ out, int n4) {
  int i = blockIdx.x * 256 + threadIdx.x;
  if (i >= n4) return;
  float4 v = ((const float4*)in)[i];
  uint2 o;
  o.x = (unsigned int)f2b(v.x) | ((unsigned int)f2b(v.y) << 16);
  o.y = (unsigned int)f2b(v.z) | ((unsigned int)f2b(v.w) << 16);
  ((uint2*)out)[i] = o;
}

// ---------------- concat up to 3 x 1024-f32 vectors ----------------
__global__ __launch_bounds__(256) void k_concat3(
    const float* __restrict__ a, const float* __restrict__ b,
    const float* __restrict__ c, float* __restrict__ o) {
  int i = blockIdx.x * 256 + threadIdx.x;
  float v = (i < 1024) ? a[i] : (i < 2048) ? b[i - 1024] : c[i - 2048];
  o[i] = v;
}

// ---- mem_keys row-normalize + cvt to bf16 (folds cosine norm into B) ----
__global__ __launch_bounds__(256) void k_normcvt(
    const float* __restrict__ mk, unsigned short* __restrict__ out) {
  int m = blockIdx.x, t = threadIdx.x;
  float4 v = ((const float4*)(mk + (size_t)m * En))[t];
  float ss = v.x*v.x + v.y*v.y + v.z*v.z + v.w*v.w;
  #pragma unroll
  for (int d = 32; d; d >>= 1) ss += __shfl_down(ss, d);
  __shared__ float red[4];
  int lane = t & 63, w = t >> 6;
  if (lane == 0) red[w] = ss;
  __syncthreads();
  float rs = 1.0f / fmaxf(sqrtf(red[0] + red[1] + red[2] + red[3]), 1e-12f);
  uint2 o;
  o.x = (unsigned int)f2b(v.x * rs) | ((unsigned int)f2b(v.y * rs) << 16);
  o.y = (unsigned int)f2b(v.z * rs) | ((unsigned int)f2b(v.w * rs) << 16);
  ((uint2*)(out + (size_t)m * En))[t] = o;
}

// ---------------- LayerNorm over rows of [NT][En] ----------------
__global__ __launch_bounds__(256) void k_layernorm(
    const float* __restrict__ in, const float* __restrict__ g, const float* __restrict__ bb,
    float* __restrict__ outf, unsigned short* __restrict__ outb) {
  int n = blockIdx.x, t = threadIdx.x;
  float4 v = ((const float4*)(in + (size_t)n * En))[t];
  float s  = v.x + v.y + v.z + v.w;
  float s2 = v.x*v.x + v.y*v.y + v.z*v.z + v.w*v.w;
  #pragma unroll
  for (int d = 32; d; d >>= 1) { s += __shfl_down(s, d); s2 += __shfl_down(s2, d); }
  __shared__ float rs[4], rq[4];
  int lane = t & 63, w = t >> 6;
  if (lane == 0) { rs[w] = s; rq[w] = s2; }
  __syncthreads();
  float mean = (rs[0]+rs[1]+rs[2]+rs[3]) * (1.0f/En);
  float var  = (rq[0]+rq[1]+rq[2]+rq[3]) * (1.0f/En) - mean*mean;
  float rstd = rsqrtf(var + 1e-5f);
  float4 gg = ((const float4*)g)[t];
  float4 bv = ((const float4*)bb)[t];
  float o0 = (v.x-mean)*rstd*gg.x + bv.x;
  float o1 = (v.y-mean)*rstd*gg.y + bv.y;
  float o2 = (v.z-mean)*rstd*gg.z + bv.z;
  float o3 = (v.w-mean)*rstd*gg.w + bv.w;
  if (outf) { float4 ov = {o0,o1,o2,o3}; ((float4*)(outf + (size_t)n*En))[t] = ov; }
  if (outb) {
    uint2 o;
    o.x = (unsigned int)f2b(o0) | ((unsigned int)f2b(o1) << 16);
    o.y = (unsigned int)f2b(o2) | ((unsigned int)f2b(o3) << 16);
    ((uint2*)(outb + (size_t)n*En))[t] = o;
  }
}

// ======== 256x256xBK64 8-phase GEMM (T1+T2+T3+T4+T5), C = A @ Bt^T ========
// EPI 4: f32 out | EPI 0 + NOUT2: bf16 out (+bias), split N into 1024-wide cb0/cb1
// LDS: dynamic 128 KiB: [buf2][A|B][ks2][256 rows][32 bf16] (64B rows, st_16x32 swizzle)
template<int EPI, bool AGATHER, int NOUT, int LSWZ>
__global__ __launch_bounds__(512) void k_gemm256(
    const unsigned short* __restrict__ Ab, const unsigned short* __restrict__ Bb,
    const int* __restrict__ gidx, const float* __restrict__ bias,
    float* __restrict__ Cf, unsigned short* __restrict__ cb0, unsigned short* __restrict__ cb1,
    int Ndim, int Kdim, int nRT, int nCT) {
  extern __shared__ unsigned short lds[];
  const int t = threadIdx.x, lane = t & 63, w = t >> 6;
  const int wr = w >> 2, wc = w & 3, l15 = lane & 15, l4 = lane >> 4;
  const int lr2 = lane >> 2;
  const int cg  = (lane & 3) ^ (((lane >> 5) & 1) << 1);   // source pre-swizzle (involution)

  // bijective chunked XCD map: XCD x gets logical ids [x*(nwg/8), ...)
  const int nwg = nRT * nCT;
  int lb = ((int)blockIdx.x % 8) * (nwg >> 3) + ((int)blockIdx.x >> 3);
  int rowT, colT;
  if (LSWZ == 0) { rowT = lb % nRT; colT = lb / nRT; }   // col-tile sharers adjacent
  else           { colT = lb % nCT; rowT = lb / nCT; }   // row-tile sharers adjacent
  const int row0 = rowT * 256, col0 = colT * 256;

  auto pA = [&](int buf, int ks) -> unsigned short* { return lds + buf * 32768 + ks * 8192; };
  auto pB = [&](int buf, int ks) -> unsigned short* { return lds + buf * 32768 + 16384 + ks * 8192; };

  // per-thread staging sources (row via lr2, col-group pre-swizzled via cg)
  const unsigned short *aSrc0, *aSrc1;
  if constexpr (AGATHER) {
    aSrc0 = Ab + (size_t)gidx[row0 + w * 32 + lr2] * Kdim + cg * 8;
    aSrc1 = Ab + (size_t)gidx[row0 + w * 32 + 16 + lr2] * Kdim + cg * 8;
  } else {
    aSrc0 = Ab + (size_t)(row0 + w * 32 + lr2) * Kdim + cg * 8;
    aSrc1 = aSrc0 + (size_t)16 * Kdim;
  }
  const unsigned short* bSrc0 = Bb + (size_t)(col0 + w * 32 + lr2) * Kdim + cg * 8;
  const unsigned short* bSrc1 = bSrc0 + (size_t)16 * Kdim;

  f32x4 acc[8][4];
  #pragma unroll
  for (int i = 0; i < 8; i++)
    #pragma unroll
    for (int j = 0; j < 4; j++) acc[i][j] = (f32x4){0.f, 0.f, 0.f, 0.f};

  // prologue: stage K-tile 0 into buf0 (8 wave-issues of 1KiB)
  gload16(aSrc0,      pA(0,0) + w*32*32);       gload16(aSrc0 + 32, pA(0,1) + w*32*32);
  gload16(aSrc1,      pA(0,0) + (w*32+16)*32);  gload16(aSrc1 + 32, pA(0,1) + (w*32+16)*32);
  gload16(bSrc0,      pB(0,0) + w*32*32);       gload16(bSrc0 + 32, pB(0,1) + w*32*32);
  gload16(bSrc1,      pB(0,0) + (w*32+16)*32);  gload16(bSrc1 + 32, pB(0,1) + (w*32+16)*32);

  const int NKT = Kdim >> 6;
  for (int tk = 0; tk < NKT; ++tk) {
    const int cur = tk & 1, nxt = cur ^ 1;
    const bool pf = (tk + 1) < NKT;
    const int ktn = (tk + 1) * 64;
    // K-tile boundary: all gloads for buf[cur] complete (only place vmcnt drains)
    asm volatile("s_waitcnt vmcnt(0)" ::: "memory");
    __builtin_amdgcn_s_barrier();
    asm volatile("" ::: "memory");

    bf16x8 bfr[4];
    #pragma unroll
    for (int ph = 0; ph < 4; ++ph) {
      const int ks = ph >> 1, half = ph & 1;
      const unsigned short* Ap = pA(cur, ks);
      const unsigned short* Bp = pB(cur, ks);
      bf16x8 af[4];
      if (half == 0) {
        #pragma unroll
        for (int ni = 0; ni < 4; ni++) {
          int row = wc * 64 + ni * 16 + l15;
          int c8 = l4 ^ (((row >> 3) & 1) << 1);          // st_16x32 read swizzle
          bfr[ni] = *(const bf16x8*)&Bp[row * 32 + c8 * 8];
        }
      }
      #pragma unroll
      for (int m = 0; m < 4; m++) {
        int row = wr * 128 + (half * 4 + m) * 16 + l15;
        int c8 = l4 ^ (((row >> 3) & 1) << 1);
        af[m] = *(const bf16x8*)&Ap[row * 32 + c8 * 8];
      }
      if (pf) {  // stage 1 half-tile of K-tile tk+1 (2 gloads), spread over 4 phases
        if (ph == 0) { gload16(aSrc0 + ktn, pA(nxt,0) + w*32*32);      gload16(aSrc0 + ktn + 32, pA(nxt,1) + w*32*32); }
        if (ph == 1) { gload16(aSrc1 + ktn, pA(nxt,0) + (w*32+16)*32); gload16(aSrc1 + ktn + 32, pA(nxt,1) + (w*32+16)*32); }
        if (ph == 2) { gload16(bSrc0 + ktn, pB(nxt,0) + w*32*32);      gload16(bSrc0 + ktn + 32, pB(nxt,1) + w*32*32); }
        if (ph == 3) { gload16(bSrc1 + ktn, pB(nxt,0) + (w*32+16)*32); gload16(bSrc1 + ktn + 32, pB(nxt,1) + (w*32+16)*32); }
      }
      asm volatile("" ::: "memory");
      __builtin_amdgcn_s_barrier();           // raw barrier: no vmcnt drain
      asm volatile("" ::: "memory");
      __builtin_amdgcn_s_setprio(1);
      #pragma unroll
      for (int m = 0; m < 4; m++)
        #pragma unroll
        for (int ni = 0; ni < 4; ni++)
          acc[half * 4 + m][ni] = __builtin_amdgcn_mfma_f32_16x16x32_bf16(af[m], bfr[ni], acc[half * 4 + m][ni], 0, 0, 0);
      __builtin_amdgcn_s_setprio(0);
      asm volatile("" ::: "memory");
      __builtin_amdgcn_s_barrier();
      asm volatile("" ::: "memory");
    }
  }

  #pragma unroll
  for (int m = 0; m < 8; m++) {
    #pragma unroll
    for (int ni = 0; ni < 4; ni++) {
      int col  = col0 + wc * 64 + ni * 16 + l15;
      int rowb = row0 + wr * 128 + m * 16 + l4 * 4;
      #pragma unroll
      for (int r = 0; r < 4; r++) {
        float v = acc[m][ni][r];
        if constexpr (EPI == 4) {
          Cf[(size_t)(rowb + r) * Ndim + col] = v;
        } else {
          unsigned short* cb = (col >> 10) ? cb1 : cb0;
          cb[(size_t)(rowb + r) * 1024 + (col & 1023)] = f2b(v + bias[col]);
        }
      }
    }
  }
}

// ---------------- GEMM 128x128 (2-phase) for the small GEMMs ----------------
// EPI 0: bf16 out (+bias) | 1: f32 out (+bias+resid) | 2: GELU->bf16 (+bias) | 4: f32 out
template<int EPI, bool AGATHER, bool SWAPG, int NOUT>
__global__ __launch_bounds__(256) void k_gemm(
    const unsigned short* __restrict__ Ab, const unsigned short* __restrict__ Bb,
    const int* __restrict__ gidx,
    const float* __restrict__ bias, const float* __restrict__ resid,
    float* __restrict__ Cf, unsigned short* __restrict__ cb0,
    unsigned short* __restrict__ cb1, unsigned short* __restrict__ cb2,
    int Ndim, int Kdim) {
  __shared__ unsigned short As[128][32];
  __shared__ unsigned short Bs[128][32];
  const int t = threadIdx.x, lane = t & 63, w = t >> 6;
  const int wr = w >> 1, wc = w & 1, l15 = lane & 15, l4 = lane >> 4;
  const int row0 = (SWAPG ? blockIdx.x : blockIdx.y) * 128;
  const int col0 = (SWAPG ? blockIdx.y : blockIdx.x) * 128;
  const int c8  = (lane & 3) * 8;
  const int r16 = lane >> 2;
  const int rA0 = w * 32 + r16, rA1 = rA0 + 16;

  size_t raA0, raA1, raB0, raB1;
  if constexpr (AGATHER) {
    raA0 = (size_t)gidx[row0 + rA0] * Kdim;
    raA1 = (size_t)gidx[row0 + rA1] * Kdim;
  } else {
    raA0 = (size_t)(row0 + rA0) * Kdim;
    raA1 = (size_t)(row0 + rA1) * Kdim;
  }
  raB0 = (size_t)(col0 + rA0) * Kdim;
  raB1 = (size_t)(col0 + rA1) * Kdim;

  f32x4 acc[4][4];
  #pragma unroll
  for (int i = 0; i < 4; i++)
    #pragma unroll
    for (int j = 0; j < 4; j++) acc[i][j] = (f32x4){0.f,0.f,0.f,0.f};

  for (int kt0 = 0; kt0 < Kdim; kt0 += 32) {
    __syncthreads();
    gload16(Ab + raA0 + kt0 + c8, &As[w * 32][0]);
    gload16(Ab + raA1 + kt0 + c8, &As[w * 32 + 16][0]);
    gload16(Bb + raB0 + kt0 + c8, &Bs[w * 32][0]);
    gload16(Bb + raB1 + kt0 + c8, &Bs[w * 32 + 16][0]);
    __syncthreads();
    bf16x8 af[4], bfr[4];
    #pragma unroll
    for (int mi = 0; mi < 4; mi++) af[mi]  = *(const bf16x8*)&As[wr*64 + mi*16 + l15][l4*8];
    #pragma unroll
    for (int ni = 0; ni < 4; ni++) bfr[ni] = *(const bf16x8*)&Bs[wc*64 + ni*16 + l15][l4*8];
    #pragma unroll
    for (int mi = 0; mi < 4; mi++)
      #pragma unroll
      for (int ni = 0; ni < 4; ni++)
        acc[mi][ni] = __builtin_amdgcn_mfma_f32_16x16x32_bf16(af[mi], bfr[ni], acc[mi][ni], 0, 0, 0);
  }

  unsigned short* cbase = cb0;
  int colsub = 0;
  if constexpr (NOUT > 1) {
    int which = col0 >> 10;
    cbase = (which == 0) ? cb0 : (which == 1) ? cb1 : cb2;
    colsub = col0 & 1023;
  }

  #pragma unroll
  for (int mi = 0; mi < 4; mi++) {
    #pragma unroll
    for (int ni = 0; ni < 4; ni++) {
      int col  = col0 + wc*64 + ni*16 + l15;
      int rowb = row0 + wr*64 + mi*16 + l4*4;
      #pragma unroll
      for (int r = 0; r < 4; r++) {
        float v = acc[mi][ni][r];
        size_t off = (size_t)(rowb + r) * Ndim + col;
        if constexpr (EPI == 0) {
          if constexpr (NOUT > 1) {
            int c2 = colsub + wc*64 + ni*16 + l15;
            cbase[(size_t)(rowb + r) * 1024 + c2] = f2b(v + bias[col]);
          } else {
            cb0[off] = f2b(v + bias[col]);
          }
        } else if constexpr (EPI == 1) {
          Cf[off] = v + bias[col] + resid[off];
        } else if constexpr (EPI == 2) {
          float u = v + bias[col];
          u = 0.5f * u * (1.0f + erff(u * 0.70710678118654752f));
          cb0[off] = f2b(u);
        } else {
          Cf[off] = v;
        }
      }
    }
  }
}

// ---------------- fused attention (flash-style) with optional KV-split ----------------
template<int SPLIT>
__global__ __launch_bounds__(256) void k_attn(
    const unsigned short* __restrict__ Qp, const unsigned short* __restrict__ Kp,
    const unsigned short* __restrict__ Vp, unsigned short* __restrict__ Op,
    float* __restrict__ PO, float* __restrict__ PM, float* __restrict__ PL, int Lk) {
  __shared__ unsigned short Ks[64][72];
  __shared__ unsigned short Vt[64][72];   // V transposed (k-chunk XOR-swizzled by d>>3)
  __shared__ float Ps[4][16][68];         // per-wave P transpose buffer
  const int b = blockIdx.z / SPLIT, sp = blockIdx.z % SPLIT;
  const int h = blockIdx.y, q0 = blockIdx.x * 64;
  const int t = threadIdx.x, lane = t & 63, w = t >> 6;
  const int l15 = lane & 15, l4 = lane >> 4;

  const int qrow = q0 + w * 16 + l15;
  const unsigned short* qptr = Qp + (size_t)(b * Sn + qrow) * En + h * 64 + l4 * 8;
  bf16x8 qf0 = *(const bf16x8*)qptr;
  bf16x8 qf1 = *(const bf16x8*)(qptr + 32);

  f32x4 oacc[4];
  #pragma unroll
  for (int i = 0; i < 4; i++) oacc[i] = (f32x4){0.f,0.f,0.f,0.f};
  float m_[4] = {-INFINITY, -INFINITY, -INFINITY, -INFINITY};
  float l_[4] = {0.f, 0.f, 0.f, 0.f};

  const int nkt = Lk / (64 * SPLIT);
  for (int kt = sp * nkt; kt < (sp + 1) * nkt; ++kt) {
    __syncthreads();
    #pragma unroll
    for (int i = 0; i < 2; i++) {
      int ld = t + i * 256;
      int kr = ld >> 3, d8 = (ld & 7) * 8;
      size_t base = (size_t)(b * Lk + kt * 64 + kr) * En + h * 64 + d8;
      *(uint4*)&Ks[kr][d8] = *(const uint4*)(Kp + base);
      bf16x8 vv = *(const bf16x8*)(Vp + base);
      int colswz = kr ^ ((t & 7) << 3);
      #pragma unroll
      for (int j = 0; j < 8; j++) Vt[d8 + j][colswz] = ((unsigned short*)&vv)[j];
    }
    __syncthreads();

    f32x4 s[4];
    #pragma unroll
    for (int ni = 0; ni < 4; ni++) {
      s[ni] = (f32x4){0.f,0.f,0.f,0.f};
      bf16x8 kb0 = *(const bf16x8*)&Ks[ni*16 + l15][l4*8];
      bf16x8 kb1 = *(const bf16x8*)&Ks[ni*16 + l15][l4*8 + 32];
      s[ni] = __builtin_amdgcn_mfma_f32_16x16x32_bf16(qf0, kb0, s[ni], 0, 0, 0);
      s[ni] = __builtin_amdgcn_mfma_f32_16x16x32_bf16(qf1, kb1, s[ni], 0, 0, 0);
    }

    #pragma unroll
    for (int r = 0; r < 4; r++) {
      #pragma unroll
      for (int ni = 0; ni < 4; ni++) s[ni][r] *= 0.125f;
      float mx = fmaxf(fmaxf(s[0][r], s[1][r]), fmaxf(s[2][r], s[3][r]));
      #pragma unroll
      for (int d2 = 1; d2 < 16; d2 <<= 1) mx = fmaxf(mx, __shfl_xor(mx, d2));
      float mn = fmaxf(m_[r], mx);
      float alpha = expf(m_[r] - mn);
      float rsum = 0.f;
      #pragma unroll
      for (int ni = 0; ni < 4; ni++) { float p = expf(s[ni][r] - mn); s[ni][r] = p; rsum += p; }
      #pragma unroll
      for (int d2 = 1; d2 < 16; d2 <<= 1) rsum += __shfl_xor(rsum, d2);
      l_[r] = l_[r] * alpha + rsum;
      m_[r] = mn;
      #pragma unroll
      for (int nd = 0; nd < 4; nd++) oacc[nd][r] *= alpha;
    }

    #pragma unroll
    for (int ni = 0; ni < 4; ni++)
      #pragma unroll
      for (int r = 0; r < 4; r++)
        Ps[w][l4*4 + r][ni*16 + l15] = s[ni][r];
    asm volatile("s_waitcnt lgkmcnt(0)" ::: "memory");

    #pragma unroll
    for (int half = 0; half < 2; half++) {
      float4 pv0 = *(const float4*)&Ps[w][l15][half*32 + l4*8];
      float4 pv1 = *(const float4*)&Ps[w][l15][half*32 + l4*8 + 4];
      bf16x8 pa;
      pa[0]=(short)f2b(pv0.x); pa[1]=(short)f2b(pv0.y); pa[2]=(short)f2b(pv0.z); pa[3]=(short)f2b(pv0.w);
      pa[4]=(short)f2b(pv1.x); pa[5]=(short)f2b(pv1.y); pa[6]=(short)f2b(pv1.z); pa[7]=(short)f2b(pv1.w);
      #pragma unroll
      for (int nd = 0; nd < 4; nd++) {
        int dd = nd*16 + l15;
        bf16x8 vb = *(const bf16x8*)&Vt[dd][(half*32 + l4*8) ^ (((dd >> 3) & 7) << 3)];
        oacc[nd] = __builtin_amdgcn_mfma_f32_16x16x32_bf16(pa, vb, oacc[nd], 0, 0, 0);
      }
    }
  }

  if constexpr (SPLIT == 1) {
    #pragma unroll
    for (int nd = 0; nd < 4; nd++)
      #pragma unroll
      for (int r = 0; r < 4; r++) {
        int q = q0 + w*16 + l4*4 + r;
        Op[(size_t)(b * Sn + q) * En + h * 64 + nd*16 + l15] = f2b(oacc[nd][r] / l_[r]);
      }
  } else {
    const int slot = ((b * Hn + h) * 4 + blockIdx.x) * SPLIT + sp;
    #pragma unroll
    for (int nd = 0; nd < 4; nd++)
      #pragma unroll
      for (int r = 0; r < 4; r++)
        PO[slot * 4096 + (w*16 + l4*4 + r) * 64 + nd*16 + l15] = oacc[nd][r];
    if (l15 == 0) {
      #pragma unroll
      for (int r = 0; r < 4; r++) {
        PM[slot * 64 + w*16 + l4*4 + r] = m_[r];
        PL[slot * 64 + w*16 + l4*4 + r] = l_[r];
      }
    }
  }
}

// ---------------- combine split-K attention partials (SPLIT=4) ----------------
__global__ __launch_bounds__(256) void k_attn_comb(
    const float* __restrict__ PO, const float* __restrict__ PM,
    const float* __restrict__ PL, unsigned short* __restrict__ Op) {
  const int W = blockIdx.x * 4 + (threadIdx.x >> 6);
  const int lane = threadIdx.x & 63;
  const int bh = W >> 8, q = W & 255;
  const int qb = q >> 6, qq = q & 63;
  const int slotBase = (bh * 4 + qb) * 4;
  float ms[4];
  float M = -INFINITY;
  #pragma unroll
  for (int s = 0; s < 4; s++) { ms[s] = PM[(slotBase + s) * 64 + qq]; M = fmaxf(M, ms[s]); }
  float L = 0.f, acc = 0.f;
  #pragma unroll
  for (int s = 0; s < 4; s++) {
    float wgt = expf(ms[s] - M);
    L += PL[(slotBase + s) * 64 + qq] * wgt;
    acc += wgt * PO[(size_t)(slotBase + s) * 4096 + qq * 64 + lane];
  }
  const int b = bh >> 4, h = bh & 15;
  Op[(size_t)(b * Sn + q) * En + h * 64 + lane] = f2b(acc / L);
}

// ------------- helpers for radix top-k -------------
DEVFN unsigned blk_exscan(unsigned part, volatile unsigned* wsum, int lane, int wid) {
  unsigned v = part;
  #pragma unroll
  for (int d = 1; d < 64; d <<= 1) { unsigned o = __shfl_up(v, d); if (lane >= d) v += o; }
  if (lane == 63) wsum[wid] = v;
  __syncthreads();
  unsigned woff = 0;
  for (int i = 0; i < wid; i++) woff += wsum[i];
  unsigned r = woff + v - part;
  __syncthreads();
  return r;
}

DEVFN void find_thr(const unsigned* hist, int NB, unsigned need,
                    int t, int lane, int wid, volatile unsigned* wsum,
                    volatile int* s_thr, volatile unsigned* s_above) {
  int per = NB >> 9;
  int lo = NB - per * (t + 1);
  unsigned part = 0;
  for (int j = 0; j < per; j++) part += hist[lo + j];
  unsigned ex = blk_exscan(part, wsum, lane, wid);
  if (ex < need && ex + part >= need) {
    unsigned c = ex;
    for (int j = per - 1; j >= 0; j--) {
      unsigned h = hist[lo + j];
      if (c + h >= need) { *s_thr = lo + j; *s_above = c; break; }
      c += h;
    }
  }
  __syncthreads();
}

// ---------------- exact top-32 per row via 3-level radix select ----------------
__global__ __launch_bounds__(512) void k_topk(
    const float* __restrict__ sims, int* __restrict__ oidx) {
  const int n = blockIdx.x, t = threadIdx.x;
  const int lane = t & 63, wid = t >> 6;
  const float4* row4 = (const float4*)(sims + (size_t)n * Mn);
  __shared__ unsigned hist[2048];
  __shared__ unsigned wsum[8];
  __shared__ int s_thr;
  __shared__ unsigned s_above, s_imin;

  for (int i = t; i < 2048; i += 512) hist[i] = 0;
  __syncthreads();
  for (int p = 0; p < 32; p++) {
    float4 v = row4[p * 512 + t];
    atomicAdd(&hist[okey(v.x) >> 21], 1u);
    atomicAdd(&hist[okey(v.y) >> 21], 1u);
    atomicAdd(&hist[okey(v.z) >> 21], 1u);
    atomicAdd(&hist[okey(v.w) >> 21], 1u);
  }
  __syncthreads();
  find_thr(hist, 2048, 32, t, lane, wid, wsum, &s_thr, &s_above);
  const unsigned T1 = (unsigned)s_thr;
  const unsigned need2 = 32 - s_above;
  const unsigned cnt1 = hist[T1];

  unsigned L = 0, istar = 0xFFFFFFFFu;
  bool done = false;
  if (cnt1 == need2) { L = T1 << 21; done = true; }

  if (!done) {
    __syncthreads();
    for (int i = t; i < 2048; i += 512) hist[i] = 0;
    __syncthreads();
    for (int p = 0; p < 32; p++) {
      float4 v = row4[p * 512 + t];
      unsigned k;
      k = okey(v.x); if ((k >> 21) == T1) atomicAdd(&hist[(k >> 10) & 2047], 1u);
      k = okey(v.y); if ((k >> 21) == T1) atomicAdd(&hist[(k >> 10) & 2047], 1u);
      k = okey(v.z); if ((k >> 21) == T1) atomicAdd(&hist[(k >> 10) & 2047], 1u);
      k = okey(v.w); if ((k >> 21) == T1) atomicAdd(&hist[(k >> 10) & 2047], 1u);
    }
    __syncthreads();
    find_thr(hist, 2048, need2, t, lane, wid, wsum, &s_thr, &s_above);
    const unsigned T2 = (unsigned)s_thr;
    const unsigned need3 = need2 - s_above;
    const unsigned cnt2 = hist[T2];
    const unsigned pfx2 = (T1 << 11) | T2;
    if (cnt2 == need3) { L = pfx2 << 10; done = true; }

    if (!done) {
      __syncthreads();
      for (int i = t; i < 2048; i += 512) hist[i] = 0;
      __syncthreads();
      for (int p = 0; p < 32; p++) {
        float4 v = row4[p * 512 + t];
        unsigned k;
        k = okey(v.x); if ((k >> 10) == pfx2) atomicAdd(&hist[k & 1023], 1u);
        k = okey(v.y); if ((k >> 10) == pfx2) atomicAdd(&hist[k & 1023], 1u);
        k = okey(v.z); if ((k >> 10) == pfx2) atomicAdd(&hist[k & 1023], 1u);
        k = okey(v.w); if ((k >> 10) == pfx2) atomicAdd(&hist[k & 1023], 1u);
      }
      __syncthreads();
      find_thr(hist, 1024, need3, t, lane, wid, wsum, &s_thr, &s_above);
      const unsigned T3 = (unsigned)s_thr;
      const unsigned needEq = need3 - s_above;
      const unsigned cntEq = hist[T3];
      L = (pfx2 << 10) | T3;
      if (cntEq != needEq) {
        int prev = -1;
        for (unsigned j = 0; j < needEq; j++) {
          if (t == 0) s_imin = 0xFFFFFFFFu;
          __syncthreads();
          for (int p = 0; p < 32; p++) {
            float4 v = row4[p * 512 + t];
            int i0 = (p * 512 + t) * 4;
            unsigned k;
            k = okey(v.x); if (k == L && i0     > prev) atomicMin(&s_imin, (unsigned)i0);
            k = okey(v.y); if (k == L && i0 + 1 > prev) atomicMin(&s_imin, (unsigned)(i0 + 1));
            k = okey(v.z); if (k == L && i0 + 2 > prev) atomicMin(&s_imin, (unsigned)(i0 + 2));
            k = okey(v.w); if (k == L && i0 + 3 > prev) atomicMin(&s_imin, (unsigned)(i0 + 3));
          }
          __syncthreads();
          prev = (int)s_imin;
          __syncthreads();
        }
        istar = (unsigned)prev;
      }
    }
  }
  __syncthreads();

  unsigned cnt = 0;
  for (int p = 0; p < 32; p++) {
    float4 v = row4[p * 512 + t];
    unsigned i0 = (unsigned)(p * 512 + t) * 4;
    unsigned k;
    k = okey(v.x); cnt += (k > L || (k == L && i0     <= istar));
    k = okey(v.y); cnt += (k > L || (k == L && i0 + 1 <= istar));
    k = okey(v.z); cnt += (k > L || (k == L && i0 + 2 <= istar));
    k = okey(v.w); cnt += (k > L || (k == L && i0 + 3 <= istar));
  }
  unsigned pos = blk_exscan(cnt, wsum, lane, wid);
  for (int p = 0; p < 32; p++) {
    float4 v = row4[p * 512 + t];
    unsigned i0 = (unsigned)(p * 512 + t) * 4;
    unsigned k;
    k = okey(v.x); if (k > L || (k == L && i0     <= istar)) oidx[n * Kt + pos++] = (int)i0;
    k = okey(v.y); if (k > L || (k == L && i0 + 1 <= istar)) oidx[n * Kt + pos++] = (int)(i0 + 1);
    k = okey(v.z); if (k > L || (k == L && i0 + 2 <= istar)) oidx[n * Kt + pos++] = (int)(i0 + 2);
    k = okey(v.w); if (k > L || (k == L && i0 + 3 <= istar)) oidx[n * Kt + pos++] = (int)(i0 + 3);
  }
}

// =============================== host ===============================
extern "C" void kernel_launch(void* const* d_in, const int* in_sizes, int n_in,
                              void* d_out, int out_size, void* d_ws, size_t ws_size,
                              hipStream_t stream) {
  (void)in_sizes; (void)n_in; (void)out_size;
  const float* x      = (const float*)d_in[0];
  const float* mem_k  = (const float*)d_in[1];
  const float* mem_v  = (const float*)d_in[2];
  const float* sa_w[4] = {(const float*)d_in[3], (const float*)d_in[4], (const float*)d_in[5], (const float*)d_in[6]};
  const float* sa_b[4] = {(const float*)d_in[7], (const float*)d_in[8], (const float*)d_in[9], (const float*)d_in[10]};
  const float* ma_w[4] = {(const float*)d_in[11], (const float*)d_in[12], (const float*)d_in[13], (const float*)d_in[14]};
  const float* ma_b[4] = {(const float*)d_in[15], (const float*)d_in[16], (const float*)d_in[17], (const float*)d_in[18]};
  const float* ln_g[3] = {(const float*)d_in[19], (const float*)d_in[21], (const float*)d_in[23]};
  const float* ln_b[3] = {(const float*)d_in[20], (const float*)d_in[22], (const float*)d_in[24]};
  const float* fc1_w = (const float*)d_in[25];
  const float* fc1_b = (const float*)d_in[26];
  const float* fc2_w = (const float*)d_in[27];
  const float* fc2_b = (const float*)d_in[28];
  float* out = (float*)d_out;

  char* ws = (char*)d_ws;
  size_t off = 0;
  auto alloc = [&](size_t bytes) -> char* {
    char* p = ws + off;
    off = (off + bytes + 255) & ~(size_t)255;
    return p;
  };

  unsigned short* wt[8];
  for (int i = 0; i < 8; i++) wt[i] = (unsigned short*)alloc((size_t)En * En * 2);  // contiguous
  unsigned short* fc1t  = (unsigned short*)alloc((size_t)FFn * En * 2);
  unsigned short* fc2t  = (unsigned short*)alloc((size_t)En * FFn * 2);
  unsigned short* xb    = (unsigned short*)alloc((size_t)NT * En * 2);
  unsigned short* Qb    = (unsigned short*)alloc((size_t)NT * En * 2);
  unsigned short* Kb    = (unsigned short*)alloc((size_t)NT * En * 2);
  unsigned short* Vb    = (unsigned short*)alloc((size_t)NT * En * 2);
  unsigned short* at1b  = (unsigned short*)alloc((size_t)NT * En * 2);
  float*          t1    = (float*)alloc((size_t)NT * En * 4);
  float*          x1f   = (float*)alloc((size_t)NT * En * 4);
  unsigned short* x1b   = (unsigned short*)alloc((size_t)NT * En * 2);
  float*          sims  = (float*)alloc((size_t)NT * Mn * 4);          // 256 MiB
  int*            idx   = (int*)alloc((size_t)NT * Kt * 4);
  unsigned short* K2b   = (unsigned short*)alloc((size_t)NT * Kt * En * 2);  // 64 MiB
  unsigned short* V2b   = (unsigned short*)alloc((size_t)NT * Kt * En * 2);  // contiguous after K2b
  unsigned short* Q2b   = (unsigned short*)alloc((size_t)NT * En * 2);
  unsigned short* at2b  = (unsigned short*)alloc((size_t)NT * En * 2);
  float*          t2    = (float*)alloc((size_t)NT * En * 4);
  float*          x2f   = (float*)alloc((size_t)NT * En * 4);
  unsigned short* x2b   = (unsigned short*)alloc((size_t)NT * En * 2);
  unsigned short* hb    = (unsigned short*)alloc((size_t)NT * FFn * 2);
  float*          t3    = (float*)alloc((size_t)NT * En * 4);
  float*          bcat_sa = (float*)alloc(3072 * 4);
  float*          bcat_ma = (float*)alloc(2048 * 4);

  if (off > ws_size) return;   // insufficient workspace: leave output poisoned (fail loudly)

  // Overlays (dead-region reuse):
  unsigned short* mkb = (unsigned short*)K2b;
  unsigned short* mvb = (unsigned short*)sims;
  float* PO = (float*)((char*)sims + (size_t)128 * 1024 * 1024);
  float* PM = PO + (size_t)1024 * 4096;
  float* PL = PM + (size_t)1024 * 64;

  // allow 128 KiB dynamic LDS for the 256^2 kernels (best effort)
  (void)hipFuncSetAttribute((const void*)&k_gemm256<4,false,1,0>,
                            hipFuncAttributeMaxDynamicSharedMemorySize, 131072);
  (void)hipFuncSetAttribute((const void*)&k_gemm256<0,true,2,1>,
                            hipFuncAttributeMaxDynamicSharedMemorySize, 131072);

  // ---- prep: weight transposes to bf16 [N][K], bias concats ----
  for (int i = 0; i < 4; i++)
    k_transpose_bf16<<<dim3(16, 16), 256, 0, stream>>>(sa_w[i], wt[i], En, En);
  for (int i = 0; i < 4; i++)
    k_transpose_bf16<<<dim3(16, 16), 256, 0, stream>>>(ma_w[i], wt[4 + i], En, En);
  k_transpose_bf16<<<dim3(64, 16), 256, 0, stream>>>(fc1_w, fc1t, En, FFn);
  k_transpose_bf16<<<dim3(16, 64), 256, 0, stream>>>(fc2_w, fc2t, FFn, En);
  k_concat3<<<dim3(12), 256, 0, stream>>>(sa_b[0], sa_b[1], sa_b[2], bcat_sa);
  k_concat3<<<dim3(8),  256, 0, stream>>>(ma_b[1], ma_b[2], ma_b[2], bcat_ma);

  k_cvt_bf16<<<dim3(NT * En / 4 / 256), 256, 0, stream>>>(x, xb, NT * En / 4);
  k_normcvt<<<dim3(Mn), 256, 0, stream>>>(mem_k, mkb);

  const dim3 g1(En / 128, NT / 128);   // (8,8)

  // ---- self-attention (QKV fused: N=3072 over contiguous wt[0..2]) ----
  k_gemm<0,false,false,3><<<dim3(24, 8), 256, 0, stream>>>(xb, wt[0], nullptr, bcat_sa, nullptr, nullptr, Qb, Kb, Vb, 3072, En);
  k_attn<1><<<dim3(Sn / 64, Hn, Bn), 256, 0, stream>>>(Qb, Kb, Vb, at1b, nullptr, nullptr, nullptr, Sn);
  k_gemm<1,false,false,1><<<g1, 256, 0, stream>>>(at1b, wt[3], nullptr, sa_b[3], x, t1, nullptr, nullptr, nullptr, En, En);
  k_layernorm<<<NT, 256, 0, stream>>>(t1, ln_g[0], ln_b[0], x1f, x1b);

  // ---- retrieval: sims (256^2 8-phase) + radix top-k ----
  k_gemm256<4,false,1,0><<<dim3(1024), 512, 131072, stream>>>(
      x1b, mkb, nullptr, nullptr, sims, nullptr, nullptr, Mn, En, NT / 256, Mn / 256);
  k_topk<<<NT, 512, 0, stream>>>(sims, idx);

  // ---- memory cross-attention (K2/V2 fused 256^2 8-phase over contiguous wt[5..6]) ----
  k_cvt_bf16<<<dim3(Mn * En / 4 / 256), 256, 0, stream>>>(mem_v, mvb, Mn * En / 4);
  k_gemm256<0,true,2,1><<<dim3(1024), 512, 131072, stream>>>(
      mvb, wt[5], idx, bcat_ma, nullptr, K2b, V2b, 2048, En, NT * Kt / 256, 2048 / 256);
  k_gemm<0,false,false,1><<<g1, 256, 0, stream>>>(x1b, wt[4], nullptr, ma_b[0], nullptr, nullptr, Q2b, nullptr, nullptr, En, En);
  k_attn<4><<<dim3(Sn / 64, Hn, Bn * 4), 256, 0, stream>>>(Q2b, K2b, V2b, nullptr, PO, PM, PL, Sn * Kt);
  k_attn_comb<<<dim3(Bn * Hn * Sn / 4), 256, 0, stream>>>(PO, PM, PL, at2b);
  k_gemm<1,false,false,1><<<g1, 256, 0, stream>>>(at2b, wt[7], nullptr, ma_b[3], x1f, t2, nullptr, nullptr, nullptr, En, En);
  k_layernorm<<<NT, 256, 0, stream>>>(t2, ln_g[1], ln_b[1], x2f, x2b);

  // ---- FFN ----
  k_gemm<2,false,false,1><<<dim3(FFn / 128, NT / 128), 256, 0, stream>>>(x2b, fc1t, nullptr, fc1_b, nullptr, nullptr, hb, nullptr, nullptr, FFn, En);
  k_gemm<1,false,false,1><<<g1, 256, 0, stream>>>(hb, fc2t, nullptr, fc2_b, x2f, t3, nullptr, nullptr, nullptr, En, FFn);
  k_layernorm<<<NT, 256, 0, stream>>>(t3, ln_g[2], ln_b[2], out, nullptr);
}

// Round 6
// 1118.567 us; speedup vs baseline: 1.6615x; 1.0110x over previous
//
#include <hip/hip_runtime.h>
#include <hip/hip_bf16.h>
#include <math.h>

#define DEVFN __device__ __forceinline__

typedef __attribute__((ext_vector_type(8))) short bf16x8;
typedef __attribute__((ext_vector_type(4))) float f32x4;

static constexpr int Bn = 4, Sn = 256, En = 1024, Hn = 16;
static constexpr int Mn = 65536, Kt = 32, FFn = 4096;
static constexpr int NT = Bn * Sn;           // 1024 tokens

DEVFN unsigned short f2b(float f) {          // f32 -> bf16 RNE
  unsigned int u = __float_as_uint(f);
  unsigned int r = (u + 0x7FFFu + ((u >> 16) & 1u)) >> 16;
  return (unsigned short)r;
}

DEVFN unsigned okey(float f) {               // order-preserving f32 -> u32
  unsigned u = __float_as_uint(f);
  return u ^ ((u >> 31) ? 0xFFFFFFFFu : 0x80000000u);
}

typedef const __attribute__((address_space(1))) void* as1cv_t;
typedef __attribute__((address_space(3))) void* as3v_t;
DEVFN void gload16(const void* g, void* l) {   // async global->LDS, 16B/lane
  __builtin_amdgcn_global_load_lds((as1cv_t)g, (as3v_t)l, 16, 0, 0);
}
#define MEMFENCE asm volatile("" ::: "memory")

// ---------------- transpose W[R][C] f32 -> out[C][R] bf16 ----------------
__global__ __launch_bounds__(256) void k_transpose_bf16(
    const float* __restrict__ in, unsigned short* __restrict__ out, int R, int C) {
  __shared__ float tile[64][65];
  int tx = threadIdx.x & 63, ty = threadIdx.x >> 6;
  int c0 = blockIdx.x * 64, r0 = blockIdx.y * 64;
  #pragma unroll
  for (int i = 0; i < 16; i++) {
    int r = ty + i * 4;
    tile[tx][r] = in[(size_t)(r0 + r) * C + (c0 + tx)];
  }
  __syncthreads();
  #pragma unroll
  for (int i = 0; i < 16; i++) {
    int c = ty + i * 4;
    out[(size_t)(c0 + c) * R + (r0 + tx)] = f2b(tile[c][tx]);
  }
}

// ---------------- f32 -> bf16 elementwise (x4) ----------------
__global__ __launch_bounds__(256) void k_cvt_bf16(
    const float* __restrict__ in, unsigned short* __restrict__ out, int n4) {
  int i = blockIdx.x * 256 + threadIdx.x;
  if (i >= n4) return;
  float4 v = ((const float4*)in)[i];
  uint2 o;
  o.x = (unsigned int)f2b(v.x) | ((unsigned int)f2b(v.y) << 16);
  o.y = (unsigned int)f2b(v.z) | ((unsigned int)f2b(v.w) << 16);
  ((uint2*)out)[i] = o;
}

// ---------------- concat up to 3 x 1024-f32 vectors ----------------
__global__ __launch_bounds__(256) void k_concat3(
    const float* __restrict__ a, const float* __restrict__ b,
    const float* __restrict__ c, float* __restrict__ o) {
  int i = blockIdx.x * 256 + threadIdx.x;
  float v = (i < 1024) ? a[i] : (i < 2048) ? b[i - 1024] : c[i - 2048];
  o[i] = v;
}

// ---- mem_keys row-normalize + cvt to bf16 (folds cosine norm into B) ----
__global__ __launch_bounds__(256) void k_normcvt(
    const float* __restrict__ mk, unsigned short* __restrict__ out) {
  int m = blockIdx.x, t = threadIdx.x;
  float4 v = ((const float4*)(mk + (size_t)m * En))[t];
  float ss = v.x*v.x + v.y*v.y + v.z*v.z + v.w*v.w;
  #pragma unroll
  for (int d = 32; d; d >>= 1) ss += __shfl_down(ss, d);
  __shared__ float red[4];
  int lane = t & 63, w = t >> 6;
  if (lane == 0) red[w] = ss;
  __syncthreads();
  float rs = 1.0f / fmaxf(sqrtf(red[0] + red[1] + red[2] + red[3]), 1e-12f);
  uint2 o;
  o.x = (unsigned int)f2b(v.x * rs) | ((unsigned int)f2b(v.y * rs) << 16);
  o.y = (unsigned int)f2b(v.z * rs) | ((unsigned int)f2b(v.w * rs) << 16);
  ((uint2*)(out + (size_t)m * En))[t] = o;
}

// ---------------- LayerNorm over rows of [NT][En] ----------------
__global__ __launch_bounds__(256) void k_layernorm(
    const float* __restrict__ in, const float* __restrict__ g, const float* __restrict__ bb,
    float* __restrict__ outf, unsigned short* __restrict__ outb) {
  int n = blockIdx.x, t = threadIdx.x;
  float4 v = ((const float4*)(in + (size_t)n * En))[t];
  float s  = v.x + v.y + v.z + v.w;
  float s2 = v.x*v.x + v.y*v.y + v.z*v.z + v.w*v.w;
  #pragma unroll
  for (int d = 32; d; d >>= 1) { s += __shfl_down(s, d); s2 += __shfl_down(s2, d); }
  __shared__ float rs[4], rq[4];
  int lane = t & 63, w = t >> 6;
  if (lane == 0) { rs[w] = s; rq[w] = s2; }
  __syncthreads();
  float mean = (rs[0]+rs[1]+rs[2]+rs[3]) * (1.0f/En);
  float var  = (rq[0]+rq[1]+rq[2]+rq[3]) * (1.0f/En) - mean*mean;
  float rstd = rsqrtf(var + 1e-5f);
  float4 gg = ((const float4*)g)[t];
  float4 bv = ((const float4*)bb)[t];
  float o0 = (v.x-mean)*rstd*gg.x + bv.x;
  float o1 = (v.y-mean)*rstd*gg.y + bv.y;
  float o2 = (v.z-mean)*rstd*gg.z + bv.z;
  float o3 = (v.w-mean)*rstd*gg.w + bv.w;
  if (outf) { float4 ov = {o0,o1,o2,o3}; ((float4*)(outf + (size_t)n*En))[t] = ov; }
  if (outb) {
    uint2 o;
    o.x = (unsigned int)f2b(o0) | ((unsigned int)f2b(o1) << 16);
    o.y = (unsigned int)f2b(o2) | ((unsigned int)f2b(o3) << 16);
    ((uint2*)(outb + (size_t)n*En))[t] = o;
  }
}

// ======== 256x256 GEMM, 4 half-tile ring buffers + counted vmcnt (T1..T5) ========
// EPI 4: f32 out | EPI 0 + NOUT2: bf16 out (+bias), split N into 1024-wide cb0/cb1
// LDS 128 KiB: 4 half-buffers x (A[256][32] + B[256][32]) bf16, st_16x32 swizzle.
// K advances in 32-wide halves; prefetch distance 3 halves; vmcnt(8) steady-state.
template<int EPI, bool AGATHER, int NOUT, int LSWZ>
__global__ __launch_bounds__(512) void k_gemm256(
    const unsigned short* __restrict__ Ab, const unsigned short* __restrict__ Bb,
    const int* __restrict__ gidx, const float* __restrict__ bias,
    float* __restrict__ Cf, unsigned short* __restrict__ cb0, unsigned short* __restrict__ cb1,
    int Ndim, int Kdim, int nRT, int nCT) {
  extern __shared__ unsigned short lds[];
  const int t = threadIdx.x, lane = t & 63, w = t >> 6;
  const int wr = w >> 2, wc = w & 3, l15 = lane & 15, l4 = lane >> 4;
  const int lr2 = lane >> 2;
  const int cg  = (lane & 3) ^ (((lane >> 5) & 1) << 1);   // source pre-swizzle (involution)

  // bijective chunked XCD map: XCD x gets logical ids [x*(nwg/8), ...)
  const int nwg = nRT * nCT;
  int lb = ((int)blockIdx.x % 8) * (nwg >> 3) + ((int)blockIdx.x >> 3);
  int rowT, colT;
  if (LSWZ == 0) { rowT = lb % nRT; colT = lb / nRT; }   // col-tile sharers adjacent
  else           { colT = lb % nCT; rowT = lb / nCT; }   // row-tile sharers adjacent
  const int row0 = rowT * 256, col0 = colT * 256;

  auto pa = [&](int h) -> unsigned short* { return lds + h * 16384; };
  auto pb = [&](int h) -> unsigned short* { return lds + h * 16384 + 8192; };

  // per-thread staging sources (row via lr2, col-group pre-swizzled via cg)
  const unsigned short *aSrc0, *aSrc1;
  if constexpr (AGATHER) {
    aSrc0 = Ab + (size_t)gidx[row0 + w * 32 + lr2] * Kdim + cg * 8;
    aSrc1 = Ab + (size_t)gidx[row0 + w * 32 + 16 + lr2] * Kdim + cg * 8;
  } else {
    aSrc0 = Ab + (size_t)(row0 + w * 32 + lr2) * Kdim + cg * 8;
    aSrc1 = aSrc0 + (size_t)16 * Kdim;
  }
  const unsigned short* bSrc0 = Bb + (size_t)(col0 + w * 32 + lr2) * Kdim + cg * 8;
  const unsigned short* bSrc1 = bSrc0 + (size_t)16 * Kdim;

  f32x4 acc[8][4];
  #pragma unroll
  for (int i = 0; i < 8; i++)
    #pragma unroll
    for (int j = 0; j < 4; j++) acc[i][j] = (f32x4){0.f, 0.f, 0.f, 0.f};

  const int NH = Kdim >> 5;                 // K half-tiles of 32
  // prologue: stage halves 0,1,2 (4 loads each, hs-grouped issue order)
  #pragma unroll
  for (int h = 0; h < 3; ++h) {
    const int ko = h * 32;
    gload16(aSrc0 + ko, pa(h) + w*32*32);
    gload16(aSrc1 + ko, pa(h) + (w*32+16)*32);
    gload16(bSrc0 + ko, pb(h) + w*32*32);
    gload16(bSrc1 + ko, pb(h) + (w*32+16)*32);
  }
  asm volatile("s_waitcnt vmcnt(8)" ::: "memory");   // half 0 landed
  __builtin_amdgcn_s_barrier();
  MEMFENCE;

  for (int hs = 0; hs < NH; ++hs) {
    const int cur = hs & 3;
    const unsigned short* Ap = pa(cur);
    const unsigned short* Bp = pb(cur);
    const int h3 = (hs + 3) & 3, ko3 = (hs + 3) * 32;
    const bool pf = (hs + 3) < NH;
    bf16x8 bfr[4], af[4];

    // ---- phase 0: B frags + A rows 0..63 of wave's 128 ----
    #pragma unroll
    for (int ni = 0; ni < 4; ni++) {
      int row = wc * 64 + ni * 16 + l15;
      int c8 = l4 ^ (((row >> 3) & 1) << 1);
      bfr[ni] = *(const bf16x8*)&Bp[row * 32 + c8 * 8];
    }
    #pragma unroll
    for (int m = 0; m < 4; m++) {
      int row = wr * 128 + m * 16 + l15;
      int c8 = l4 ^ (((row >> 3) & 1) << 1);
      af[m] = *(const bf16x8*)&Ap[row * 32 + c8 * 8];
    }
    if (pf) {
      gload16(aSrc0 + ko3, pa(h3) + w*32*32);
      gload16(aSrc1 + ko3, pa(h3) + (w*32+16)*32);
    }
    MEMFENCE; __builtin_amdgcn_s_barrier(); MEMFENCE;
    __builtin_amdgcn_s_setprio(1);
    #pragma unroll
    for (int m = 0; m < 4; m++)
      #pragma unroll
      for (int ni = 0; ni < 4; ni++)
        acc[m][ni] = __builtin_amdgcn_mfma_f32_16x16x32_bf16(af[m], bfr[ni], acc[m][ni], 0, 0, 0);
    __builtin_amdgcn_s_setprio(0);
    MEMFENCE; __builtin_amdgcn_s_barrier(); MEMFENCE;

    // ---- phase 1: A rows 64..127 ----
    #pragma unroll
    for (int m = 0; m < 4; m++) {
      int row = wr * 128 + (4 + m) * 16 + l15;
      int c8 = l4 ^ (((row >> 3) & 1) << 1);
      af[m] = *(const bf16x8*)&Ap[row * 32 + c8 * 8];
    }
    if (pf) {
      gload16(bSrc0 + ko3, pb(h3) + w*32*32);
      gload16(bSrc1 + ko3, pb(h3) + (w*32+16)*32);
    }
    MEMFENCE; __builtin_amdgcn_s_barrier(); MEMFENCE;
    __builtin_amdgcn_s_setprio(1);
    #pragma unroll
    for (int m = 0; m < 4; m++)
      #pragma unroll
      for (int ni = 0; ni < 4; ni++)
        acc[4 + m][ni] = __builtin_amdgcn_mfma_f32_16x16x32_bf16(af[m], bfr[ni], acc[4 + m][ni], 0, 0, 0);
    __builtin_amdgcn_s_setprio(0);

    // ---- boundary: counted wait for half hs+1, merged with phase-end barrier ----
    if (hs + 1 < NH) {
      const int rem = NH - 2 - hs;          // prefetched halves beyond hs+1
      if (rem >= 2)      asm volatile("s_waitcnt vmcnt(8)" ::: "memory");
      else if (rem == 1) asm volatile("s_waitcnt vmcnt(4)" ::: "memory");
      else               asm volatile("s_waitcnt vmcnt(0)" ::: "memory");
      __builtin_amdgcn_s_barrier();
      MEMFENCE;
    }
  }

  #pragma unroll
  for (int m = 0; m < 8; m++) {
    #pragma unroll
    for (int ni = 0; ni < 4; ni++) {
      int col  = col0 + wc * 64 + ni * 16 + l15;
      int rowb = row0 + wr * 128 + m * 16 + l4 * 4;
      #pragma unroll
      for (int r = 0; r < 4; r++) {
        float v = acc[m][ni][r];
        if constexpr (EPI == 4) {
          Cf[(size_t)(rowb + r) * Ndim + col] = v;
        } else {
          unsigned short* cb = (col >> 10) ? cb1 : cb0;
          cb[(size_t)(rowb + r) * 1024 + (col & 1023)] = f2b(v + bias[col]);
        }
      }
    }
  }
}

// ---------------- GEMM 128x128 (2-phase) for the small GEMMs ----------------
// EPI 0: bf16 out (+bias) | 1: f32 out (+bias+resid) | 2: GELU->bf16 (+bias) | 4: f32 out
template<int EPI, bool AGATHER, bool SWAPG, int NOUT>
__global__ __launch_bounds__(256) void k_gemm(
    const unsigned short* __restrict__ Ab, const unsigned short* __restrict__ Bb,
    const int* __restrict__ gidx,
    const float* __restrict__ bias, const float* __restrict__ resid,
    float* __restrict__ Cf, unsigned short* __restrict__ cb0,
    unsigned short* __restrict__ cb1, unsigned short* __restrict__ cb2,
    int Ndim, int Kdim) {
  __shared__ unsigned short As[128][32];
  __shared__ unsigned short Bs[128][32];
  const int t = threadIdx.x, lane = t & 63, w = t >> 6;
  const int wr = w >> 1, wc = w & 1, l15 = lane & 15, l4 = lane >> 4;
  const int row0 = (SWAPG ? blockIdx.x : blockIdx.y) * 128;
  const int col0 = (SWAPG ? blockIdx.y : blockIdx.x) * 128;
  const int c8  = (lane & 3) * 8;
  const int r16 = lane >> 2;
  const int rA0 = w * 32 + r16, rA1 = rA0 + 16;

  size_t raA0, raA1, raB0, raB1;
  if constexpr (AGATHER) {
    raA0 = (size_t)gidx[row0 + rA0] * Kdim;
    raA1 = (size_t)gidx[row0 + rA1] * Kdim;
  } else {
    raA0 = (size_t)(row0 + rA0) * Kdim;
    raA1 = (size_t)(row0 + rA1) * Kdim;
  }
  raB0 = (size_t)(col0 + rA0) * Kdim;
  raB1 = (size_t)(col0 + rA1) * Kdim;

  f32x4 acc[4][4];
  #pragma unroll
  for (int i = 0; i < 4; i++)
    #pragma unroll
    for (int j = 0; j < 4; j++) acc[i][j] = (f32x4){0.f,0.f,0.f,0.f};

  for (int kt0 = 0; kt0 < Kdim; kt0 += 32) {
    __syncthreads();
    gload16(Ab + raA0 + kt0 + c8, &As[w * 32][0]);
    gload16(Ab + raA1 + kt0 + c8, &As[w * 32 + 16][0]);
    gload16(Bb + raB0 + kt0 + c8, &Bs[w * 32][0]);
    gload16(Bb + raB1 + kt0 + c8, &Bs[w * 32 + 16][0]);
    __syncthreads();
    bf16x8 af[4], bfr[4];
    #pragma unroll
    for (int mi = 0; mi < 4; mi++) af[mi]  = *(const bf16x8*)&As[wr*64 + mi*16 + l15][l4*8];
    #pragma unroll
    for (int ni = 0; ni < 4; ni++) bfr[ni] = *(const bf16x8*)&Bs[wc*64 + ni*16 + l15][l4*8];
    #pragma unroll
    for (int mi = 0; mi < 4; mi++)
      #pragma unroll
      for (int ni = 0; ni < 4; ni++)
        acc[mi][ni] = __builtin_amdgcn_mfma_f32_16x16x32_bf16(af[mi], bfr[ni], acc[mi][ni], 0, 0, 0);
  }

  unsigned short* cbase = cb0;
  int colsub = 0;
  if constexpr (NOUT > 1) {
    int which = col0 >> 10;
    cbase = (which == 0) ? cb0 : (which == 1) ? cb1 : cb2;
    colsub = col0 & 1023;
  }

  #pragma unroll
  for (int mi = 0; mi < 4; mi++) {
    #pragma unroll
    for (int ni = 0; ni < 4; ni++) {
      int col  = col0 + wc*64 + ni*16 + l15;
      int rowb = row0 + wr*64 + mi*16 + l4*4;
      #pragma unroll
      for (int r = 0; r < 4; r++) {
        float v = acc[mi][ni][r];
        size_t off = (size_t)(rowb + r) * Ndim + col;
        if constexpr (EPI == 0) {
          if constexpr (NOUT > 1) {
            int c2 = colsub + wc*64 + ni*16 + l15;
            cbase[(size_t)(rowb + r) * 1024 + c2] = f2b(v + bias[col]);
          } else {
            cb0[off] = f2b(v + bias[col]);
          }
        } else if constexpr (EPI == 1) {
          Cf[off] = v + bias[col] + resid[off];
        } else if constexpr (EPI == 2) {
          float u = v + bias[col];
          u = 0.5f * u * (1.0f + erff(u * 0.70710678118654752f));
          cb0[off] = f2b(u);
        } else {
          Cf[off] = v;
        }
      }
    }
  }
}

// ---------------- fused attention (flash-style) with optional KV-split ----------------
template<int SPLIT>
__global__ __launch_bounds__(256) void k_attn(
    const unsigned short* __restrict__ Qp, const unsigned short* __restrict__ Kp,
    const unsigned short* __restrict__ Vp, unsigned short* __restrict__ Op,
    float* __restrict__ PO, float* __restrict__ PM, float* __restrict__ PL, int Lk) {
  __shared__ unsigned short Ks[64][72];
  __shared__ unsigned short Vt[64][72];   // V transposed (k-chunk XOR-swizzled by d>>3)
  __shared__ float Ps[4][16][68];         // per-wave P transpose buffer
  const int b = blockIdx.z / SPLIT, sp = blockIdx.z % SPLIT;
  const int h = blockIdx.y, q0 = blockIdx.x * 64;
  const int t = threadIdx.x, lane = t & 63, w = t >> 6;
  const int l15 = lane & 15, l4 = lane >> 4;

  const int qrow = q0 + w * 16 + l15;
  const unsigned short* qptr = Qp + (size_t)(b * Sn + qrow) * En + h * 64 + l4 * 8;
  bf16x8 qf0 = *(const bf16x8*)qptr;
  bf16x8 qf1 = *(const bf16x8*)(qptr + 32);

  f32x4 oacc[4];
  #pragma unroll
  for (int i = 0; i < 4; i++) oacc[i] = (f32x4){0.f,0.f,0.f,0.f};
  float m_[4] = {-INFINITY, -INFINITY, -INFINITY, -INFINITY};
  float l_[4] = {0.f, 0.f, 0.f, 0.f};

  const int nkt = Lk / (64 * SPLIT);
  for (int kt = sp * nkt; kt < (sp + 1) * nkt; ++kt) {
    __syncthreads();
    #pragma unroll
    for (int i = 0; i < 2; i++) {
      int ld = t + i * 256;
      int kr = ld >> 3, d8 = (ld & 7) * 8;
      size_t base = (size_t)(b * Lk + kt * 64 + kr) * En + h * 64 + d8;
      *(uint4*)&Ks[kr][d8] = *(const uint4*)(Kp + base);
      bf16x8 vv = *(const bf16x8*)(Vp + base);
      int colswz = kr ^ ((t & 7) << 3);
      #pragma unroll
      for (int j = 0; j < 8; j++) Vt[d8 + j][colswz] = ((unsigned short*)&vv)[j];
    }
    __syncthreads();

    f32x4 s[4];
    #pragma unroll
    for (int ni = 0; ni < 4; ni++) {
      s[ni] = (f32x4){0.f,0.f,0.f,0.f};
      bf16x8 kb0 = *(const bf16x8*)&Ks[ni*16 + l15][l4*8];
      bf16x8 kb1 = *(const bf16x8*)&Ks[ni*16 + l15][l4*8 + 32];
      s[ni] = __builtin_amdgcn_mfma_f32_16x16x32_bf16(qf0, kb0, s[ni], 0, 0, 0);
      s[ni] = __builtin_amdgcn_mfma_f32_16x16x32_bf16(qf1, kb1, s[ni], 0, 0, 0);
    }

    #pragma unroll
    for (int r = 0; r < 4; r++) {
      #pragma unroll
      for (int ni = 0; ni < 4; ni++) s[ni][r] *= 0.125f;
      float mx = fmaxf(fmaxf(s[0][r], s[1][r]), fmaxf(s[2][r], s[3][r]));
      #pragma unroll
      for (int d2 = 1; d2 < 16; d2 <<= 1) mx = fmaxf(mx, __shfl_xor(mx, d2));
      float mn = fmaxf(m_[r], mx);
      float alpha = expf(m_[r] - mn);
      float rsum = 0.f;
      #pragma unroll
      for (int ni = 0; ni < 4; ni++) { float p = expf(s[ni][r] - mn); s[ni][r] = p; rsum += p; }
      #pragma unroll
      for (int d2 = 1; d2 < 16; d2 <<= 1) rsum += __shfl_xor(rsum, d2);
      l_[r] = l_[r] * alpha + rsum;
      m_[r] = mn;
      #pragma unroll
      for (int nd = 0; nd < 4; nd++) oacc[nd][r] *= alpha;
    }

    #pragma unroll
    for (int ni = 0; ni < 4; ni++)
      #pragma unroll
      for (int r = 0; r < 4; r++)
        Ps[w][l4*4 + r][ni*16 + l15] = s[ni][r];
    asm volatile("s_waitcnt lgkmcnt(0)" ::: "memory");

    #pragma unroll
    for (int half = 0; half < 2; half++) {
      float4 pv0 = *(const float4*)&Ps[w][l15][half*32 + l4*8];
      float4 pv1 = *(const float4*)&Ps[w][l15][half*32 + l4*8 + 4];
      bf16x8 pa;
      pa[0]=(short)f2b(pv0.x); pa[1]=(short)f2b(pv0.y); pa[2]=(short)f2b(pv0.z); pa[3]=(short)f2b(pv0.w);
      pa[4]=(short)f2b(pv1.x); pa[5]=(short)f2b(pv1.y); pa[6]=(short)f2b(pv1.z); pa[7]=(short)f2b(pv1.w);
      #pragma unroll
      for (int nd = 0; nd < 4; nd++) {
        int dd = nd*16 + l15;
        bf16x8 vb = *(const bf16x8*)&Vt[dd][(half*32 + l4*8) ^ (((dd >> 3) & 7) << 3)];
        oacc[nd] = __builtin_amdgcn_mfma_f32_16x16x32_bf16(pa, vb, oacc[nd], 0, 0, 0);
      }
    }
  }

  if constexpr (SPLIT == 1) {
    #pragma unroll
    for (int nd = 0; nd < 4; nd++)
      #pragma unroll
      for (int r = 0; r < 4; r++) {
        int q = q0 + w*16 + l4*4 + r;
        Op[(size_t)(b * Sn + q) * En + h * 64 + nd*16 + l15] = f2b(oacc[nd][r] / l_[r]);
      }
  } else {
    const int slot = ((b * Hn + h) * 4 + blockIdx.x) * SPLIT + sp;
    #pragma unroll
    for (int nd = 0; nd < 4; nd++)
      #pragma unroll
      for (int r = 0; r < 4; r++)
        PO[slot * 4096 + (w*16 + l4*4 + r) * 64 + nd*16 + l15] = oacc[nd][r];
    if (l15 == 0) {
      #pragma unroll
      for (int r = 0; r < 4; r++) {
        PM[slot * 64 + w*16 + l4*4 + r] = m_[r];
        PL[slot * 64 + w*16 + l4*4 + r] = l_[r];
      }
    }
  }
}

// ---------------- combine split-K attention partials (SPLIT=4) ----------------
__global__ __launch_bounds__(256) void k_attn_comb(
    const float* __restrict__ PO, const float* __restrict__ PM,
    const float* __restrict__ PL, unsigned short* __restrict__ Op) {
  const int W = blockIdx.x * 4 + (threadIdx.x >> 6);
  const int lane = threadIdx.x & 63;
  const int bh = W >> 8, q = W & 255;
  const int qb = q >> 6, qq = q & 63;
  const int slotBase = (bh * 4 + qb) * 4;
  float ms[4];
  float M = -INFINITY;
  #pragma unroll
  for (int s = 0; s < 4; s++) { ms[s] = PM[(slotBase + s) * 64 + qq]; M = fmaxf(M, ms[s]); }
  float L = 0.f, acc = 0.f;
  #pragma unroll
  for (int s = 0; s < 4; s++) {
    float wgt = expf(ms[s] - M);
    L += PL[(slotBase + s) * 64 + qq] * wgt;
    acc += wgt * PO[(size_t)(slotBase + s) * 4096 + qq * 64 + lane];
  }
  const int b = bh >> 4, h = bh & 15;
  Op[(size_t)(b * Sn + q) * En + h * 64 + lane] = f2b(acc / L);
}

// ------------- helpers for radix top-k -------------
DEVFN unsigned blk_exscan(unsigned part, volatile unsigned* wsum, int lane, int wid) {
  unsigned v = part;
  #pragma unroll
  for (int d = 1; d < 64; d <<= 1) { unsigned o = __shfl_up(v, d); if (lane >= d) v += o; }
  if (lane == 63) wsum[wid] = v;
  __syncthreads();
  unsigned woff = 0;
  for (int i = 0; i < wid; i++) woff += wsum[i];
  unsigned r = woff + v - part;
  __syncthreads();
  return r;
}

DEVFN void find_thr(const unsigned* hist, int NB, unsigned need,
                    int t, int lane, int wid, volatile unsigned* wsum,
                    volatile int* s_thr, volatile unsigned* s_above) {
  int per = NB >> 9;
  int lo = NB - per * (t + 1);
  unsigned part = 0;
  for (int j = 0; j < per; j++) part += hist[lo + j];
  unsigned ex = blk_exscan(part, wsum, lane, wid);
  if (ex < need && ex + part >= need) {
    unsigned c = ex;
    for (int j = per - 1; j >= 0; j--) {
      unsigned h = hist[lo + j];
      if (c + h >= need) { *s_thr = lo + j; *s_above = c; break; }
      c += h;
    }
  }
  __syncthreads();
}

// ---------------- exact top-32 per row via 3-level radix select ----------------
__global__ __launch_bounds__(512) void k_topk(
    const float* __restrict__ sims, int* __restrict__ oidx) {
  const int n = blockIdx.x, t = threadIdx.x;
  const int lane = t & 63, wid = t >> 6;
  const float4* row4 = (const float4*)(sims + (size_t)n * Mn);
  __shared__ unsigned hist[2048];
  __shared__ unsigned wsum[8];
  __shared__ int s_thr;
  __shared__ unsigned s_above, s_imin;

  for (int i = t; i < 2048; i += 512) hist[i] = 0;
  __syncthreads();
  for (int p = 0; p < 32; p++) {
    float4 v = row4[p * 512 + t];
    atomicAdd(&hist[okey(v.x) >> 21], 1u);
    atomicAdd(&hist[okey(v.y) >> 21], 1u);
    atomicAdd(&hist[okey(v.z) >> 21], 1u);
    atomicAdd(&hist[okey(v.w) >> 21], 1u);
  }
  __syncthreads();
  find_thr(hist, 2048, 32, t, lane, wid, wsum, &s_thr, &s_above);
  const unsigned T1 = (unsigned)s_thr;
  const unsigned need2 = 32 - s_above;
  const unsigned cnt1 = hist[T1];

  unsigned L = 0, istar = 0xFFFFFFFFu;
  bool done = false;
  if (cnt1 == need2) { L = T1 << 21; done = true; }

  if (!done) {
    __syncthreads();
    for (int i = t; i < 2048; i += 512) hist[i] = 0;
    __syncthreads();
    for (int p = 0; p < 32; p++) {
      float4 v = row4[p * 512 + t];
      unsigned k;
      k = okey(v.x); if ((k >> 21) == T1) atomicAdd(&hist[(k >> 10) & 2047], 1u);
      k = okey(v.y); if ((k >> 21) == T1) atomicAdd(&hist[(k >> 10) & 2047], 1u);
      k = okey(v.z); if ((k >> 21) == T1) atomicAdd(&hist[(k >> 10) & 2047], 1u);
      k = okey(v.w); if ((k >> 21) == T1) atomicAdd(&hist[(k >> 10) & 2047], 1u);
    }
    __syncthreads();
    find_thr(hist, 2048, need2, t, lane, wid, wsum, &s_thr, &s_above);
    const unsigned T2 = (unsigned)s_thr;
    const unsigned need3 = need2 - s_above;
    const unsigned cnt2 = hist[T2];
    const unsigned pfx2 = (T1 << 11) | T2;
    if (cnt2 == need3) { L = pfx2 << 10; done = true; }

    if (!done) {
      __syncthreads();
      for (int i = t; i < 2048; i += 512) hist[i] = 0;
      __syncthreads();
      for (int p = 0; p < 32; p++) {
        float4 v = row4[p * 512 + t];
        unsigned k;
        k = okey(v.x); if ((k >> 10) == pfx2) atomicAdd(&hist[k & 1023], 1u);
        k = okey(v.y); if ((k >> 10) == pfx2) atomicAdd(&hist[k & 1023], 1u);
        k = okey(v.z); if ((k >> 10) == pfx2) atomicAdd(&hist[k & 1023], 1u);
        k = okey(v.w); if ((k >> 10) == pfx2) atomicAdd(&hist[k & 1023], 1u);
      }
      __syncthreads();
      find_thr(hist, 1024, need3, t, lane, wid, wsum, &s_thr, &s_above);
      const unsigned T3 = (unsigned)s_thr;
      const unsigned needEq = need3 - s_above;
      const unsigned cntEq = hist[T3];
      L = (pfx2 << 10) | T3;
      if (cntEq != needEq) {
        int prev = -1;
        for (unsigned j = 0; j < needEq; j++) {
          if (t == 0) s_imin = 0xFFFFFFFFu;
          __syncthreads();
          for (int p = 0; p < 32; p++) {
            float4 v = row4[p * 512 + t];
            int i0 = (p * 512 + t) * 4;
            unsigned k;
            k = okey(v.x); if (k == L && i0     > prev) atomicMin(&s_imin, (unsigned)i0);
            k = okey(v.y); if (k == L && i0 + 1 > prev) atomicMin(&s_imin, (unsigned)(i0 + 1));
            k = okey(v.z); if (k == L && i0 + 2 > prev) atomicMin(&s_imin, (unsigned)(i0 + 2));
            k = okey(v.w); if (k == L && i0 + 3 > prev) atomicMin(&s_imin, (unsigned)(i0 + 3));
          }
          __syncthreads();
          prev = (int)s_imin;
          __syncthreads();
        }
        istar = (unsigned)prev;
      }
    }
  }
  __syncthreads();

  unsigned cnt = 0;
  for (int p = 0; p < 32; p++) {
    float4 v = row4[p * 512 + t];
    unsigned i0 = (unsigned)(p * 512 + t) * 4;
    unsigned k;
    k = okey(v.x); cnt += (k > L || (k == L && i0     <= istar));
    k = okey(v.y); cnt += (k > L || (k == L && i0 + 1 <= istar));
    k = okey(v.z); cnt += (k > L || (k == L && i0 + 2 <= istar));
    k = okey(v.w); cnt += (k > L || (k == L && i0 + 3 <= istar));
  }
  unsigned pos = blk_exscan(cnt, wsum, lane, wid);
  for (int p = 0; p < 32; p++) {
    float4 v = row4[p * 512 + t];
    unsigned i0 = (unsigned)(p * 512 + t) * 4;
    unsigned k;
    k = okey(v.x); if (k > L || (k == L && i0     <= istar)) oidx[n * Kt + pos++] = (int)i0;
    k = okey(v.y); if (k > L || (k == L && i0 + 1 <= istar)) oidx[n * Kt + pos++] = (int)(i0 + 1);
    k = okey(v.z); if (k > L || (k == L && i0 + 2 <= istar)) oidx[n * Kt + pos++] = (int)(i0 + 2);
    k = okey(v.w); if (k > L || (k == L && i0 + 3 <= istar)) oidx[n * Kt + pos++] = (int)(i0 + 3);
  }
}

// =============================== host ===============================
extern "C" void kernel_launch(void* const* d_in, const int* in_sizes, int n_in,
                              void* d_out, int out_size, void* d_ws, size_t ws_size,
                              hipStream_t stream) {
  (void)in_sizes; (void)n_in; (void)out_size;
  const float* x      = (const float*)d_in[0];
  const float* mem_k  = (const float*)d_in[1];
  const float* mem_v  = (const float*)d_in[2];
  const float* sa_w[4] = {(const float*)d_in[3], (const float*)d_in[4], (const float*)d_in[5], (const float*)d_in[6]};
  const float* sa_b[4] = {(const float*)d_in[7], (const float*)d_in[8], (const float*)d_in[9], (const float*)d_in[10]};
  const float* ma_w[4] = {(const float*)d_in[11], (const float*)d_in[12], (const float*)d_in[13], (const float*)d_in[14]};
  const float* ma_b[4] = {(const float*)d_in[15], (const float*)d_in[16], (const float*)d_in[17], (const float*)d_in[18]};
  const float* ln_g[3] = {(const float*)d_in[19], (const float*)d_in[21], (const float*)d_in[23]};
  const float* ln_b[3] = {(const float*)d_in[20], (const float*)d_in[22], (const float*)d_in[24]};
  const float* fc1_w = (const float*)d_in[25];
  const float* fc1_b = (const float*)d_in[26];
  const float* fc2_w = (const float*)d_in[27];
  const float* fc2_b = (const float*)d_in[28];
  float* out = (float*)d_out;

  char* ws = (char*)d_ws;
  size_t off = 0;
  auto alloc = [&](size_t bytes) -> char* {
    char* p = ws + off;
    off = (off + bytes + 255) & ~(size_t)255;
    return p;
  };

  unsigned short* wt[8];
  for (int i = 0; i < 8; i++) wt[i] = (unsigned short*)alloc((size_t)En * En * 2);  // contiguous
  unsigned short* fc1t  = (unsigned short*)alloc((size_t)FFn * En * 2);
  unsigned short* fc2t  = (unsigned short*)alloc((size_t)En * FFn * 2);
  unsigned short* xb    = (unsigned short*)alloc((size_t)NT * En * 2);
  unsigned short* Qb    = (unsigned short*)alloc((size_t)NT * En * 2);
  unsigned short* Kb    = (unsigned short*)alloc((size_t)NT * En * 2);
  unsigned short* Vb    = (unsigned short*)alloc((size_t)NT * En * 2);
  unsigned short* at1b  = (unsigned short*)alloc((size_t)NT * En * 2);
  float*          t1    = (float*)alloc((size_t)NT * En * 4);
  float*          x1f   = (float*)alloc((size_t)NT * En * 4);
  unsigned short* x1b   = (unsigned short*)alloc((size_t)NT * En * 2);
  float*          sims  = (float*)alloc((size_t)NT * Mn * 4);          // 256 MiB
  int*            idx   = (int*)alloc((size_t)NT * Kt * 4);
  unsigned short* K2b   = (unsigned short*)alloc((size_t)NT * Kt * En * 2);  // 64 MiB
  unsigned short* V2b   = (unsigned short*)alloc((size_t)NT * Kt * En * 2);  // contiguous after K2b
  unsigned short* Q2b   = (unsigned short*)alloc((size_t)NT * En * 2);
  unsigned short* at2b  = (unsigned short*)alloc((size_t)NT * En * 2);
  float*          t2    = (float*)alloc((size_t)NT * En * 4);
  float*          x2f   = (float*)alloc((size_t)NT * En * 4);
  unsigned short* x2b   = (unsigned short*)alloc((size_t)NT * En * 2);
  unsigned short* hb    = (unsigned short*)alloc((size_t)NT * FFn * 2);
  float*          t3    = (float*)alloc((size_t)NT * En * 4);
  float*          bcat_sa = (float*)alloc(3072 * 4);
  float*          bcat_ma = (float*)alloc(2048 * 4);

  if (off > ws_size) return;   // insufficient workspace: leave output poisoned (fail loudly)

  // Overlays (dead-region reuse):
  unsigned short* mkb = (unsigned short*)K2b;
  unsigned short* mvb = (unsigned short*)sims;
  float* PO = (float*)((char*)sims + (size_t)128 * 1024 * 1024);
  float* PM = PO + (size_t)1024 * 4096;
  float* PL = PM + (size_t)1024 * 64;

  // allow 128 KiB dynamic LDS for the 256^2 kernels (best effort)
  (void)hipFuncSetAttribute((const void*)&k_gemm256<4,false,1,0>,
                            hipFuncAttributeMaxDynamicSharedMemorySize, 131072);
  (void)hipFuncSetAttribute((const void*)&k_gemm256<0,true,2,1>,
                            hipFuncAttributeMaxDynamicSharedMemorySize, 131072);

  // ---- prep: weight transposes to bf16 [N][K], bias concats ----
  for (int i = 0; i < 4; i++)
    k_transpose_bf16<<<dim3(16, 16), 256, 0, stream>>>(sa_w[i], wt[i], En, En);
  for (int i = 0; i < 4; i++)
    k_transpose_bf16<<<dim3(16, 16), 256, 0, stream>>>(ma_w[i], wt[4 + i], En, En);
  k_transpose_bf16<<<dim3(64, 16), 256, 0, stream>>>(fc1_w, fc1t, En, FFn);
  k_transpose_bf16<<<dim3(16, 64), 256, 0, stream>>>(fc2_w, fc2t, FFn, En);
  k_concat3<<<dim3(12), 256, 0, stream>>>(sa_b[0], sa_b[1], sa_b[2], bcat_sa);
  k_concat3<<<dim3(8),  256, 0, stream>>>(ma_b[1], ma_b[2], ma_b[2], bcat_ma);

  k_cvt_bf16<<<dim3(NT * En / 4 / 256), 256, 0, stream>>>(x, xb, NT * En / 4);
  k_normcvt<<<dim3(Mn), 256, 0, stream>>>(mem_k, mkb);

  const dim3 g1(En / 128, NT / 128);   // (8,8)

  // ---- self-attention (QKV fused: N=3072 over contiguous wt[0..2]) ----
  k_gemm<0,false,false,3><<<dim3(24, 8), 256, 0, stream>>>(xb, wt[0], nullptr, bcat_sa, nullptr, nullptr, Qb, Kb, Vb, 3072, En);
  k_attn<1><<<dim3(Sn / 64, Hn, Bn), 256, 0, stream>>>(Qb, Kb, Vb, at1b, nullptr, nullptr, nullptr, Sn);
  k_gemm<1,false,false,1><<<g1, 256, 0, stream>>>(at1b, wt[3], nullptr, sa_b[3], x, t1, nullptr, nullptr, nullptr, En, En);
  k_layernorm<<<NT, 256, 0, stream>>>(t1, ln_g[0], ln_b[0], x1f, x1b);

  // ---- retrieval: sims (256^2 ring-buffer pipeline) + radix top-k ----
  k_gemm256<4,false,1,0><<<dim3(1024), 512, 131072, stream>>>(
      x1b, mkb, nullptr, nullptr, sims, nullptr, nullptr, Mn, En, NT / 256, Mn / 256);
  k_topk<<<NT, 512, 0, stream>>>(sims, idx);

  // ---- memory cross-attention (K2/V2 fused 256^2 over contiguous wt[5..6]) ----
  k_cvt_bf16<<<dim3(Mn * En / 4 / 256), 256, 0, stream>>>(mem_v, mvb, Mn * En / 4);
  k_gemm256<0,true,2,1><<<dim3(1024), 512, 131072, stream>>>(
      mvb, wt[5], idx, bcat_ma, nullptr, K2b, V2b, 2048, En, NT * Kt / 256, 2048 / 256);
  k_gemm<0,false,false,1><<<g1, 256, 0, stream>>>(x1b, wt[4], nullptr, ma_b[0], nullptr, nullptr, Q2b, nullptr, nullptr, En, En);
  k_attn<4><<<dim3(Sn / 64, Hn, Bn * 4), 256, 0, stream>>>(Q2b, K2b, V2b, nullptr, PO, PM, PL, Sn * Kt);
  k_attn_comb<<<dim3(Bn * Hn * Sn / 4), 256, 0, stream>>>(PO, PM, PL, at2b);
  k_gemm<1,false,false,1><<<g1, 256, 0, stream>>>(at2b, wt[7], nullptr, ma_b[3], x1f, t2, nullptr, nullptr, nullptr, En, En);
  k_layernorm<<<NT, 256, 0, stream>>>(t2, ln_g[1], ln_b[1], x2f, x2b);

  // ---- FFN ----
  k_gemm<2,false,false,1><<<dim3(FFn / 128, NT / 128), 256, 0, stream>>>(x2b, fc1t, nullptr, fc1_b, nullptr, nullptr, hb, nullptr, nullptr, FFn, En);
  k_gemm<1,false,false,1><<<g1, 256, 0, stream>>>(hb, fc2t, nullptr, fc2_b, x2f, t3, nullptr, nullptr, nullptr, En, FFn);
  k_layernorm<<<NT, 256, 0, stream>>>(t3, ln_g[2], ln_b[2], out, nullptr);
}